// Round 1
// baseline (7639.400 us; speedup 1.0000x reference)
//
#include <hip/hip_runtime.h>
#include <hip/hip_bf16.h>
#include <math.h>

#define BATCH 16
#define TLEN 3600
#define LEADS 12
#define PP 9
#define SS 400
#define DP 128
#define DM 256
#define NH 8
#define HD 32
#define NLAY 6
#define VV 512
#define RH 64

__device__ __forceinline__ float gelu_f(float x) {
    return 0.5f * x * (1.0f + erff(x * 0.70710678118654752f));
}

// ---------- block reduction helpers ----------
__device__ __forceinline__ float block_sum_256(float v, float* sm) {
    #pragma unroll
    for (int o = 32; o > 0; o >>= 1) v += __shfl_down(v, o);
    __syncthreads();
    if ((threadIdx.x & 63) == 0) sm[threadIdx.x >> 6] = v;
    __syncthreads();
    return sm[0] + sm[1] + sm[2] + sm[3];
}

__device__ __forceinline__ float block_sum_128(float v, float* sm) {
    #pragma unroll
    for (int o = 32; o > 0; o >>= 1) v += __shfl_down(v, o);
    __syncthreads();
    if ((threadIdx.x & 63) == 0) sm[threadIdx.x >> 6] = v;
    __syncthreads();
    return sm[0] + sm[1];
}

__device__ __forceinline__ float block_max_128(float v, float* sm) {
    #pragma unroll
    for (int o = 32; o > 0; o >>= 1) v = fmaxf(v, __shfl_down(v, o));
    __syncthreads();
    if ((threadIdx.x & 63) == 0) sm[threadIdx.x >> 6] = v;
    __syncthreads();
    return fmaxf(sm[0], sm[1]);
}

// ---------- conv over (B,T,LEADS)-layout input, output (B,Co,T), always GELU ----------
__global__ __launch_bounds__(256) void conv_tl_k(const float* __restrict__ in,
                                                 const float* __restrict__ w,
                                                 const float* __restrict__ bias,
                                                 float* __restrict__ out,
                                                 int Ci, int Co, int K, int pad) {
    __shared__ float ws[LEADS * 7];
    int co = blockIdx.y, b = blockIdx.z;
    for (int i = threadIdx.x; i < Ci * K; i += 256) ws[i] = w[co * Ci * K + i];
    __syncthreads();
    int t = blockIdx.x * 256 + threadIdx.x;
    if (t >= TLEN) return;
    float acc = bias[co];
    for (int k = 0; k < K; ++k) {
        int tt = t + k - pad;
        if (tt < 0 || tt >= TLEN) continue;
        const float* xr = in + ((size_t)b * TLEN + tt) * LEADS;
        for (int ci = 0; ci < Ci; ++ci) acc += xr[ci] * ws[ci * K + k];
    }
    out[((size_t)(b * Co + co)) * TLEN + t] = gelu_f(acc);
}

// ---------- conv over channel-major (B,Ci,T) input, output (B,Co,T) ----------
__global__ __launch_bounds__(256) void conv_cm_k(const float* __restrict__ in,
                                                 const float* __restrict__ w,
                                                 const float* __restrict__ bias,
                                                 float* __restrict__ out,
                                                 int Ci, int Co, int K, int pad, int act) {
    __shared__ float ws[DP * 5];
    int co = blockIdx.y, b = blockIdx.z;
    for (int i = threadIdx.x; i < Ci * K; i += 256) ws[i] = w[co * Ci * K + i];
    __syncthreads();
    int t = blockIdx.x * 256 + threadIdx.x;
    if (t >= TLEN) return;
    float acc = bias[co];
    for (int ci = 0; ci < Ci; ++ci) {
        const float* ip = in + ((size_t)(b * Ci + ci)) * TLEN;
        const float* wr = ws + ci * K;
        for (int k = 0; k < K; ++k) {
            int tt = t + k - pad;
            if (tt >= 0 && tt < TLEN) acc += ip[tt] * wr[k];
        }
    }
    out[((size_t)(b * Co + co)) * TLEN + t] = act ? gelu_f(acc) : acc;
}

// ---------- patch conv (stride 9, k 9) + LayerNorm over DP, out z_e (B*S, DP) ----------
__global__ __launch_bounds__(128) void patchln_k(const float* __restrict__ h2,
                                                 const float* __restrict__ pw,
                                                 const float* __restrict__ pb,
                                                 const float* __restrict__ g,
                                                 const float* __restrict__ bb,
                                                 float* __restrict__ ze) {
    int s = blockIdx.x, b = blockIdx.y, d = threadIdx.x;
    __shared__ __align__(16) float tile[DP * PP];
    __shared__ float sm[2];
    const float* src = h2 + ((size_t)(b * DP + d)) * TLEN + s * PP;
    #pragma unroll
    for (int k = 0; k < PP; ++k) tile[d * PP + k] = src[k];
    __syncthreads();
    float acc = pb[d];
    const float* wr = pw + (size_t)d * (DP * PP);
    for (int i = 0; i < DP * PP; i += 4) {
        float4 w4 = *(const float4*)(wr + i);
        float4 t4 = *(const float4*)(tile + i);
        acc += w4.x * t4.x + w4.y * t4.y + w4.z * t4.z + w4.w * t4.w;
    }
    float mean = block_sum_128(acc, sm) * (1.0f / DP);
    float dv = acc - mean;
    float var = block_sum_128(dv * dv, sm) * (1.0f / DP);
    ze[((size_t)(b * SS + s)) * DP + d] = dv * rsqrtf(var + 1e-5f) * g[d] + bb[d];
}

// ---------- codebook norms ----------
__global__ void cbnorm_k(const float* __restrict__ cb, float* __restrict__ cbn) {
    int c = blockIdx.x * 256 + threadIdx.x;
    if (c < VV) {
        const float* cr = cb + (size_t)c * DP;
        float s = 0;
        for (int i = 0; i < DP; ++i) s += cr[i] * cr[i];
        cbn[c] = s;
    }
}

// ---------- VQ: argmin over codebook + per-row (zq-zf)^2 sum ----------
__global__ __launch_bounds__(256) void vq_k(const float* __restrict__ ze,
                                            const float* __restrict__ cb,
                                            const float* __restrict__ cbn,
                                            float* __restrict__ zq,
                                            float* __restrict__ vqs) {
    int row = blockIdx.x, tid = threadIdx.x;
    __shared__ __align__(16) float zf[DP];
    __shared__ float sval[256];
    __shared__ int sidx[256];
    __shared__ float sm[4];
    if (tid < DP) zf[tid] = ze[(size_t)row * DP + tid];
    __syncthreads();
    float best = 1e30f; int bi = 0;
    for (int c = tid; c < VV; c += 256) {
        const float* cr = cb + (size_t)c * DP;
        float dot = 0;
        #pragma unroll 8
        for (int i = 0; i < DP; i += 4) {
            float4 c4 = *(const float4*)(cr + i);
            float4 z4 = *(const float4*)(zf + i);
            dot += c4.x * z4.x + c4.y * z4.y + c4.z * z4.z + c4.w * z4.w;
        }
        float dist = cbn[c] - 2.0f * dot;
        if (dist < best) { best = dist; bi = c; }
    }
    sval[tid] = best; sidx[tid] = bi;
    __syncthreads();
    for (int s = 128; s > 0; s >>= 1) {
        if (tid < s) {
            float ov = sval[tid + s]; int oi = sidx[tid + s];
            if (ov < sval[tid] || (ov == sval[tid] && oi < sidx[tid])) { sval[tid] = ov; sidx[tid] = oi; }
        }
        __syncthreads();
    }
    int tok = sidx[0];
    float part = 0;
    if (tid < DP) {
        float qv = cb[(size_t)tok * DP + tid];
        zq[(size_t)row * DP + tid] = qv;
        float dq = qv - zf[tid];
        part = dq * dq;
    }
    float tot = block_sum_256(part, sm);
    if (tid == 0) vqs[row] = tot;
}

__global__ void vqreduce_k(const float* __restrict__ vqs, float* __restrict__ out) {
    float s = 0;
    for (int i = threadIdx.x; i < BATCH * SS; i += 256) s += vqs[i];
    __shared__ float sm[4];
    s = block_sum_256(s, sm);
    if (threadIdx.x == 0) out[0] = s * (1.25f / (float)(BATCH * SS * DP));
}

// ---------- generic fp32 GEMM: C = [res +] act( A(MxK) @ W(NxK)^T + bias ) ----------
template <int ACT, int RES>
__global__ __launch_bounds__(256) void gemm_k(const float* __restrict__ A,
                                              const float* __restrict__ W,
                                              const float* __restrict__ bias,
                                              const float* __restrict__ res,
                                              float* __restrict__ C,
                                              int M, int N, int K) {
    __shared__ float As[16][65];
    __shared__ float Bs[16][65];
    const int bm = blockIdx.y * 64, bn = blockIdx.x * 64;
    const int tid = threadIdx.x;
    const int tx = tid & 15, ty = tid >> 4;
    float acc[4][4] = {};
    const int lr = tid >> 2;
    const int lc = (tid & 3) * 4;
    for (int k0 = 0; k0 < K; k0 += 16) {
        float4 av = *(const float4*)&A[(size_t)(bm + lr) * K + k0 + lc];
        As[lc + 0][lr] = av.x; As[lc + 1][lr] = av.y; As[lc + 2][lr] = av.z; As[lc + 3][lr] = av.w;
        float4 wv = *(const float4*)&W[(size_t)(bn + lr) * K + k0 + lc];
        Bs[lc + 0][lr] = wv.x; Bs[lc + 1][lr] = wv.y; Bs[lc + 2][lr] = wv.z; Bs[lc + 3][lr] = wv.w;
        __syncthreads();
        #pragma unroll
        for (int kk = 0; kk < 16; ++kk) {
            float a[4], bv[4];
            #pragma unroll
            for (int i = 0; i < 4; ++i) a[i] = As[kk][ty * 4 + i];
            #pragma unroll
            for (int j = 0; j < 4; ++j) bv[j] = Bs[kk][tx * 4 + j];
            #pragma unroll
            for (int i = 0; i < 4; ++i)
                #pragma unroll
                for (int j = 0; j < 4; ++j) acc[i][j] = fmaf(a[i], bv[j], acc[i][j]);
        }
        __syncthreads();
    }
    #pragma unroll
    for (int i = 0; i < 4; ++i) {
        int m = bm + ty * 4 + i;
        #pragma unroll
        for (int j = 0; j < 4; ++j) {
            int n = bn + tx * 4 + j;
            float t = acc[i][j] + bias[n];
            if (ACT == 1) t = gelu_f(t);
            if (RES == 1) t += res[(size_t)m * N + n];
            C[(size_t)m * N + n] = t;
        }
    }
}

// ---------- LayerNorm over 256 (one row per block) ----------
__global__ __launch_bounds__(256) void ln_k(const float* __restrict__ in,
                                            const float* __restrict__ g,
                                            const float* __restrict__ bb,
                                            float* __restrict__ out) {
    int row = blockIdx.x, tid = threadIdx.x;
    __shared__ float sm[4];
    float v = in[(size_t)row * DM + tid];
    float mean = block_sum_256(v, sm) * (1.0f / DM);
    float d = v - mean;
    float var = block_sum_256(d * d, sm) * (1.0f / DM);
    out[(size_t)row * DM + tid] = d * rsqrtf(var + 1e-5f) * g[tid] + bb[tid];
}

// ---------- attention: one block per (q, h, b) ----------
__global__ __launch_bounds__(128) void attn_k(const float* __restrict__ qkv,
                                              const float* __restrict__ slopes,
                                              float* __restrict__ out) {
    int q = blockIdx.x, hh = blockIdx.y, b = blockIdx.z;
    int tid = threadIdx.x;
    __shared__ __align__(16) float qrow[HD];
    __shared__ float ls[SS];
    __shared__ float sm[2];
    __shared__ float sacc[4][HD];
    const float slope = fabsf(slopes[hh]);
    const float* base = qkv + (size_t)b * SS * (3 * DM);
    if (tid < HD) qrow[tid] = base[(size_t)q * (3 * DM) + hh * HD + tid];
    __syncthreads();
    for (int k = tid; k < SS; k += 128) {
        const float* kr = base + (size_t)k * (3 * DM) + DM + hh * HD;
        float d = 0;
        #pragma unroll
        for (int i = 0; i < HD; i += 4) {
            float4 k4 = *(const float4*)(kr + i);
            d += qrow[i] * k4.x + qrow[i + 1] * k4.y + qrow[i + 2] * k4.z + qrow[i + 3] * k4.w;
        }
        ls[k] = d * 0.17677669529663687f - slope * fabsf((float)(q - k));
    }
    __syncthreads();
    float m = -1e30f;
    for (int k = tid; k < SS; k += 128) m = fmaxf(m, ls[k]);
    m = block_max_128(m, sm);
    float ssum = 0;
    for (int k = tid; k < SS; k += 128) { float e = __expf(ls[k] - m); ls[k] = e; ssum += e; }
    float tot = block_sum_128(ssum, sm);
    float inv = 1.0f / tot;
    __syncthreads();
    int chunk = tid >> 5, d = tid & 31;
    const float* vbase = base + 2 * DM + hh * HD + d;
    float acc = 0;
    for (int k = chunk * 100; k < chunk * 100 + 100; ++k) acc += ls[k] * vbase[(size_t)k * (3 * DM)];
    sacc[chunk][d] = acc;
    __syncthreads();
    if (tid < HD)
        out[((size_t)(b * SS + q)) * DM + hh * HD + tid] =
            (sacc[0][tid] + sacc[1][tid] + sacc[2][tid] + sacc[3][tid]) * inv;
}

// ---------- decoder up-projection (ConvTranspose stride=kernel=9), GELU ----------
__global__ __launch_bounds__(256) void upproj_k(const float* __restrict__ hf,
                                                const float* __restrict__ uw,
                                                const float* __restrict__ ub,
                                                float* __restrict__ u) {
    int row = blockIdx.x, tid = threadIdx.x;
    int b = row / SS, s = row - b * SS;
    __shared__ float hr[DM];
    hr[tid] = hf[(size_t)row * DM + tid];
    __syncthreads();
    for (int n = tid; n < (DM / 2) * PP; n += 256) {
        int o = n / PP, k = n - o * PP;
        float acc = ub[o];
        for (int d = 0; d < DM; ++d) acc += hr[d] * uw[(size_t)d * ((DM / 2) * PP) + n];
        u[((size_t)(b * (DM / 2) + o)) * TLEN + s * PP + k] = gelu_f(acc);
    }
}

// ---------- final: d2 conv + r4 1x1 conv + alpha blend, out (B,T,LEADS) ----------
__global__ __launch_bounds__(256) void final_k(const float* __restrict__ ud1,
                                               const float* __restrict__ r3,
                                               const float* __restrict__ d2w,
                                               const float* __restrict__ d2b,
                                               const float* __restrict__ r4w,
                                               const float* __restrict__ r4b,
                                               const float* __restrict__ alpha,
                                               float* __restrict__ out) {
    int idx = blockIdx.x * 256 + threadIdx.x;
    int l = idx % LEADS;
    int bt = idx / LEADS;
    int t = bt % TLEN;
    int b = bt / TLEN;
    float dec = d2b[l];
    for (int ci = 0; ci < 64; ++ci) {
        const float* up = ud1 + ((size_t)(b * 64 + ci)) * TLEN;
        const float* w = d2w + (l * 64 + ci) * 3;
        if (t > 0) dec += up[t - 1] * w[0];
        dec += up[t] * w[1];
        if (t < TLEN - 1) dec += up[t + 1] * w[2];
    }
    float res = r4b[l];
    const float* rb = r3 + (size_t)b * 64 * TLEN + t;
    for (int ci = 0; ci < 64; ++ci) res += rb[(size_t)ci * TLEN] * r4w[l * 64 + ci];
    out[idx] = dec + alpha[0] * res;
}

extern "C" void kernel_launch(void* const* d_in, const int* in_sizes, int n_in,
                              void* d_out, int out_size, void* d_ws, size_t ws_size,
                              hipStream_t stream) {
    const float* x     = (const float*)d_in[0];
    const float* pe_w1 = (const float*)d_in[1];
    const float* pe_b1 = (const float*)d_in[2];
    const float* pe_w2 = (const float*)d_in[3];
    const float* pe_b2 = (const float*)d_in[4];
    const float* pe_pw = (const float*)d_in[5];
    const float* pe_pb = (const float*)d_in[6];
    const float* pe_g  = (const float*)d_in[7];
    const float* pe_bb = (const float*)d_in[8];
    const float* cb    = (const float*)d_in[9];
    const float* tp_w  = (const float*)d_in[10];
    const float* tp_b  = (const float*)d_in[11];
    const float* tp_g  = (const float*)d_in[12];
    const float* tp_bb = (const float*)d_in[13];
    const float* ln1_g = (const float*)d_in[14];
    const float* ln1_b = (const float*)d_in[15];
    const float* inw   = (const float*)d_in[16];
    const float* inb   = (const float*)d_in[17];
    const float* ow    = (const float*)d_in[18];
    const float* ob    = (const float*)d_in[19];
    const float* ln2_g = (const float*)d_in[20];
    const float* ln2_b = (const float*)d_in[21];
    const float* f1w   = (const float*)d_in[22];
    const float* f1b   = (const float*)d_in[23];
    const float* f2w   = (const float*)d_in[24];
    const float* f2b   = (const float*)d_in[25];
    const float* slopes= (const float*)d_in[26];
    const float* fn_g  = (const float*)d_in[27];
    const float* fn_b  = (const float*)d_in[28];
    const float* up_w  = (const float*)d_in[29];
    const float* up_b  = (const float*)d_in[30];
    const float* d1w   = (const float*)d_in[31];
    const float* d1b   = (const float*)d_in[32];
    const float* d2w   = (const float*)d_in[33];
    const float* d2b   = (const float*)d_in[34];
    const float* r1w   = (const float*)d_in[35];
    const float* r1b   = (const float*)d_in[36];
    const float* r2w   = (const float*)d_in[37];
    const float* r2b   = (const float*)d_in[38];
    const float* r3w   = (const float*)d_in[39];
    const float* r3b   = (const float*)d_in[40];
    const float* r4w   = (const float*)d_in[41];
    const float* r4b   = (const float*)d_in[42];
    const float* alpha = (const float*)d_in[43];

    float* W = (float*)d_ws;
    size_t off = 0;
    auto alloc = [&](size_t n) { float* p = W + off; off += n; return p; };
    float* A   = alloc((size_t)BATCH * DP * TLEN);        // h2 / u        7.37M
    float* Bb  = alloc((size_t)BATCH * 64 * TLEN);        // h1 / ud1      3.69M
    float* Cc  = alloc((size_t)BATCH * 64 * TLEN);        // r1 / r3       3.69M
    float* Dd  = alloc((size_t)BATCH * 64 * TLEN);        // r2            3.69M
    float* ze  = alloc((size_t)BATCH * SS * DP);          // 0.82M
    float* zqb = alloc((size_t)BATCH * SS * DP);          // 0.82M
    float* tx  = alloc((size_t)BATCH * SS * DM);          // tpre/xn/hfin  1.64M
    float* hb  = alloc((size_t)BATCH * SS * DM);          // h             1.64M
    float* qf  = alloc((size_t)BATCH * SS * 4 * DM);      // qkv / ffn1    6.55M
    float* ao  = alloc((size_t)BATCH * SS * DM);          // attn out      1.64M
    float* cbn = alloc(VV);
    float* vqs = alloc((size_t)BATCH * SS);
    if (off * sizeof(float) > ws_size) return;  // workspace too small — fail loudly

    float* outp = (float*)d_out;
    const int tgrid = (TLEN + 255) / 256;  // 15

    // --- encoder ---
    conv_tl_k<<<dim3(tgrid, 64, BATCH), 256, 0, stream>>>(x, pe_w1, pe_b1, Bb, LEADS, 64, 3, 1);
    conv_cm_k<<<dim3(tgrid, DP, BATCH), 256, 0, stream>>>(Bb, pe_w2, pe_b2, A, 64, DP, 3, 1, 1);
    cbnorm_k<<<2, 256, 0, stream>>>(cb, cbn);
    patchln_k<<<dim3(SS, BATCH), 128, 0, stream>>>(A, pe_pw, pe_pb, pe_g, pe_bb, ze);
    vq_k<<<BATCH * SS, 256, 0, stream>>>(ze, cb, cbn, zqb, vqs);
    vqreduce_k<<<1, 256, 0, stream>>>(vqs, outp + (size_t)BATCH * TLEN * LEADS);

    // --- token projection + LN ---
    gemm_k<0, 0><<<dim3(DM / 64, BATCH * SS / 64), 256, 0, stream>>>(zqb, tp_w, tp_b, nullptr, tx, BATCH * SS, DM, DP);
    ln_k<<<BATCH * SS, 256, 0, stream>>>(tx, tp_g, tp_bb, hb);

    // --- transformer ---
    for (int l = 0; l < NLAY; ++l) {
        ln_k<<<BATCH * SS, 256, 0, stream>>>(hb, ln1_g + l * DM, ln1_b + l * DM, tx);
        gemm_k<0, 0><<<dim3(3 * DM / 64, BATCH * SS / 64), 256, 0, stream>>>(
            tx, inw + (size_t)l * 3 * DM * DM, inb + l * 3 * DM, nullptr, qf, BATCH * SS, 3 * DM, DM);
        attn_k<<<dim3(SS, NH, BATCH), 128, 0, stream>>>(qf, slopes + l * NH, ao);
        gemm_k<0, 1><<<dim3(DM / 64, BATCH * SS / 64), 256, 0, stream>>>(
            ao, ow + (size_t)l * DM * DM, ob + l * DM, hb, hb, BATCH * SS, DM, DM);
        ln_k<<<BATCH * SS, 256, 0, stream>>>(hb, ln2_g + l * DM, ln2_b + l * DM, tx);
        gemm_k<1, 0><<<dim3(4 * DM / 64, BATCH * SS / 64), 256, 0, stream>>>(
            tx, f1w + (size_t)l * 4 * DM * DM, f1b + l * 4 * DM, nullptr, qf, BATCH * SS, 4 * DM, DM);
        gemm_k<0, 1><<<dim3(DM / 64, BATCH * SS / 64), 256, 0, stream>>>(
            qf, f2w + (size_t)l * DM * 4 * DM, f2b + l * DM, hb, hb, BATCH * SS, DM, 4 * DM);
    }
    ln_k<<<BATCH * SS, 256, 0, stream>>>(hb, fn_g, fn_b, tx);

    // --- decoder ---
    upproj_k<<<BATCH * SS, 256, 0, stream>>>(tx, up_w, up_b, A);
    conv_cm_k<<<dim3(tgrid, 64, BATCH), 256, 0, stream>>>(A, d1w, d1b, Bb, DP, 64, 5, 2, 1);

    // --- residual CNN ---
    conv_tl_k<<<dim3(tgrid, 64, BATCH), 256, 0, stream>>>(x, r1w, r1b, Cc, LEADS, 64, 7, 3);
    conv_cm_k<<<dim3(tgrid, 64, BATCH), 256, 0, stream>>>(Cc, r2w, r2b, Dd, 64, 64, 5, 2, 1);
    conv_cm_k<<<dim3(tgrid, 64, BATCH), 256, 0, stream>>>(Dd, r3w, r3b, Cc, 64, 64, 3, 1, 1);

    // --- fused d2 conv + r4 conv + alpha blend ---
    final_k<<<(BATCH * TLEN * LEADS) / 256, 256, 0, stream>>>(Bb, Cc, d2w, d2b, r4w, r4b, alpha, outp);
}

// Round 2
// 3905.977 us; speedup vs baseline: 1.9558x; 1.9558x over previous
//
#include <hip/hip_runtime.h>
#include <hip/hip_bf16.h>
#include <math.h>

#define BATCH 16
#define TLEN 3600
#define LEADS 12
#define PP 9
#define SS 400
#define DP 128
#define DM 256
#define NH 8
#define HD 32
#define NLAY 6
#define VV 512
#define RH 64

__device__ __forceinline__ float gelu_f(float x) {
    return 0.5f * x * (1.0f + erff(x * 0.70710678118654752f));
}

// ---------- block reduction helpers ----------
__device__ __forceinline__ float block_sum_256(float v, float* sm) {
    #pragma unroll
    for (int o = 32; o > 0; o >>= 1) v += __shfl_down(v, o);
    __syncthreads();
    if ((threadIdx.x & 63) == 0) sm[threadIdx.x >> 6] = v;
    __syncthreads();
    return sm[0] + sm[1] + sm[2] + sm[3];
}

__device__ __forceinline__ float block_sum_128(float v, float* sm) {
    #pragma unroll
    for (int o = 32; o > 0; o >>= 1) v += __shfl_down(v, o);
    __syncthreads();
    if ((threadIdx.x & 63) == 0) sm[threadIdx.x >> 6] = v;
    __syncthreads();
    return sm[0] + sm[1];
}

// ---------- generic LDS-staged implicit-GEMM conv ----------
// out(B,Co,T) = act( w(Co,CI,K) * in + bias ), T=3600.
// LAYOUT 0: in(B,CI,T) channel-major. LAYOUT 1: in(B,T,CI) time-major.
// LAYOUT 2: in(B,S,CI*9) patch-major (upproj GEMM output), t = s*9+k.
// Block: 64 co x 64 t tile, 256 threads, 4x4 register accum.
template <int CI, int K, int LAYOUT, int ACT>
__global__ __launch_bounds__(256) void convg_k(const float* __restrict__ in,
                                               const float* __restrict__ w,
                                               const float* __restrict__ bias,
                                               float* __restrict__ out,
                                               int Co, int pad) {
    constexpr int CHUNK = (CI % 16 == 0) ? 16 : CI;
    constexpr int TT = 64 + K - 1;
    constexpr int NV = (K + 6) / 4;        // float4 loads covering tx*4 .. tx*4+3+K-1
    constexpr int TTP = 64 + 4 * NV;       // padded row so float4 reads stay in-bounds
    __shared__ __align__(16) float in_s[CHUNK][TTP];
    __shared__ __align__(16) float w_s[CHUNK][K][64];
    const int b = blockIdx.z;
    const int co0 = blockIdx.y * 64;
    const int t0 = blockIdx.x * 64;
    const int tid = threadIdx.x;
    const int tx = tid & 15, ty = tid >> 4;
    float acc[4][4] = {};
    for (int c0 = 0; c0 < CI; c0 += CHUNK) {
        __syncthreads();
        for (int idx = tid; idx < CHUNK * TT; idx += 256) {
            int ci = idx / TT, j = idx - ci * TT;
            int t = t0 + j - pad;
            float v = 0.f;
            if (t >= 0 && t < TLEN) {
                if (LAYOUT == 0) v = in[((size_t)(b * CI + c0 + ci)) * TLEN + t];
                else if (LAYOUT == 1) v = in[((size_t)b * TLEN + t) * CI + (c0 + ci)];
                else { int s = t / PP, k = t - s * PP;
                       v = in[((size_t)(b * SS + s)) * (CI * PP) + (c0 + ci) * PP + k]; }
            }
            in_s[ci][j] = v;
        }
        for (int idx = tid; idx < CHUNK * K * 64; idx += 256) {
            int co = idx & 63; int rest = idx >> 6; int k = rest % K; int ci = rest / K;
            w_s[ci][k][co] = w[((size_t)(co0 + co) * CI + (c0 + ci)) * K + k];
        }
        __syncthreads();
        #pragma unroll
        for (int ci = 0; ci < CHUNK; ++ci) {
            float tv[NV * 4];
            #pragma unroll
            for (int vv = 0; vv < NV; ++vv)
                *(float4*)&tv[vv * 4] = *(const float4*)&in_s[ci][tx * 4 + vv * 4];
            #pragma unroll
            for (int k = 0; k < K; ++k) {
                float4 wv = *(const float4*)&w_s[ci][k][ty * 4];
                #pragma unroll
                for (int j = 0; j < 4; ++j) {
                    float iv = tv[j + k];
                    acc[0][j] = fmaf(wv.x, iv, acc[0][j]);
                    acc[1][j] = fmaf(wv.y, iv, acc[1][j]);
                    acc[2][j] = fmaf(wv.z, iv, acc[2][j]);
                    acc[3][j] = fmaf(wv.w, iv, acc[3][j]);
                }
            }
        }
    }
    const bool full = (t0 + 64 <= TLEN);
    #pragma unroll
    for (int i = 0; i < 4; ++i) {
        int co = co0 + ty * 4 + i;
        float bs = bias[co];
        float* orow = out + ((size_t)(b * Co + co)) * TLEN;
        if (full) {
            float4 o4;
            float vv0 = acc[i][0] + bs, vv1 = acc[i][1] + bs, vv2 = acc[i][2] + bs, vv3 = acc[i][3] + bs;
            if (ACT) { vv0 = gelu_f(vv0); vv1 = gelu_f(vv1); vv2 = gelu_f(vv2); vv3 = gelu_f(vv3); }
            o4.x = vv0; o4.y = vv1; o4.z = vv2; o4.w = vv3;
            *(float4*)&orow[t0 + tx * 4] = o4;
        } else {
            #pragma unroll
            for (int j = 0; j < 4; ++j) {
                int t = t0 + tx * 4 + j;
                if (t < TLEN) {
                    float v = acc[i][j] + bs;
                    if (ACT) v = gelu_f(v);
                    orow[t] = v;
                }
            }
        }
    }
}

// ---------- patch conv (stride 9, k 9) + LayerNorm over DP, out z_e (B*S, DP) ----------
__global__ __launch_bounds__(128) void patchln_k(const float* __restrict__ h2,
                                                 const float* __restrict__ pw,
                                                 const float* __restrict__ pb,
                                                 const float* __restrict__ g,
                                                 const float* __restrict__ bb,
                                                 float* __restrict__ ze) {
    int s = blockIdx.x, b = blockIdx.y, d = threadIdx.x;
    __shared__ __align__(16) float tile[DP * PP];
    __shared__ float sm[2];
    const float* src = h2 + ((size_t)(b * DP + d)) * TLEN + s * PP;
    #pragma unroll
    for (int k = 0; k < PP; ++k) tile[d * PP + k] = src[k];
    __syncthreads();
    float acc = pb[d];
    const float* wr = pw + (size_t)d * (DP * PP);
    for (int i = 0; i < DP * PP; i += 4) {
        float4 w4 = *(const float4*)(wr + i);
        float4 t4 = *(const float4*)(tile + i);
        acc += w4.x * t4.x + w4.y * t4.y + w4.z * t4.z + w4.w * t4.w;
    }
    float mean = block_sum_128(acc, sm) * (1.0f / DP);
    float dv = acc - mean;
    float var = block_sum_128(dv * dv, sm) * (1.0f / DP);
    ze[((size_t)(b * SS + s)) * DP + d] = dv * rsqrtf(var + 1e-5f) * g[d] + bb[d];
}

// ---------- codebook norms ----------
__global__ void cbnorm_k(const float* __restrict__ cb, float* __restrict__ cbn) {
    int c = blockIdx.x * 256 + threadIdx.x;
    if (c < VV) {
        const float* cr = cb + (size_t)c * DP;
        float s = 0;
        for (int i = 0; i < DP; ++i) s += cr[i] * cr[i];
        cbn[c] = s;
    }
}

// ---------- VQ: tiled distance GEMM + argmin + commit partials ----------
// Block: 32 rows, iterate codebook in 64-code LDS chunks. thread = (r, cs): r=tid>>3, cs=tid&7.
__global__ __launch_bounds__(256) void vq2_k(const float* __restrict__ ze,
                                             const float* __restrict__ cb,
                                             const float* __restrict__ cbn,
                                             float* __restrict__ zq,
                                             float* __restrict__ vqs) {
    __shared__ __align__(16) float z_s[32][132];
    __shared__ __align__(16) float cb_s[64][132];
    __shared__ float cbn_s[64];
    __shared__ float bval[256];
    __shared__ int bidx[256];
    __shared__ int tok_s[32];
    __shared__ float psum[256];
    const int tid = threadIdx.x;
    const int r0 = blockIdx.x * 32;
    const int r = tid >> 3, cs = tid & 7;
    for (int idx = tid; idx < 32 * 128; idx += 256) {
        int rr = idx >> 7, cc = idx & 127;
        z_s[rr][cc] = ze[((size_t)(r0 + rr)) * DP + cc];
    }
    float best = 1e30f; int bi = 0;
    for (int c0 = 0; c0 < VV; c0 += 64) {
        __syncthreads();
        for (int idx = tid; idx < 64 * 128; idx += 256) {
            int rr = idx >> 7, cc = idx & 127;
            cb_s[rr][cc] = cb[((size_t)(c0 + rr)) * DP + cc];
        }
        if (tid < 64) cbn_s[tid] = cbn[c0 + tid];
        __syncthreads();
        float dot[8] = {};
        for (int i = 0; i < 128; i += 4) {
            float4 zv = *(const float4*)&z_s[r][i];
            #pragma unroll
            for (int j = 0; j < 8; ++j) {
                float4 cv = *(const float4*)&cb_s[cs + 8 * j][i];
                dot[j] += zv.x * cv.x + zv.y * cv.y + zv.z * cv.z + zv.w * cv.w;
            }
        }
        #pragma unroll
        for (int j = 0; j < 8; ++j) {
            float dist = cbn_s[cs + 8 * j] - 2.0f * dot[j];
            if (dist < best) { best = dist; bi = c0 + cs + 8 * j; }  // visited in increasing c
        }
    }
    bval[tid] = best; bidx[tid] = bi;
    __syncthreads();
    if (cs == 0) {
        float bv = bval[tid]; int bix = bidx[tid];
        #pragma unroll
        for (int j = 1; j < 8; ++j) {
            float v = bval[tid + j]; int ix = bidx[tid + j];
            if (v < bv || (v == bv && ix < bix)) { bv = v; bix = ix; }
        }
        tok_s[r] = bix;
    }
    __syncthreads();
    int tok = tok_s[r];
    float part = 0;
    const float* cr = cb + (size_t)tok * DP + cs * 16;
    #pragma unroll
    for (int i = 0; i < 16; i += 4) {
        float4 qv = *(const float4*)(cr + i);
        float4 zv = *(const float4*)&z_s[r][cs * 16 + i];
        float dx = qv.x - zv.x, dy = qv.y - zv.y, dz = qv.z - zv.z, dw = qv.w - zv.w;
        part += dx * dx + dy * dy + dz * dz + dw * dw;
        *(float4*)&zq[((size_t)(r0 + r)) * DP + cs * 16 + i] = qv;
    }
    psum[tid] = part;
    __syncthreads();
    if (cs == 0) {
        float s = 0;
        #pragma unroll
        for (int j = 0; j < 8; ++j) s += psum[tid + j];
        vqs[r0 + r] = s;
    }
}

__global__ void vqreduce_k(const float* __restrict__ vqs, float* __restrict__ out) {
    float s = 0;
    for (int i = threadIdx.x; i < BATCH * SS; i += 256) s += vqs[i];
    __shared__ float sm[4];
    s = block_sum_256(s, sm);
    if (threadIdx.x == 0) out[0] = s * (1.25f / (float)(BATCH * SS * DP));
}

// ---------- generic fp32 GEMM: C = [res +] act( A(MxK) @ W(NxK)^T + bias ) ----------
template <int ACT, int RES>
__global__ __launch_bounds__(256) void gemm_k(const float* __restrict__ A,
                                              const float* __restrict__ W,
                                              const float* __restrict__ bias,
                                              const float* __restrict__ res,
                                              float* __restrict__ C,
                                              int M, int N, int K) {
    __shared__ float As[16][65];
    __shared__ float Bs[16][65];
    const int bm = blockIdx.y * 64, bn = blockIdx.x * 64;
    const int tid = threadIdx.x;
    const int tx = tid & 15, ty = tid >> 4;
    float acc[4][4] = {};
    const int lr = tid >> 2;
    const int lc = (tid & 3) * 4;
    for (int k0 = 0; k0 < K; k0 += 16) {
        float4 av = *(const float4*)&A[(size_t)(bm + lr) * K + k0 + lc];
        As[lc + 0][lr] = av.x; As[lc + 1][lr] = av.y; As[lc + 2][lr] = av.z; As[lc + 3][lr] = av.w;
        float4 wv = *(const float4*)&W[(size_t)(bn + lr) * K + k0 + lc];
        Bs[lc + 0][lr] = wv.x; Bs[lc + 1][lr] = wv.y; Bs[lc + 2][lr] = wv.z; Bs[lc + 3][lr] = wv.w;
        __syncthreads();
        #pragma unroll
        for (int kk = 0; kk < 16; ++kk) {
            float a[4], bv[4];
            #pragma unroll
            for (int i = 0; i < 4; ++i) a[i] = As[kk][ty * 4 + i];
            #pragma unroll
            for (int j = 0; j < 4; ++j) bv[j] = Bs[kk][tx * 4 + j];
            #pragma unroll
            for (int i = 0; i < 4; ++i)
                #pragma unroll
                for (int j = 0; j < 4; ++j) acc[i][j] = fmaf(a[i], bv[j], acc[i][j]);
        }
        __syncthreads();
    }
    #pragma unroll
    for (int i = 0; i < 4; ++i) {
        int m = bm + ty * 4 + i;
        #pragma unroll
        for (int j = 0; j < 4; ++j) {
            int n = bn + tx * 4 + j;
            float t = acc[i][j] + bias[n];
            if (ACT == 1) t = gelu_f(t);
            if (RES == 1) t += res[(size_t)m * N + n];
            C[(size_t)m * N + n] = t;
        }
    }
}

// ---------- GEMM with W in (K,N) layout: C = act( A(MxK) @ W(KxN) + bias ) ----------
template <int ACT>
__global__ __launch_bounds__(256) void gemm_wk_k(const float* __restrict__ A,
                                                 const float* __restrict__ W,
                                                 const float* __restrict__ bias,
                                                 float* __restrict__ C,
                                                 int M, int N, int K) {
    __shared__ float As[16][65];
    __shared__ float Bs[16][65];
    const int bm = blockIdx.y * 64, bn = blockIdx.x * 64;
    const int tid = threadIdx.x;
    const int tx = tid & 15, ty = tid >> 4;
    float acc[4][4] = {};
    const int lr = tid >> 2;
    const int lc = (tid & 3) * 4;
    const int br = tid >> 4, bc = (tid & 15) * 4;
    for (int k0 = 0; k0 < K; k0 += 16) {
        float4 av = *(const float4*)&A[(size_t)(bm + lr) * K + k0 + lc];
        As[lc + 0][lr] = av.x; As[lc + 1][lr] = av.y; As[lc + 2][lr] = av.z; As[lc + 3][lr] = av.w;
        float4 wv = *(const float4*)&W[(size_t)(k0 + br) * N + bn + bc];
        Bs[br][bc + 0] = wv.x; Bs[br][bc + 1] = wv.y; Bs[br][bc + 2] = wv.z; Bs[br][bc + 3] = wv.w;
        __syncthreads();
        #pragma unroll
        for (int kk = 0; kk < 16; ++kk) {
            float a[4], bv[4];
            #pragma unroll
            for (int i = 0; i < 4; ++i) a[i] = As[kk][ty * 4 + i];
            #pragma unroll
            for (int j = 0; j < 4; ++j) bv[j] = Bs[kk][tx * 4 + j];
            #pragma unroll
            for (int i = 0; i < 4; ++i)
                #pragma unroll
                for (int j = 0; j < 4; ++j) acc[i][j] = fmaf(a[i], bv[j], acc[i][j]);
        }
        __syncthreads();
    }
    #pragma unroll
    for (int i = 0; i < 4; ++i) {
        int m = bm + ty * 4 + i;
        #pragma unroll
        for (int j = 0; j < 4; ++j) {
            int n = bn + tx * 4 + j;
            float t = acc[i][j] + bias[n];
            if (ACT == 1) t = gelu_f(t);
            C[(size_t)m * N + n] = t;
        }
    }
}

// ---------- LayerNorm over 256 (one row per block) ----------
__global__ __launch_bounds__(256) void ln_k(const float* __restrict__ in,
                                            const float* __restrict__ g,
                                            const float* __restrict__ bb,
                                            float* __restrict__ out) {
    int row = blockIdx.x, tid = threadIdx.x;
    __shared__ float sm[4];
    float v = in[(size_t)row * DM + tid];
    float mean = block_sum_256(v, sm) * (1.0f / DM);
    float d = v - mean;
    float var = block_sum_256(d * d, sm) * (1.0f / DM);
    out[(size_t)row * DM + tid] = d * rsqrtf(var + 1e-5f) * g[tid] + bb[tid];
}

// ---------- attention: one block per (4 q rows, h, b) ----------
__global__ __launch_bounds__(128) void attn_k(const float* __restrict__ qkv,
                                              const float* __restrict__ slopes,
                                              float* __restrict__ out) {
    const int q0 = blockIdx.x * 4, hh = blockIdx.y, b = blockIdx.z;
    const int tid = threadIdx.x;
    __shared__ __align__(16) float qrow[4][HD];
    __shared__ float ls[4][SS];
    const float slope = fabsf(slopes[hh]);
    const float* base = qkv + (size_t)b * SS * (3 * DM);
    {
        int qi = tid >> 5, d = tid & 31;
        qrow[qi][d] = base[(size_t)(q0 + qi) * (3 * DM) + hh * HD + d];
    }
    __syncthreads();
    for (int k = tid; k < SS; k += 128) {
        const float* kr = base + (size_t)k * (3 * DM) + DM + hh * HD;
        float4 kv[8];
        #pragma unroll
        for (int i = 0; i < 8; ++i) kv[i] = *(const float4*)(kr + 4 * i);
        #pragma unroll
        for (int qi = 0; qi < 4; ++qi) {
            float dd = 0;
            #pragma unroll
            for (int i = 0; i < 8; ++i) {
                float4 qv = *(const float4*)&qrow[qi][4 * i];
                dd += qv.x * kv[i].x + qv.y * kv[i].y + qv.z * kv[i].z + qv.w * kv[i].w;
            }
            ls[qi][k] = dd * 0.17677669529663687f - slope * fabsf((float)(q0 + qi - k));
        }
    }
    __syncthreads();
    const int qi = tid >> 5, lk = tid & 31;
    float m = -1e30f;
    for (int k = lk; k < SS; k += 32) m = fmaxf(m, ls[qi][k]);
    #pragma unroll
    for (int o = 16; o > 0; o >>= 1) m = fmaxf(m, __shfl_down(m, o, 32));
    m = __shfl(m, 0, 32);
    float ssum = 0;
    for (int k = lk; k < SS; k += 32) { float e = __expf(ls[qi][k] - m); ls[qi][k] = e; ssum += e; }
    #pragma unroll
    for (int o = 16; o > 0; o >>= 1) ssum += __shfl_down(ssum, o, 32);
    float inv = 1.0f / __shfl(ssum, 0, 32);
    const float* vbase = base + 2 * DM + hh * HD + lk;
    float acc = 0;
    for (int k = 0; k < SS; ++k) acc += ls[qi][k] * vbase[(size_t)k * (3 * DM)];
    out[((size_t)(b * SS + q0 + qi)) * DM + hh * HD + lk] = acc * inv;
}

// ---------- final: d2 conv + r4 1x1 conv + alpha blend, out (B,T,LEADS) ----------
__global__ __launch_bounds__(256) void final2_k(const float* __restrict__ ud1,
                                                const float* __restrict__ r3i,
                                                const float* __restrict__ d2w,
                                                const float* __restrict__ d2b,
                                                const float* __restrict__ r4w,
                                                const float* __restrict__ r4b,
                                                const float* __restrict__ alpha,
                                                float* __restrict__ out) {
    __shared__ float u_s[64][66];
    __shared__ float r_s[64][64];
    __shared__ float wd_s[64][3][12];
    __shared__ float wr_s[64][12];
    __shared__ float o_s[64][12];
    const int b = blockIdx.z, t0 = blockIdx.x * 64, tid = threadIdx.x;
    for (int idx = tid; idx < 64 * 66; idx += 256) {
        int ci = idx / 66, j = idx - ci * 66;
        int t = t0 + j - 1;
        u_s[ci][j] = (t >= 0 && t < TLEN) ? ud1[((size_t)(b * 64 + ci)) * TLEN + t] : 0.f;
    }
    for (int idx = tid; idx < 64 * 64; idx += 256) {
        int ci = idx >> 6, j = idx & 63;
        int t = t0 + j;
        r_s[ci][j] = (t < TLEN) ? r3i[((size_t)(b * 64 + ci)) * TLEN + t] : 0.f;
    }
    for (int idx = tid; idx < 64 * 3 * 12; idx += 256) {
        int l = idx % 12, k = (idx / 12) % 3, ci = idx / 36;
        wd_s[ci][k][l] = d2w[(l * 64 + ci) * 3 + k];
    }
    for (int idx = tid; idx < 64 * 12; idx += 256) {
        int l = idx % 12, ci = idx / 12;
        wr_s[ci][l] = r4w[l * 64 + ci];
    }
    __syncthreads();
    const int tl = tid & 63, lg = tid >> 6;  // l = lg*3 + c, lg<4 -> 12 leads
    float accD[3] = {}, accR[3] = {};
    for (int ci = 0; ci < 64; ++ci) {
        float u0 = u_s[ci][tl], u1 = u_s[ci][tl + 1], u2 = u_s[ci][tl + 2];
        float rv = r_s[ci][tl];
        #pragma unroll
        for (int c = 0; c < 3; ++c) {
            int l = lg * 3 + c;
            accD[c] += u0 * wd_s[ci][0][l] + u1 * wd_s[ci][1][l] + u2 * wd_s[ci][2][l];
            accR[c] = fmaf(rv, wr_s[ci][l], accR[c]);
        }
    }
    float al = alpha[0];
    #pragma unroll
    for (int c = 0; c < 3; ++c) {
        int l = lg * 3 + c;
        o_s[tl][l] = accD[c] + d2b[l] + al * (accR[c] + r4b[l]);
    }
    __syncthreads();
    for (int idx = tid; idx < 64 * 12; idx += 256) {
        int t = t0 + idx / 12;
        if (t < TLEN) out[((size_t)b * TLEN + t) * 12 + idx % 12] = o_s[idx / 12][idx % 12];
    }
}

extern "C" void kernel_launch(void* const* d_in, const int* in_sizes, int n_in,
                              void* d_out, int out_size, void* d_ws, size_t ws_size,
                              hipStream_t stream) {
    const float* x     = (const float*)d_in[0];
    const float* pe_w1 = (const float*)d_in[1];
    const float* pe_b1 = (const float*)d_in[2];
    const float* pe_w2 = (const float*)d_in[3];
    const float* pe_b2 = (const float*)d_in[4];
    const float* pe_pw = (const float*)d_in[5];
    const float* pe_pb = (const float*)d_in[6];
    const float* pe_g  = (const float*)d_in[7];
    const float* pe_bb = (const float*)d_in[8];
    const float* cb    = (const float*)d_in[9];
    const float* tp_w  = (const float*)d_in[10];
    const float* tp_b  = (const float*)d_in[11];
    const float* tp_g  = (const float*)d_in[12];
    const float* tp_bb = (const float*)d_in[13];
    const float* ln1_g = (const float*)d_in[14];
    const float* ln1_b = (const float*)d_in[15];
    const float* inw   = (const float*)d_in[16];
    const float* inb   = (const float*)d_in[17];
    const float* ow    = (const float*)d_in[18];
    const float* ob    = (const float*)d_in[19];
    const float* ln2_g = (const float*)d_in[20];
    const float* ln2_b = (const float*)d_in[21];
    const float* f1w   = (const float*)d_in[22];
    const float* f1b   = (const float*)d_in[23];
    const float* f2w   = (const float*)d_in[24];
    const float* f2b   = (const float*)d_in[25];
    const float* slopes= (const float*)d_in[26];
    const float* fn_g  = (const float*)d_in[27];
    const float* fn_b  = (const float*)d_in[28];
    const float* up_w  = (const float*)d_in[29];
    const float* up_b  = (const float*)d_in[30];
    const float* d1w   = (const float*)d_in[31];
    const float* d1b   = (const float*)d_in[32];
    const float* d2w   = (const float*)d_in[33];
    const float* d2b   = (const float*)d_in[34];
    const float* r1w   = (const float*)d_in[35];
    const float* r1b   = (const float*)d_in[36];
    const float* r2w   = (const float*)d_in[37];
    const float* r2b   = (const float*)d_in[38];
    const float* r3w   = (const float*)d_in[39];
    const float* r3b   = (const float*)d_in[40];
    const float* r4w   = (const float*)d_in[41];
    const float* r4b   = (const float*)d_in[42];
    const float* alpha = (const float*)d_in[43];

    float* W = (float*)d_ws;
    size_t off = 0;
    auto alloc = [&](size_t n) { float* p = W + off; off += n; return p; };
    float* A   = alloc((size_t)BATCH * DP * TLEN);        // h2 / u(patch-major)
    float* Bb  = alloc((size_t)BATCH * 64 * TLEN);        // h1 / ud1
    float* Cc  = alloc((size_t)BATCH * 64 * TLEN);        // r1 / r3
    float* Dd  = alloc((size_t)BATCH * 64 * TLEN);        // r2
    float* ze  = alloc((size_t)BATCH * SS * DP);
    float* zqb = alloc((size_t)BATCH * SS * DP);
    float* tx  = alloc((size_t)BATCH * SS * DM);          // tpre/xn/hfin
    float* hb  = alloc((size_t)BATCH * SS * DM);          // h
    float* qf  = alloc((size_t)BATCH * SS * 4 * DM);      // qkv / ffn1
    float* ao  = alloc((size_t)BATCH * SS * DM);          // attn out
    float* cbn = alloc(VV);
    float* vqs = alloc((size_t)BATCH * SS);
    if (off * sizeof(float) > ws_size) return;

    float* outp = (float*)d_out;
    const dim3 cgrid(57, 1, BATCH);   // ceil(3600/64)=57

    // --- encoder ---
    convg_k<12, 3, 1, 1><<<cgrid, 256, 0, stream>>>(x, pe_w1, pe_b1, Bb, 64, 1);
    convg_k<64, 3, 0, 1><<<dim3(57, 2, BATCH), 256, 0, stream>>>(Bb, pe_w2, pe_b2, A, 128, 1);
    cbnorm_k<<<2, 256, 0, stream>>>(cb, cbn);
    patchln_k<<<dim3(SS, BATCH), 128, 0, stream>>>(A, pe_pw, pe_pb, pe_g, pe_bb, ze);
    vq2_k<<<BATCH * SS / 32, 256, 0, stream>>>(ze, cb, cbn, zqb, vqs);
    vqreduce_k<<<1, 256, 0, stream>>>(vqs, outp + (size_t)BATCH * TLEN * LEADS);

    // --- token projection + LN ---
    gemm_k<0, 0><<<dim3(DM / 64, BATCH * SS / 64), 256, 0, stream>>>(zqb, tp_w, tp_b, nullptr, tx, BATCH * SS, DM, DP);
    ln_k<<<BATCH * SS, 256, 0, stream>>>(tx, tp_g, tp_bb, hb);

    // --- transformer ---
    for (int l = 0; l < NLAY; ++l) {
        ln_k<<<BATCH * SS, 256, 0, stream>>>(hb, ln1_g + l * DM, ln1_b + l * DM, tx);
        gemm_k<0, 0><<<dim3(3 * DM / 64, BATCH * SS / 64), 256, 0, stream>>>(
            tx, inw + (size_t)l * 3 * DM * DM, inb + l * 3 * DM, nullptr, qf, BATCH * SS, 3 * DM, DM);
        attn_k<<<dim3(SS / 4, NH, BATCH), 128, 0, stream>>>(qf, slopes + l * NH, ao);
        gemm_k<0, 1><<<dim3(DM / 64, BATCH * SS / 64), 256, 0, stream>>>(
            ao, ow + (size_t)l * DM * DM, ob + l * DM, hb, hb, BATCH * SS, DM, DM);
        ln_k<<<BATCH * SS, 256, 0, stream>>>(hb, ln2_g + l * DM, ln2_b + l * DM, tx);
        gemm_k<1, 0><<<dim3(4 * DM / 64, BATCH * SS / 64), 256, 0, stream>>>(
            tx, f1w + (size_t)l * 4 * DM * DM, f1b + l * 4 * DM, nullptr, qf, BATCH * SS, 4 * DM, DM);
        gemm_k<0, 1><<<dim3(DM / 64, BATCH * SS / 64), 256, 0, stream>>>(
            qf, f2w + (size_t)l * DM * 4 * DM, f2b + l * DM, hb, hb, BATCH * SS, DM, 4 * DM);
    }
    ln_k<<<BATCH * SS, 256, 0, stream>>>(hb, fn_g, fn_b, tx);

    // --- decoder: upproj GEMM (W is (K=256, N=1152)) -> u in patch-major layout ---
    gemm_wk_k<1><<<dim3(1152 / 64, BATCH * SS / 64), 256, 0, stream>>>(tx, up_w, up_b, A, BATCH * SS, 1152, DM);
    convg_k<128, 5, 2, 1><<<cgrid, 256, 0, stream>>>(A, d1w, d1b, Bb, 64, 2);

    // --- residual CNN ---
    convg_k<12, 7, 1, 1><<<cgrid, 256, 0, stream>>>(x, r1w, r1b, Cc, 64, 3);
    convg_k<64, 5, 0, 1><<<cgrid, 256, 0, stream>>>(Cc, r2w, r2b, Dd, 64, 2);
    convg_k<64, 3, 0, 1><<<cgrid, 256, 0, stream>>>(Dd, r3w, r3b, Cc, 64, 1);

    // --- fused d2 conv + r4 conv + alpha blend ---
    final2_k<<<cgrid, 256, 0, stream>>>(Bb, Cc, d2w, d2b, r4w, r4b, alpha, outp);
}

// Round 3
// 2346.758 us; speedup vs baseline: 3.2553x; 1.6644x over previous
//
#include <hip/hip_runtime.h>
#include <hip/hip_bf16.h>
#include <math.h>

#define BATCH 16
#define TLEN 3600
#define LEADS 12
#define PP 9
#define SS 400
#define DP 128
#define DM 256
#define NH 8
#define HD 32
#define NLAY 6
#define VV 512
#define RH 64

typedef __attribute__((ext_vector_type(8))) short short8b;
typedef __attribute__((ext_vector_type(4))) float f32x4;

__device__ __forceinline__ float gelu_f(float x) {
    return 0.5f * x * (1.0f + erff(x * 0.70710678118654752f));
}

__device__ __forceinline__ unsigned short f2bf(float f) {
    union { float f; unsigned u; } v; v.f = f;
    return (unsigned short)((v.u + 0x7FFFu + ((v.u >> 16) & 1u)) >> 16);
}

// ---------- block reduction helpers ----------
__device__ __forceinline__ float block_sum_256(float v, float* sm) {
    #pragma unroll
    for (int o = 32; o > 0; o >>= 1) v += __shfl_down(v, o);
    __syncthreads();
    if ((threadIdx.x & 63) == 0) sm[threadIdx.x >> 6] = v;
    __syncthreads();
    return sm[0] + sm[1] + sm[2] + sm[3];
}

__device__ __forceinline__ float block_sum_128(float v, float* sm) {
    #pragma unroll
    for (int o = 32; o > 0; o >>= 1) v += __shfl_down(v, o);
    __syncthreads();
    if ((threadIdx.x & 63) == 0) sm[threadIdx.x >> 6] = v;
    __syncthreads();
    return sm[0] + sm[1];
}

// ---------- generic LDS-staged implicit-GEMM conv ----------
// LAYOUT 0: in(B,CI,T). LAYOUT 1: in(B,T,CI). LAYOUT 2: in(B,S,CI*9) patch-major.
// OL 0: out(B,Co,T). OL 1: out(B,S,Co*9) patch-major.
template <int CI, int K, int LAYOUT, int ACT, int OL>
__global__ __launch_bounds__(256) void convg_k(const float* __restrict__ in,
                                               const float* __restrict__ w,
                                               const float* __restrict__ bias,
                                               float* __restrict__ out,
                                               int Co, int pad) {
    constexpr int CHUNK = (CI % 16 == 0) ? 16 : CI;
    constexpr int TT = 64 + K - 1;
    constexpr int NV = (K + 6) / 4;
    constexpr int TTP = 64 + 4 * NV;
    __shared__ __align__(16) float in_s[CHUNK][TTP];
    __shared__ __align__(16) float w_s[CHUNK][K][64];
    const int b = blockIdx.z;
    const int co0 = blockIdx.y * 64;
    const int t0 = blockIdx.x * 64;
    const int tid = threadIdx.x;
    const int tx = tid & 15, ty = tid >> 4;
    float acc[4][4] = {};
    for (int c0 = 0; c0 < CI; c0 += CHUNK) {
        __syncthreads();
        for (int idx = tid; idx < CHUNK * TT; idx += 256) {
            int ci = idx / TT, j = idx - ci * TT;
            int t = t0 + j - pad;
            float v = 0.f;
            if (t >= 0 && t < TLEN) {
                if (LAYOUT == 0) v = in[((size_t)(b * CI + c0 + ci)) * TLEN + t];
                else if (LAYOUT == 1) v = in[((size_t)b * TLEN + t) * CI + (c0 + ci)];
                else { int s = t / PP, k = t - s * PP;
                       v = in[((size_t)(b * SS + s)) * (CI * PP) + (c0 + ci) * PP + k]; }
            }
            in_s[ci][j] = v;
        }
        for (int idx = tid; idx < CHUNK * K * 64; idx += 256) {
            int co = idx & 63; int rest = idx >> 6; int k = rest % K; int ci = rest / K;
            w_s[ci][k][co] = w[((size_t)(co0 + co) * CI + (c0 + ci)) * K + k];
        }
        __syncthreads();
        #pragma unroll
        for (int ci = 0; ci < CHUNK; ++ci) {
            float tv[NV * 4];
            #pragma unroll
            for (int vv = 0; vv < NV; ++vv)
                *(float4*)&tv[vv * 4] = *(const float4*)&in_s[ci][tx * 4 + vv * 4];
            #pragma unroll
            for (int k = 0; k < K; ++k) {
                float4 wv = *(const float4*)&w_s[ci][k][ty * 4];
                #pragma unroll
                for (int j = 0; j < 4; ++j) {
                    float iv = tv[j + k];
                    acc[0][j] = fmaf(wv.x, iv, acc[0][j]);
                    acc[1][j] = fmaf(wv.y, iv, acc[1][j]);
                    acc[2][j] = fmaf(wv.z, iv, acc[2][j]);
                    acc[3][j] = fmaf(wv.w, iv, acc[3][j]);
                }
            }
        }
    }
    if (OL == 0) {
        const bool full = (t0 + 64 <= TLEN);
        #pragma unroll
        for (int i = 0; i < 4; ++i) {
            int co = co0 + ty * 4 + i;
            float bs = bias[co];
            float* orow = out + ((size_t)(b * Co + co)) * TLEN;
            if (full) {
                float4 o4;
                float vv0 = acc[i][0] + bs, vv1 = acc[i][1] + bs, vv2 = acc[i][2] + bs, vv3 = acc[i][3] + bs;
                if (ACT) { vv0 = gelu_f(vv0); vv1 = gelu_f(vv1); vv2 = gelu_f(vv2); vv3 = gelu_f(vv3); }
                o4.x = vv0; o4.y = vv1; o4.z = vv2; o4.w = vv3;
                *(float4*)&orow[t0 + tx * 4] = o4;
            } else {
                #pragma unroll
                for (int j = 0; j < 4; ++j) {
                    int t = t0 + tx * 4 + j;
                    if (t < TLEN) {
                        float v = acc[i][j] + bs;
                        if (ACT) v = gelu_f(v);
                        orow[t] = v;
                    }
                }
            }
        }
    } else {
        #pragma unroll
        for (int i = 0; i < 4; ++i) {
            int co = co0 + ty * 4 + i;
            float bs = bias[co];
            #pragma unroll
            for (int j = 0; j < 4; ++j) {
                int t = t0 + tx * 4 + j;
                if (t < TLEN) {
                    float v = acc[i][j] + bs;
                    if (ACT) v = gelu_f(v);
                    int s = t / PP, kk = t - s * PP;
                    out[((size_t)(b * SS + s)) * (size_t)(Co * PP) + co * PP + kk] = v;
                }
            }
        }
    }
}

// ---------- fp32 GEMM (used for patch projection only) ----------
template <int ACT, int RES>
__global__ __launch_bounds__(256) void gemm_k(const float* __restrict__ A,
                                              const float* __restrict__ W,
                                              const float* __restrict__ bias,
                                              const float* __restrict__ res,
                                              float* __restrict__ C,
                                              int M, int N, int K) {
    __shared__ float As[16][65];
    __shared__ float Bs[16][65];
    const int bm = blockIdx.y * 64, bn = blockIdx.x * 64;
    const int tid = threadIdx.x;
    const int tx = tid & 15, ty = tid >> 4;
    float acc[4][4] = {};
    const int lr = tid >> 2;
    const int lc = (tid & 3) * 4;
    for (int k0 = 0; k0 < K; k0 += 16) {
        float4 av = *(const float4*)&A[(size_t)(bm + lr) * K + k0 + lc];
        As[lc + 0][lr] = av.x; As[lc + 1][lr] = av.y; As[lc + 2][lr] = av.z; As[lc + 3][lr] = av.w;
        float4 wv = *(const float4*)&W[(size_t)(bn + lr) * K + k0 + lc];
        Bs[lc + 0][lr] = wv.x; Bs[lc + 1][lr] = wv.y; Bs[lc + 2][lr] = wv.z; Bs[lc + 3][lr] = wv.w;
        __syncthreads();
        #pragma unroll
        for (int kk = 0; kk < 16; ++kk) {
            float a[4], bv[4];
            #pragma unroll
            for (int i = 0; i < 4; ++i) a[i] = As[kk][ty * 4 + i];
            #pragma unroll
            for (int j = 0; j < 4; ++j) bv[j] = Bs[kk][tx * 4 + j];
            #pragma unroll
            for (int i = 0; i < 4; ++i)
                #pragma unroll
                for (int j = 0; j < 4; ++j) acc[i][j] = fmaf(a[i], bv[j], acc[i][j]);
        }
        __syncthreads();
    }
    #pragma unroll
    for (int i = 0; i < 4; ++i) {
        int m = bm + ty * 4 + i;
        #pragma unroll
        for (int j = 0; j < 4; ++j) {
            int n = bn + tx * 4 + j;
            float t = acc[i][j] + bias[n];
            if (ACT == 1) t = gelu_f(t);
            if (RES == 1) t += res[(size_t)m * N + n];
            C[(size_t)m * N + n] = t;
        }
    }
}

// ---------- bf16 MFMA GEMM: C = [res +] act( A(MxK)bf16 @ W(NxK)^T bf16 + bias ) ----------
// 128x128 tile, 4 waves (2x2), each wave 64x64 via 4x4 frags of 16x16x32.
template <int ACT, int RES, int OUTBF>
__global__ __launch_bounds__(256) void bgemm_k(const unsigned short* __restrict__ A,
                                               const unsigned short* __restrict__ W,
                                               const float* __restrict__ bias,
                                               const float* __restrict__ res,
                                               void* __restrict__ Cv,
                                               int M, int N, int K) {
    __shared__ __align__(16) unsigned short As[128][40];
    __shared__ __align__(16) unsigned short Bs[128][40];
    const int tid = threadIdx.x;
    const int gm0 = blockIdx.y * 128, gn0 = blockIdx.x * 128;
    const int w = tid >> 6, lane = tid & 63;
    const int wr0 = (w >> 1) * 64, wc0 = (w & 1) * 64;
    const int srow = tid >> 1, sc = (tid & 1) * 16;
    const unsigned short* ga = A + (size_t)(gm0 + srow) * K + sc;
    const unsigned short* gb = W + (size_t)(gn0 + srow) * K + sc;
    short8b ra0 = *(const short8b*)(ga), ra1 = *(const short8b*)(ga + 8);
    short8b rb0 = *(const short8b*)(gb), rb1 = *(const short8b*)(gb + 8);
    f32x4 acc[4][4];
    #pragma unroll
    for (int i = 0; i < 4; ++i)
        #pragma unroll
        for (int j = 0; j < 4; ++j) acc[i][j] = (f32x4){0.f, 0.f, 0.f, 0.f};
    const int fr = lane & 15, kg = (lane >> 4) * 8;
    const int nstep = K >> 5;
    for (int s = 0; s < nstep; ++s) {
        __syncthreads();
        *(short8b*)&As[srow][sc] = ra0; *(short8b*)&As[srow][sc + 8] = ra1;
        *(short8b*)&Bs[srow][sc] = rb0; *(short8b*)&Bs[srow][sc + 8] = rb1;
        __syncthreads();
        if (s + 1 < nstep) {
            ga += 32; gb += 32;
            ra0 = *(const short8b*)(ga); ra1 = *(const short8b*)(ga + 8);
            rb0 = *(const short8b*)(gb); rb1 = *(const short8b*)(gb + 8);
        }
        short8b af[4], bf[4];
        #pragma unroll
        for (int i = 0; i < 4; ++i) {
            af[i] = *(const short8b*)&As[wr0 + i * 16 + fr][kg];
            bf[i] = *(const short8b*)&Bs[wc0 + i * 16 + fr][kg];
        }
        #pragma unroll
        for (int i = 0; i < 4; ++i)
            #pragma unroll
            for (int j = 0; j < 4; ++j)
                acc[i][j] = __builtin_amdgcn_mfma_f32_16x16x32_bf16(af[i], bf[j], acc[i][j], 0, 0, 0);
    }
    const int orow = (lane >> 4) * 4, ocol = lane & 15;
    #pragma unroll
    for (int i = 0; i < 4; ++i) {
        #pragma unroll
        for (int j = 0; j < 4; ++j) {
            const int colg = gn0 + wc0 + j * 16 + ocol;
            const float bsv = bias[colg];
            #pragma unroll
            for (int r = 0; r < 4; ++r) {
                const int rowg = gm0 + wr0 + i * 16 + orow + r;
                float v = acc[i][j][r] + bsv;
                if (ACT) v = gelu_f(v);
                if (RES) v += res[(size_t)rowg * N + colg];
                if (OUTBF) ((unsigned short*)Cv)[(size_t)rowg * N + colg] = f2bf(v);
                else ((float*)Cv)[(size_t)rowg * N + colg] = v;
            }
        }
    }
}

// ---------- weight fp32 -> bf16 ----------
__global__ void tobf_k(const float* __restrict__ in, unsigned short* __restrict__ out, int n) {
    int i = blockIdx.x * 256 + threadIdx.x;
    if (i < n) out[i] = f2bf(in[i]);
}

// up_w (K=256, N=1152) -> bf16 (N=1152, K=256)
__global__ void upwt_k(const float* __restrict__ in, unsigned short* __restrict__ out) {
    int idx = blockIdx.x * 256 + threadIdx.x;
    if (idx < 1152 * 256) {
        int d = idx & 255, n = idx >> 8;
        out[idx] = f2bf(in[(size_t)d * 1152 + n]);
    }
}

// ---------- LayerNorm over 128 ----------
__global__ __launch_bounds__(128) void ln128_k(const float* __restrict__ in,
                                               const float* __restrict__ g,
                                               const float* __restrict__ bb,
                                               float* __restrict__ out) {
    int row = blockIdx.x, tid = threadIdx.x;
    __shared__ float sm[2];
    float v = in[(size_t)row * DP + tid];
    float mean = block_sum_128(v, sm) * (1.0f / DP);
    float d = v - mean;
    float var = block_sum_128(d * d, sm) * (1.0f / DP);
    out[(size_t)row * DP + tid] = d * rsqrtf(var + 1e-5f) * g[tid] + bb[tid];
}

// ---------- codebook norms ----------
__global__ void cbnorm_k(const float* __restrict__ cb, float* __restrict__ cbn) {
    int c = blockIdx.x * 256 + threadIdx.x;
    if (c < VV) {
        const float* cr = cb + (size_t)c * DP;
        float s = 0;
        for (int i = 0; i < DP; ++i) s += cr[i] * cr[i];
        cbn[c] = s;
    }
}

// ---------- VQ: tiled distance GEMM + argmin + commit partials; zq written as bf16 ----------
__global__ __launch_bounds__(256) void vq2_k(const float* __restrict__ ze,
                                             const float* __restrict__ cb,
                                             const float* __restrict__ cbn,
                                             unsigned short* __restrict__ zqb,
                                             float* __restrict__ vqs) {
    __shared__ __align__(16) float z_s[32][132];
    __shared__ __align__(16) float cb_s[64][132];
    __shared__ float cbn_s[64];
    __shared__ float bval[256];
    __shared__ int bidx[256];
    __shared__ int tok_s[32];
    __shared__ float psum[256];
    const int tid = threadIdx.x;
    const int r0 = blockIdx.x * 32;
    const int r = tid >> 3, cs = tid & 7;
    for (int idx = tid; idx < 32 * 128; idx += 256) {
        int rr = idx >> 7, cc = idx & 127;
        z_s[rr][cc] = ze[((size_t)(r0 + rr)) * DP + cc];
    }
    float best = 1e30f; int bi = 0;
    for (int c0 = 0; c0 < VV; c0 += 64) {
        __syncthreads();
        for (int idx = tid; idx < 64 * 128; idx += 256) {
            int rr = idx >> 7, cc = idx & 127;
            cb_s[rr][cc] = cb[((size_t)(c0 + rr)) * DP + cc];
        }
        if (tid < 64) cbn_s[tid] = cbn[c0 + tid];
        __syncthreads();
        float dot[8] = {};
        for (int i = 0; i < 128; i += 4) {
            float4 zv = *(const float4*)&z_s[r][i];
            #pragma unroll
            for (int j = 0; j < 8; ++j) {
                float4 cv = *(const float4*)&cb_s[cs + 8 * j][i];
                dot[j] += zv.x * cv.x + zv.y * cv.y + zv.z * cv.z + zv.w * cv.w;
            }
        }
        #pragma unroll
        for (int j = 0; j < 8; ++j) {
            float dist = cbn_s[cs + 8 * j] - 2.0f * dot[j];
            if (dist < best) { best = dist; bi = c0 + cs + 8 * j; }
        }
    }
    bval[tid] = best; bidx[tid] = bi;
    __syncthreads();
    if (cs == 0) {
        float bv = bval[tid]; int bix = bidx[tid];
        #pragma unroll
        for (int j = 1; j < 8; ++j) {
            float v = bval[tid + j]; int ix = bidx[tid + j];
            if (v < bv || (v == bv && ix < bix)) { bv = v; bix = ix; }
        }
        tok_s[r] = bix;
    }
    __syncthreads();
    int tok = tok_s[r];
    float part = 0;
    const float* cr = cb + (size_t)tok * DP + cs * 16;
    #pragma unroll
    for (int i = 0; i < 16; i += 4) {
        float4 qv = *(const float4*)(cr + i);
        float4 zv = *(const float4*)&z_s[r][cs * 16 + i];
        float dx = qv.x - zv.x, dy = qv.y - zv.y, dz = qv.z - zv.z, dw = qv.w - zv.w;
        part += dx * dx + dy * dy + dz * dz + dw * dw;
        size_t ob = ((size_t)(r0 + r)) * DP + cs * 16 + i;
        zqb[ob + 0] = f2bf(qv.x); zqb[ob + 1] = f2bf(qv.y);
        zqb[ob + 2] = f2bf(qv.z); zqb[ob + 3] = f2bf(qv.w);
    }
    psum[tid] = part;
    __syncthreads();
    if (cs == 0) {
        float s = 0;
        #pragma unroll
        for (int j = 0; j < 8; ++j) s += psum[tid + j];
        vqs[r0 + r] = s;
    }
}

__global__ void vqreduce_k(const float* __restrict__ vqs, float* __restrict__ out) {
    float s = 0;
    for (int i = threadIdx.x; i < BATCH * SS; i += 256) s += vqs[i];
    __shared__ float sm[4];
    s = block_sum_256(s, sm);
    if (threadIdx.x == 0) out[0] = s * (1.25f / (float)(BATCH * SS * DP));
}

// ---------- LayerNorm over 256; OUTBF selects fp32 or bf16 output ----------
template <int OUTBF>
__global__ __launch_bounds__(256) void ln_k(const float* __restrict__ in,
                                            const float* __restrict__ g,
                                            const float* __restrict__ bb,
                                            void* __restrict__ out) {
    int row = blockIdx.x, tid = threadIdx.x;
    __shared__ float sm[4];
    float v = in[(size_t)row * DM + tid];
    float mean = block_sum_256(v, sm) * (1.0f / DM);
    float d = v - mean;
    float var = block_sum_256(d * d, sm) * (1.0f / DM);
    float o = d * rsqrtf(var + 1e-5f) * g[tid] + bb[tid];
    if (OUTBF) ((unsigned short*)out)[(size_t)row * DM + tid] = f2bf(o);
    else ((float*)out)[(size_t)row * DM + tid] = o;
}

// ---------- attention: one block per (4 q rows, h, b); bf16 output ----------
__global__ __launch_bounds__(128) void attn_k(const float* __restrict__ qkv,
                                              const float* __restrict__ slopes,
                                              unsigned short* __restrict__ out) {
    const int q0 = blockIdx.x * 4, hh = blockIdx.y, b = blockIdx.z;
    const int tid = threadIdx.x;
    __shared__ __align__(16) float qrow[4][HD];
    __shared__ float ls[4][SS];
    const float slope = fabsf(slopes[hh]);
    const float* base = qkv + (size_t)b * SS * (3 * DM);
    {
        int qi = tid >> 5, d = tid & 31;
        qrow[qi][d] = base[(size_t)(q0 + qi) * (3 * DM) + hh * HD + d];
    }
    __syncthreads();
    for (int k = tid; k < SS; k += 128) {
        const float* kr = base + (size_t)k * (3 * DM) + DM + hh * HD;
        float4 kv[8];
        #pragma unroll
        for (int i = 0; i < 8; ++i) kv[i] = *(const float4*)(kr + 4 * i);
        #pragma unroll
        for (int qi = 0; qi < 4; ++qi) {
            float dd = 0;
            #pragma unroll
            for (int i = 0; i < 8; ++i) {
                float4 qv = *(const float4*)&qrow[qi][4 * i];
                dd += qv.x * kv[i].x + qv.y * kv[i].y + qv.z * kv[i].z + qv.w * kv[i].w;
            }
            ls[qi][k] = dd * 0.17677669529663687f - slope * fabsf((float)(q0 + qi - k));
        }
    }
    __syncthreads();
    const int qi = tid >> 5, lk = tid & 31;
    float m = -1e30f;
    for (int k = lk; k < SS; k += 32) m = fmaxf(m, ls[qi][k]);
    #pragma unroll
    for (int o = 16; o > 0; o >>= 1) m = fmaxf(m, __shfl_down(m, o, 32));
    m = __shfl(m, 0, 32);
    float ssum = 0;
    for (int k = lk; k < SS; k += 32) { float e = __expf(ls[qi][k] - m); ls[qi][k] = e; ssum += e; }
    #pragma unroll
    for (int o = 16; o > 0; o >>= 1) ssum += __shfl_down(ssum, o, 32);
    float inv = 1.0f / __shfl(ssum, 0, 32);
    const float* vbase = base + 2 * DM + hh * HD + lk;
    float acc = 0;
    for (int k = 0; k < SS; ++k) acc += ls[qi][k] * vbase[(size_t)k * (3 * DM)];
    out[((size_t)(b * SS + q0 + qi)) * DM + hh * HD + lk] = f2bf(acc * inv);
}

// ---------- final: d2 conv + r4 1x1 conv + alpha blend, out (B,T,LEADS) ----------
__global__ __launch_bounds__(256) void final2_k(const float* __restrict__ ud1,
                                                const float* __restrict__ r3i,
                                                const float* __restrict__ d2w,
                                                const float* __restrict__ d2b,
                                                const float* __restrict__ r4w,
                                                const float* __restrict__ r4b,
                                                const float* __restrict__ alpha,
                                                float* __restrict__ out) {
    __shared__ float u_s[64][66];
    __shared__ float r_s[64][64];
    __shared__ float wd_s[64][3][12];
    __shared__ float wr_s[64][12];
    __shared__ float o_s[64][12];
    const int b = blockIdx.z, t0 = blockIdx.x * 64, tid = threadIdx.x;
    for (int idx = tid; idx < 64 * 66; idx += 256) {
        int ci = idx / 66, j = idx - ci * 66;
        int t = t0 + j - 1;
        u_s[ci][j] = (t >= 0 && t < TLEN) ? ud1[((size_t)(b * 64 + ci)) * TLEN + t] : 0.f;
    }
    for (int idx = tid; idx < 64 * 64; idx += 256) {
        int ci = idx >> 6, j = idx & 63;
        int t = t0 + j;
        r_s[ci][j] = (t < TLEN) ? r3i[((size_t)(b * 64 + ci)) * TLEN + t] : 0.f;
    }
    for (int idx = tid; idx < 64 * 3 * 12; idx += 256) {
        int l = idx % 12, k = (idx / 12) % 3, ci = idx / 36;
        wd_s[ci][k][l] = d2w[(l * 64 + ci) * 3 + k];
    }
    for (int idx = tid; idx < 64 * 12; idx += 256) {
        int l = idx % 12, ci = idx / 12;
        wr_s[ci][l] = r4w[l * 64 + ci];
    }
    __syncthreads();
    const int tl = tid & 63, lg = tid >> 6;
    float accD[3] = {}, accR[3] = {};
    for (int ci = 0; ci < 64; ++ci) {
        float u0 = u_s[ci][tl], u1 = u_s[ci][tl + 1], u2 = u_s[ci][tl + 2];
        float rv = r_s[ci][tl];
        #pragma unroll
        for (int c = 0; c < 3; ++c) {
            int l = lg * 3 + c;
            accD[c] += u0 * wd_s[ci][0][l] + u1 * wd_s[ci][1][l] + u2 * wd_s[ci][2][l];
            accR[c] = fmaf(rv, wr_s[ci][l], accR[c]);
        }
    }
    float al = alpha[0];
    #pragma unroll
    for (int c = 0; c < 3; ++c) {
        int l = lg * 3 + c;
        o_s[tl][l] = accD[c] + d2b[l] + al * (accR[c] + r4b[l]);
    }
    __syncthreads();
    for (int idx = tid; idx < 64 * 12; idx += 256) {
        int t = t0 + idx / 12;
        if (t < TLEN) out[((size_t)b * TLEN + t) * 12 + idx % 12] = o_s[idx / 12][idx % 12];
    }
}

extern "C" void kernel_launch(void* const* d_in, const int* in_sizes, int n_in,
                              void* d_out, int out_size, void* d_ws, size_t ws_size,
                              hipStream_t stream) {
    const float* x     = (const float*)d_in[0];
    const float* pe_w1 = (const float*)d_in[1];
    const float* pe_b1 = (const float*)d_in[2];
    const float* pe_w2 = (const float*)d_in[3];
    const float* pe_b2 = (const float*)d_in[4];
    const float* pe_pw = (const float*)d_in[5];
    const float* pe_pb = (const float*)d_in[6];
    const float* pe_g  = (const float*)d_in[7];
    const float* pe_bb = (const float*)d_in[8];
    const float* cb    = (const float*)d_in[9];
    const float* tp_w  = (const float*)d_in[10];
    const float* tp_b  = (const float*)d_in[11];
    const float* tp_g  = (const float*)d_in[12];
    const float* tp_bb = (const float*)d_in[13];
    const float* ln1_g = (const float*)d_in[14];
    const float* ln1_b = (const float*)d_in[15];
    const float* inw   = (const float*)d_in[16];
    const float* inb   = (const float*)d_in[17];
    const float* ow    = (const float*)d_in[18];
    const float* ob    = (const float*)d_in[19];
    const float* ln2_g = (const float*)d_in[20];
    const float* ln2_b = (const float*)d_in[21];
    const float* f1w   = (const float*)d_in[22];
    const float* f1b   = (const float*)d_in[23];
    const float* f2w   = (const float*)d_in[24];
    const float* f2b   = (const float*)d_in[25];
    const float* slopes= (const float*)d_in[26];
    const float* fn_g  = (const float*)d_in[27];
    const float* fn_b  = (const float*)d_in[28];
    const float* up_w  = (const float*)d_in[29];
    const float* up_b  = (const float*)d_in[30];
    const float* d1w   = (const float*)d_in[31];
    const float* d1b   = (const float*)d_in[32];
    const float* d2w   = (const float*)d_in[33];
    const float* d2b   = (const float*)d_in[34];
    const float* r1w   = (const float*)d_in[35];
    const float* r1b   = (const float*)d_in[36];
    const float* r2w   = (const float*)d_in[37];
    const float* r2b   = (const float*)d_in[38];
    const float* r3w   = (const float*)d_in[39];
    const float* r3b   = (const float*)d_in[40];
    const float* r4w   = (const float*)d_in[41];
    const float* r4b   = (const float*)d_in[42];
    const float* alpha = (const float*)d_in[43];

    float* W = (float*)d_ws;
    size_t off = 0;
    auto alloc = [&](size_t n) { float* p = W + off; off += (n + 3) & ~(size_t)3; return p; };
    const size_t M = (size_t)BATCH * SS;  // 6400
    float* A   = alloc((size_t)BATCH * DP * TLEN);     // conv2 patch-major / upproj out
    float* Bb  = alloc((size_t)BATCH * 64 * TLEN);     // h1 / ud1
    float* Cc  = alloc((size_t)BATCH * 64 * TLEN);     // r1 / r3
    float* Dd  = alloc((size_t)BATCH * 64 * TLEN);     // r2
    float* ze  = alloc(M * DP);
    float* tx  = alloc(M * DM);                        // patch-gemm out / tokproj out
    float* hb  = alloc(M * DM);                        // residual stream
    float* qf  = alloc(M * 3 * DM);                    // qkv fp32 / ffn1 bf16 alias
    float* cbn = alloc(VV);
    float* vqs = alloc(M);
    unsigned short* zqb  = (unsigned short*)alloc(M * DP / 2);
    unsigned short* xnb  = (unsigned short*)alloc(M * DM / 2);
    unsigned short* aob  = (unsigned short*)alloc(M * DM / 2);
    unsigned short* ffb  = (unsigned short*)qf;        // alias (qkv dead when ffn1 runs)
    unsigned short* inwb = (unsigned short*)alloc((size_t)NLAY * 3 * DM * DM / 2);
    unsigned short* owb  = (unsigned short*)alloc((size_t)NLAY * DM * DM / 2);
    unsigned short* f1wb = (unsigned short*)alloc((size_t)NLAY * 4 * DM * DM / 2);
    unsigned short* f2wb = (unsigned short*)alloc((size_t)NLAY * 4 * DM * DM / 2);
    unsigned short* tpwb = (unsigned short*)alloc((size_t)DM * DP / 2);
    unsigned short* upwb = (unsigned short*)alloc((size_t)1152 * DM / 2);
    if (off * sizeof(float) > ws_size) return;

    float* outp = (float*)d_out;
    const dim3 cgrid(57, 1, BATCH);

    // --- weight conversions (bf16) ---
    tobf_k<<<(NLAY * 3 * DM * DM + 255) / 256, 256, 0, stream>>>(inw, inwb, NLAY * 3 * DM * DM);
    tobf_k<<<(NLAY * DM * DM + 255) / 256, 256, 0, stream>>>(ow, owb, NLAY * DM * DM);
    tobf_k<<<(NLAY * 4 * DM * DM + 255) / 256, 256, 0, stream>>>(f1w, f1wb, NLAY * 4 * DM * DM);
    tobf_k<<<(NLAY * 4 * DM * DM + 255) / 256, 256, 0, stream>>>(f2w, f2wb, NLAY * 4 * DM * DM);
    tobf_k<<<(DM * DP + 255) / 256, 256, 0, stream>>>(tp_w, tpwb, DM * DP);
    upwt_k<<<(1152 * 256 + 255) / 256, 256, 0, stream>>>(up_w, upwb);

    // --- encoder (fp32: protects VQ argmin) ---
    convg_k<12, 3, 1, 1, 0><<<cgrid, 256, 0, stream>>>(x, pe_w1, pe_b1, Bb, 64, 1);
    convg_k<64, 3, 0, 1, 1><<<dim3(57, 2, BATCH), 256, 0, stream>>>(Bb, pe_w2, pe_b2, A, 128, 1);
    cbnorm_k<<<2, 256, 0, stream>>>(cb, cbn);
    gemm_k<0, 0><<<dim3(2, M / 64), 256, 0, stream>>>(A, pe_pw, pe_pb, nullptr, tx, M, DP, DP * PP);
    ln128_k<<<M, 128, 0, stream>>>(tx, pe_g, pe_bb, ze);
    vq2_k<<<M / 32, 256, 0, stream>>>(ze, cb, cbn, zqb, vqs);
    vqreduce_k<<<1, 256, 0, stream>>>(vqs, outp + (size_t)BATCH * TLEN * LEADS);

    // --- token projection + LN ---
    bgemm_k<0, 0, 0><<<dim3(DM / 128, M / 128), 256, 0, stream>>>(zqb, tpwb, tp_b, nullptr, tx, M, DM, DP);
    ln_k<0><<<M, 256, 0, stream>>>(tx, tp_g, tp_bb, hb);

    // --- transformer (bf16 MFMA GEMMs, fp32 residual stream) ---
    for (int l = 0; l < NLAY; ++l) {
        ln_k<1><<<M, 256, 0, stream>>>(hb, ln1_g + l * DM, ln1_b + l * DM, xnb);
        bgemm_k<0, 0, 0><<<dim3(3 * DM / 128, M / 128), 256, 0, stream>>>(
            xnb, inwb + (size_t)l * 3 * DM * DM, inb + l * 3 * DM, nullptr, qf, M, 3 * DM, DM);
        attn_k<<<dim3(SS / 4, NH, BATCH), 128, 0, stream>>>(qf, slopes + l * NH, aob);
        bgemm_k<0, 1, 0><<<dim3(DM / 128, M / 128), 256, 0, stream>>>(
            aob, owb + (size_t)l * DM * DM, ob + l * DM, hb, hb, M, DM, DM);
        ln_k<1><<<M, 256, 0, stream>>>(hb, ln2_g + l * DM, ln2_b + l * DM, xnb);
        bgemm_k<1, 0, 1><<<dim3(4 * DM / 128, M / 128), 256, 0, stream>>>(
            xnb, f1wb + (size_t)l * 4 * DM * DM, f1b + l * 4 * DM, nullptr, ffb, M, 4 * DM, DM);
        bgemm_k<0, 1, 0><<<dim3(DM / 128, M / 128), 256, 0, stream>>>(
            ffb, f2wb + (size_t)l * 4 * DM * DM, f2b + l * DM, hb, hb, M, DM, 4 * DM);
    }
    ln_k<1><<<M, 256, 0, stream>>>(hb, fn_g, fn_b, xnb);

    // --- decoder: upproj bf16 GEMM -> patch-major fp32, then d1 conv ---
    bgemm_k<1, 0, 0><<<dim3(1152 / 128, M / 128), 256, 0, stream>>>(xnb, upwb, up_b, nullptr, A, M, 1152, DM);
    convg_k<128, 5, 2, 1, 0><<<cgrid, 256, 0, stream>>>(A, d1w, d1b, Bb, 64, 2);

    // --- residual CNN ---
    convg_k<12, 7, 1, 1, 0><<<cgrid, 256, 0, stream>>>(x, r1w, r1b, Cc, 64, 3);
    convg_k<64, 5, 0, 1, 0><<<cgrid, 256, 0, stream>>>(Cc, r2w, r2b, Dd, 64, 2);
    convg_k<64, 3, 0, 1, 0><<<cgrid, 256, 0, stream>>>(Dd, r3w, r3b, Cc, 64, 1);

    // --- fused d2 conv + r4 conv + alpha blend ---
    final2_k<<<cgrid, 256, 0, stream>>>(Bb, Cc, d2w, d2b, r4w, r4b, alpha, outp);
}

// Round 4
// 1138.618 us; speedup vs baseline: 6.7094x; 2.0611x over previous
//
#include <hip/hip_runtime.h>
#include <hip/hip_bf16.h>
#include <math.h>

#define BATCH 16
#define TLEN 3600
#define LEADS 12
#define PP 9
#define SS 400
#define DP 128
#define DM 256
#define NH 8
#define HD 32
#define NLAY 6
#define VV 512
#define RH 64

typedef __attribute__((ext_vector_type(8))) short short8b;
typedef __attribute__((ext_vector_type(4))) float f32x4;

__device__ __forceinline__ float gelu_f(float x) {
    return 0.5f * x * (1.0f + erff(x * 0.70710678118654752f));
}

__device__ __forceinline__ unsigned short f2bf(float f) {
    union { float f; unsigned u; } v; v.f = f;
    return (unsigned short)((v.u + 0x7FFFu + ((v.u >> 16) & 1u)) >> 16);
}

// ---------- block reduction helpers ----------
__device__ __forceinline__ float block_sum_256(float v, float* sm) {
    #pragma unroll
    for (int o = 32; o > 0; o >>= 1) v += __shfl_down(v, o);
    __syncthreads();
    if ((threadIdx.x & 63) == 0) sm[threadIdx.x >> 6] = v;
    __syncthreads();
    return sm[0] + sm[1] + sm[2] + sm[3];
}

__device__ __forceinline__ float block_sum_128(float v, float* sm) {
    #pragma unroll
    for (int o = 32; o > 0; o >>= 1) v += __shfl_down(v, o);
    __syncthreads();
    if ((threadIdx.x & 63) == 0) sm[threadIdx.x >> 6] = v;
    __syncthreads();
    return sm[0] + sm[1];
}

// ---------- generic LDS-staged implicit-GEMM conv ----------
// LAYOUT 0: in(B,CI,T). LAYOUT 1: in(B,T,CI). LAYOUT 2: in(B,S,CI*9) patch-major.
// OL 0: out(B,Co,T). OL 1: out(B,S,Co*9) patch-major.
template <int CI, int K, int LAYOUT, int ACT, int OL>
__global__ __launch_bounds__(256) void convg_k(const float* __restrict__ in,
                                               const float* __restrict__ w,
                                               const float* __restrict__ bias,
                                               float* __restrict__ out,
                                               int Co, int pad) {
    constexpr int CHUNK = (CI % 16 == 0) ? 16 : CI;
    constexpr int TT = 64 + K - 1;
    constexpr int NV = (K + 6) / 4;
    constexpr int TTP = 64 + 4 * NV;
    __shared__ __align__(16) float in_s[CHUNK][TTP];
    __shared__ __align__(16) float w_s[CHUNK][K][64];
    const int b = blockIdx.z;
    const int co0 = blockIdx.y * 64;
    const int t0 = blockIdx.x * 64;
    const int tid = threadIdx.x;
    const int tx = tid & 15, ty = tid >> 4;
    float acc[4][4] = {};
    for (int c0 = 0; c0 < CI; c0 += CHUNK) {
        __syncthreads();
        for (int idx = tid; idx < CHUNK * TT; idx += 256) {
            int ci = idx / TT, j = idx - ci * TT;
            int t = t0 + j - pad;
            float v = 0.f;
            if (t >= 0 && t < TLEN) {
                if (LAYOUT == 0) v = in[((size_t)(b * CI + c0 + ci)) * TLEN + t];
                else if (LAYOUT == 1) v = in[((size_t)b * TLEN + t) * CI + (c0 + ci)];
                else { int s = t / PP, k = t - s * PP;
                       v = in[((size_t)(b * SS + s)) * (CI * PP) + (c0 + ci) * PP + k]; }
            }
            in_s[ci][j] = v;
        }
        for (int idx = tid; idx < CHUNK * K * 64; idx += 256) {
            int co = idx & 63; int rest = idx >> 6; int k = rest % K; int ci = rest / K;
            w_s[ci][k][co] = w[((size_t)(co0 + co) * CI + (c0 + ci)) * K + k];
        }
        __syncthreads();
        #pragma unroll
        for (int ci = 0; ci < CHUNK; ++ci) {
            float tv[NV * 4];
            #pragma unroll
            for (int vv = 0; vv < NV; ++vv)
                *(float4*)&tv[vv * 4] = *(const float4*)&in_s[ci][tx * 4 + vv * 4];
            #pragma unroll
            for (int k = 0; k < K; ++k) {
                float4 wv = *(const float4*)&w_s[ci][k][ty * 4];
                #pragma unroll
                for (int j = 0; j < 4; ++j) {
                    float iv = tv[j + k];
                    acc[0][j] = fmaf(wv.x, iv, acc[0][j]);
                    acc[1][j] = fmaf(wv.y, iv, acc[1][j]);
                    acc[2][j] = fmaf(wv.z, iv, acc[2][j]);
                    acc[3][j] = fmaf(wv.w, iv, acc[3][j]);
                }
            }
        }
    }
    if (OL == 0) {
        const bool full = (t0 + 64 <= TLEN);
        #pragma unroll
        for (int i = 0; i < 4; ++i) {
            int co = co0 + ty * 4 + i;
            float bs = bias[co];
            float* orow = out + ((size_t)(b * Co + co)) * TLEN;
            if (full) {
                float4 o4;
                float vv0 = acc[i][0] + bs, vv1 = acc[i][1] + bs, vv2 = acc[i][2] + bs, vv3 = acc[i][3] + bs;
                if (ACT) { vv0 = gelu_f(vv0); vv1 = gelu_f(vv1); vv2 = gelu_f(vv2); vv3 = gelu_f(vv3); }
                o4.x = vv0; o4.y = vv1; o4.z = vv2; o4.w = vv3;
                *(float4*)&orow[t0 + tx * 4] = o4;
            } else {
                #pragma unroll
                for (int j = 0; j < 4; ++j) {
                    int t = t0 + tx * 4 + j;
                    if (t < TLEN) {
                        float v = acc[i][j] + bs;
                        if (ACT) v = gelu_f(v);
                        orow[t] = v;
                    }
                }
            }
        }
    } else {
        #pragma unroll
        for (int i = 0; i < 4; ++i) {
            int co = co0 + ty * 4 + i;
            float bs = bias[co];
            #pragma unroll
            for (int j = 0; j < 4; ++j) {
                int t = t0 + tx * 4 + j;
                if (t < TLEN) {
                    float v = acc[i][j] + bs;
                    if (ACT) v = gelu_f(v);
                    int s = t / PP, kk = t - s * PP;
                    out[((size_t)(b * SS + s)) * (size_t)(Co * PP) + co * PP + kk] = v;
                }
            }
        }
    }
}

// ---------- fp32 GEMM (used for patch projection only) ----------
template <int ACT, int RES>
__global__ __launch_bounds__(256) void gemm_k(const float* __restrict__ A,
                                              const float* __restrict__ W,
                                              const float* __restrict__ bias,
                                              const float* __restrict__ res,
                                              float* __restrict__ C,
                                              int M, int N, int K) {
    __shared__ float As[16][65];
    __shared__ float Bs[16][65];
    const int bm = blockIdx.y * 64, bn = blockIdx.x * 64;
    const int tid = threadIdx.x;
    const int tx = tid & 15, ty = tid >> 4;
    float acc[4][4] = {};
    const int lr = tid >> 2;
    const int lc = (tid & 3) * 4;
    for (int k0 = 0; k0 < K; k0 += 16) {
        float4 av = *(const float4*)&A[(size_t)(bm + lr) * K + k0 + lc];
        As[lc + 0][lr] = av.x; As[lc + 1][lr] = av.y; As[lc + 2][lr] = av.z; As[lc + 3][lr] = av.w;
        float4 wv = *(const float4*)&W[(size_t)(bn + lr) * K + k0 + lc];
        Bs[lc + 0][lr] = wv.x; Bs[lc + 1][lr] = wv.y; Bs[lc + 2][lr] = wv.z; Bs[lc + 3][lr] = wv.w;
        __syncthreads();
        #pragma unroll
        for (int kk = 0; kk < 16; ++kk) {
            float a[4], bv[4];
            #pragma unroll
            for (int i = 0; i < 4; ++i) a[i] = As[kk][ty * 4 + i];
            #pragma unroll
            for (int j = 0; j < 4; ++j) bv[j] = Bs[kk][tx * 4 + j];
            #pragma unroll
            for (int i = 0; i < 4; ++i)
                #pragma unroll
                for (int j = 0; j < 4; ++j) acc[i][j] = fmaf(a[i], bv[j], acc[i][j]);
        }
        __syncthreads();
    }
    #pragma unroll
    for (int i = 0; i < 4; ++i) {
        int m = bm + ty * 4 + i;
        #pragma unroll
        for (int j = 0; j < 4; ++j) {
            int n = bn + tx * 4 + j;
            float t = acc[i][j] + bias[n];
            if (ACT == 1) t = gelu_f(t);
            if (RES == 1) t += res[(size_t)m * N + n];
            C[(size_t)m * N + n] = t;
        }
    }
}

// ---------- bf16 MFMA GEMM: C = [res +] act( A(MxK)bf16 @ W(NxK)^T bf16 + bias ) ----------
template <int ACT, int RES, int OUTBF>
__global__ __launch_bounds__(256) void bgemm_k(const unsigned short* __restrict__ A,
                                               const unsigned short* __restrict__ W,
                                               const float* __restrict__ bias,
                                               const float* __restrict__ res,
                                               void* __restrict__ Cv,
                                               int M, int N, int K) {
    __shared__ __align__(16) unsigned short As[128][40];
    __shared__ __align__(16) unsigned short Bs[128][40];
    const int tid = threadIdx.x;
    const int gm0 = blockIdx.y * 128, gn0 = blockIdx.x * 128;
    const int w = tid >> 6, lane = tid & 63;
    const int wr0 = (w >> 1) * 64, wc0 = (w & 1) * 64;
    const int srow = tid >> 1, sc = (tid & 1) * 16;
    const unsigned short* ga = A + (size_t)(gm0 + srow) * K + sc;
    const unsigned short* gb = W + (size_t)(gn0 + srow) * K + sc;
    short8b ra0 = *(const short8b*)(ga), ra1 = *(const short8b*)(ga + 8);
    short8b rb0 = *(const short8b*)(gb), rb1 = *(const short8b*)(gb + 8);
    f32x4 acc[4][4];
    #pragma unroll
    for (int i = 0; i < 4; ++i)
        #pragma unroll
        for (int j = 0; j < 4; ++j) acc[i][j] = (f32x4){0.f, 0.f, 0.f, 0.f};
    const int fr = lane & 15, kg = (lane >> 4) * 8;
    const int nstep = K >> 5;
    for (int s = 0; s < nstep; ++s) {
        __syncthreads();
        *(short8b*)&As[srow][sc] = ra0; *(short8b*)&As[srow][sc + 8] = ra1;
        *(short8b*)&Bs[srow][sc] = rb0; *(short8b*)&Bs[srow][sc + 8] = rb1;
        __syncthreads();
        if (s + 1 < nstep) {
            ga += 32; gb += 32;
            ra0 = *(const short8b*)(ga); ra1 = *(const short8b*)(ga + 8);
            rb0 = *(const short8b*)(gb); rb1 = *(const short8b*)(gb + 8);
        }
        short8b af[4], bf[4];
        #pragma unroll
        for (int i = 0; i < 4; ++i) {
            af[i] = *(const short8b*)&As[wr0 + i * 16 + fr][kg];
            bf[i] = *(const short8b*)&Bs[wc0 + i * 16 + fr][kg];
        }
        #pragma unroll
        for (int i = 0; i < 4; ++i)
            #pragma unroll
            for (int j = 0; j < 4; ++j)
                acc[i][j] = __builtin_amdgcn_mfma_f32_16x16x32_bf16(af[i], bf[j], acc[i][j], 0, 0, 0);
    }
    const int orow = (lane >> 4) * 4, ocol = lane & 15;
    #pragma unroll
    for (int i = 0; i < 4; ++i) {
        #pragma unroll
        for (int j = 0; j < 4; ++j) {
            const int colg = gn0 + wc0 + j * 16 + ocol;
            const float bsv = bias[colg];
            #pragma unroll
            for (int r = 0; r < 4; ++r) {
                const int rowg = gm0 + wr0 + i * 16 + orow + r;
                float v = acc[i][j][r] + bsv;
                if (ACT) v = gelu_f(v);
                if (RES) v += res[(size_t)rowg * N + colg];
                if (OUTBF) ((unsigned short*)Cv)[(size_t)rowg * N + colg] = f2bf(v);
                else ((float*)Cv)[(size_t)rowg * N + colg] = v;
            }
        }
    }
}

// ---------- weight fp32 -> bf16 ----------
__global__ void tobf_k(const float* __restrict__ in, unsigned short* __restrict__ out, int n) {
    int i = blockIdx.x * 256 + threadIdx.x;
    if (i < n) out[i] = f2bf(in[i]);
}

// up_w (K=256, N=1152) -> bf16 (N=1152, K=256)
__global__ void upwt_k(const float* __restrict__ in, unsigned short* __restrict__ out) {
    int idx = blockIdx.x * 256 + threadIdx.x;
    if (idx < 1152 * 256) {
        int d = idx & 255, n = idx >> 8;
        out[idx] = f2bf(in[(size_t)d * 1152 + n]);
    }
}

// ---------- LayerNorm over 128 ----------
__global__ __launch_bounds__(128) void ln128_k(const float* __restrict__ in,
                                               const float* __restrict__ g,
                                               const float* __restrict__ bb,
                                               float* __restrict__ out) {
    int row = blockIdx.x, tid = threadIdx.x;
    __shared__ float sm[2];
    float v = in[(size_t)row * DP + tid];
    float mean = block_sum_128(v, sm) * (1.0f / DP);
    float d = v - mean;
    float var = block_sum_128(d * d, sm) * (1.0f / DP);
    out[(size_t)row * DP + tid] = d * rsqrtf(var + 1e-5f) * g[tid] + bb[tid];
}

// ---------- codebook norms ----------
__global__ void cbnorm_k(const float* __restrict__ cb, float* __restrict__ cbn) {
    int c = blockIdx.x * 256 + threadIdx.x;
    if (c < VV) {
        const float* cr = cb + (size_t)c * DP;
        float s = 0;
        for (int i = 0; i < DP; ++i) s += cr[i] * cr[i];
        cbn[c] = s;
    }
}

// ---------- VQ: tiled distance GEMM + argmin + commit partials; zq written as bf16 ----------
__global__ __launch_bounds__(256) void vq2_k(const float* __restrict__ ze,
                                             const float* __restrict__ cb,
                                             const float* __restrict__ cbn,
                                             unsigned short* __restrict__ zqb,
                                             float* __restrict__ vqs) {
    __shared__ __align__(16) float z_s[32][132];
    __shared__ __align__(16) float cb_s[64][132];
    __shared__ float cbn_s[64];
    __shared__ float bval[256];
    __shared__ int bidx[256];
    __shared__ int tok_s[32];
    __shared__ float psum[256];
    const int tid = threadIdx.x;
    const int r0 = blockIdx.x * 32;
    const int r = tid >> 3, cs = tid & 7;
    for (int idx = tid; idx < 32 * 128; idx += 256) {
        int rr = idx >> 7, cc = idx & 127;
        z_s[rr][cc] = ze[((size_t)(r0 + rr)) * DP + cc];
    }
    float best = 1e30f; int bi = 0;
    for (int c0 = 0; c0 < VV; c0 += 64) {
        __syncthreads();
        for (int idx = tid; idx < 64 * 128; idx += 256) {
            int rr = idx >> 7, cc = idx & 127;
            cb_s[rr][cc] = cb[((size_t)(c0 + rr)) * DP + cc];
        }
        if (tid < 64) cbn_s[tid] = cbn[c0 + tid];
        __syncthreads();
        float dot[8] = {};
        for (int i = 0; i < 128; i += 4) {
            float4 zv = *(const float4*)&z_s[r][i];
            #pragma unroll
            for (int j = 0; j < 8; ++j) {
                float4 cv = *(const float4*)&cb_s[cs + 8 * j][i];
                dot[j] += zv.x * cv.x + zv.y * cv.y + zv.z * cv.z + zv.w * cv.w;
            }
        }
        #pragma unroll
        for (int j = 0; j < 8; ++j) {
            float dist = cbn_s[cs + 8 * j] - 2.0f * dot[j];
            if (dist < best) { best = dist; bi = c0 + cs + 8 * j; }
        }
    }
    bval[tid] = best; bidx[tid] = bi;
    __syncthreads();
    if (cs == 0) {
        float bv = bval[tid]; int bix = bidx[tid];
        #pragma unroll
        for (int j = 1; j < 8; ++j) {
            float v = bval[tid + j]; int ix = bidx[tid + j];
            if (v < bv || (v == bv && ix < bix)) { bv = v; bix = ix; }
        }
        tok_s[r] = bix;
    }
    __syncthreads();
    int tok = tok_s[r];
    float part = 0;
    const float* cr = cb + (size_t)tok * DP + cs * 16;
    #pragma unroll
    for (int i = 0; i < 16; i += 4) {
        float4 qv = *(const float4*)(cr + i);
        float4 zv = *(const float4*)&z_s[r][cs * 16 + i];
        float dx = qv.x - zv.x, dy = qv.y - zv.y, dz = qv.z - zv.z, dw = qv.w - zv.w;
        part += dx * dx + dy * dy + dz * dz + dw * dw;
        size_t ob = ((size_t)(r0 + r)) * DP + cs * 16 + i;
        zqb[ob + 0] = f2bf(qv.x); zqb[ob + 1] = f2bf(qv.y);
        zqb[ob + 2] = f2bf(qv.z); zqb[ob + 3] = f2bf(qv.w);
    }
    psum[tid] = part;
    __syncthreads();
    if (cs == 0) {
        float s = 0;
        #pragma unroll
        for (int j = 0; j < 8; ++j) s += psum[tid + j];
        vqs[r0 + r] = s;
    }
}

__global__ void vqreduce_k(const float* __restrict__ vqs, float* __restrict__ out) {
    float s = 0;
    for (int i = threadIdx.x; i < BATCH * SS; i += 256) s += vqs[i];
    __shared__ float sm[4];
    s = block_sum_256(s, sm);
    if (threadIdx.x == 0) out[0] = s * (1.25f / (float)(BATCH * SS * DP));
}

// ---------- wave-per-row LayerNorm over 256 (shfl-only) ----------
template <int OUTBF>
__global__ __launch_bounds__(256) void lnw_k(const float* __restrict__ in,
                                             const float* __restrict__ g,
                                             const float* __restrict__ bb,
                                             void* __restrict__ out) {
    const int row = blockIdx.x * 4 + (threadIdx.x >> 6);
    const int lane = threadIdx.x & 63;
    float4 v = *(const float4*)&in[(size_t)row * DM + lane * 4];
    float s = v.x + v.y + v.z + v.w;
    #pragma unroll
    for (int o = 1; o < 64; o <<= 1) s += __shfl_xor(s, o);
    float mean = s * (1.0f / DM);
    float dx = v.x - mean, dy = v.y - mean, dz = v.z - mean, dw = v.w - mean;
    float vv = dx * dx + dy * dy + dz * dz + dw * dw;
    #pragma unroll
    for (int o = 1; o < 64; o <<= 1) vv += __shfl_xor(vv, o);
    float rstd = rsqrtf(vv * (1.0f / DM) + 1e-5f);
    float4 gv = *(const float4*)&g[lane * 4];
    float4 bv = *(const float4*)&bb[lane * 4];
    float o0 = dx * rstd * gv.x + bv.x;
    float o1 = dy * rstd * gv.y + bv.y;
    float o2 = dz * rstd * gv.z + bv.z;
    float o3 = dw * rstd * gv.w + bv.w;
    if (OUTBF) {
        unsigned long long pk = (unsigned long long)f2bf(o0)
                              | ((unsigned long long)f2bf(o1) << 16)
                              | ((unsigned long long)f2bf(o2) << 32)
                              | ((unsigned long long)f2bf(o3) << 48);
        *(unsigned long long*)((unsigned short*)out + (size_t)row * DM + lane * 4) = pk;
    } else {
        float4 o4; o4.x = o0; o4.y = o1; o4.z = o2; o4.w = o3;
        *(float4*)((float*)out + (size_t)row * DM + lane * 4) = o4;
    }
}

// ---------- fused flash MFMA attention ----------
// qkv bf16 (B,S,768). Block: (64-q tile, head, batch), 4 waves; wave = 16-q tile.
__global__ __launch_bounds__(256) void fattn_k(const unsigned short* __restrict__ qkv,
                                               const float* __restrict__ slopes,
                                               unsigned short* __restrict__ out) {
    __shared__ __align__(16) unsigned short Qs[64][40];
    __shared__ __align__(16) unsigned short Ks[64][40];
    __shared__ __align__(16) unsigned short Vt[32][72];
    __shared__ __align__(16) unsigned short Ps[4][16][72];
    const int qb = blockIdx.x, hh = blockIdx.y, b = blockIdx.z;
    const int tid = threadIdx.x;
    const int w = tid >> 6, lane = tid & 63;
    const int lr = lane & 15, lg = lane >> 4;
    const float slope = fabsf(slopes[hh]);
    const unsigned short* base = qkv + (size_t)b * SS * (3 * DM);
    {   // stage Q tile (clamped rows for the ragged last block)
        int row = tid >> 2, c = (tid & 3) * 8;
        int q = qb * 64 + row; q = q < SS ? q : SS - 1;
        *(short8b*)&Qs[row][c] = *(const short8b*)(base + (size_t)q * (3 * DM) + hh * HD + c);
    }
    __syncthreads();
    const short8b qa = *(const short8b*)&Qs[w * 16 + lr][lg * 8];
    float m_run[4] = {-1e30f, -1e30f, -1e30f, -1e30f};
    float l_run[4] = {0.f, 0.f, 0.f, 0.f};
    f32x4 of0 = (f32x4){0.f, 0.f, 0.f, 0.f}, of1 = (f32x4){0.f, 0.f, 0.f, 0.f};
    const int qg0 = qb * 64 + w * 16 + lg * 4;
    for (int kt = 0; kt < SS; kt += 64) {
        const int tl = (SS - kt) < 64 ? (SS - kt) : 64;   // 64 or 16
        const int nks = tl >> 4;
        __syncthreads();
        {   // stage K tile + transposed V tile
            int row = tid >> 2, c = (tid & 3) * 8;
            if (row < tl) {
                *(short8b*)&Ks[row][c] =
                    *(const short8b*)(base + (size_t)(kt + row) * (3 * DM) + DM + hh * HD + c);
                short8b v8 = *(const short8b*)(base + (size_t)(kt + row) * (3 * DM) + 2 * DM + hh * HD + c);
                #pragma unroll
                for (int j = 0; j < 8; ++j) Vt[c + j][row] = ((unsigned short*)&v8)[j];
            }
        }
        __syncthreads();
        // QK^T
        f32x4 sf[4];
        #pragma unroll
        for (int ks = 0; ks < 4; ++ks) {
            if (ks < nks) {
                short8b kb = *(const short8b*)&Ks[ks * 16 + lr][lg * 8];
                sf[ks] = __builtin_amdgcn_mfma_f32_16x16x32_bf16(qa, kb, (f32x4){0.f, 0.f, 0.f, 0.f}, 0, 0, 0);
            }
        }
        // bias + online softmax (per output row r)
        float pv[4][4];
        #pragma unroll
        for (int r = 0; r < 4; ++r) {
            float tmax = -1e30f;
            #pragma unroll
            for (int ks = 0; ks < 4; ++ks) {
                if (ks < nks) {
                    float sv = sf[ks][r] * 0.17677669529663687f
                             - slope * fabsf((float)(qg0 + r - (kt + ks * 16 + lr)));
                    pv[ks][r] = sv;
                    tmax = fmaxf(tmax, sv);
                }
            }
            #pragma unroll
            for (int o = 1; o < 16; o <<= 1) tmax = fmaxf(tmax, __shfl_xor(tmax, o));
            float mnew = fmaxf(m_run[r], tmax);
            float sc = __expf(m_run[r] - mnew);
            m_run[r] = mnew;
            float tsum = 0.f;
            #pragma unroll
            for (int ks = 0; ks < 4; ++ks) {
                if (ks < nks) {
                    float e = __expf(pv[ks][r] - mnew);
                    pv[ks][r] = e;
                    tsum += e;
                }
            }
            #pragma unroll
            for (int o = 1; o < 16; o <<= 1) tsum += __shfl_xor(tsum, o);
            l_run[r] = l_run[r] * sc + tsum;
            of0[r] *= sc; of1[r] *= sc;
        }
        // write P tile (bf16, zeros beyond valid k)
        #pragma unroll
        for (int ks = 0; ks < 4; ++ks)
            #pragma unroll
            for (int r = 0; r < 4; ++r)
                Ps[w][lg * 4 + r][ks * 16 + lr] = (ks < nks) ? f2bf(pv[ks][r]) : (unsigned short)0;
        // PV
        #pragma unroll
        for (int kc = 0; kc < 64; kc += 32) {
            if (kc < nks * 16) {
                short8b pa = *(const short8b*)&Ps[w][lr][kc + lg * 8];
                short8b vb0 = *(const short8b*)&Vt[lr][kc + lg * 8];
                short8b vb1 = *(const short8b*)&Vt[16 + lr][kc + lg * 8];
                of0 = __builtin_amdgcn_mfma_f32_16x16x32_bf16(pa, vb0, of0, 0, 0, 0);
                of1 = __builtin_amdgcn_mfma_f32_16x16x32_bf16(pa, vb1, of1, 0, 0, 0);
            }
        }
    }
    #pragma unroll
    for (int r = 0; r < 4; ++r) {
        int q = qg0 + r;
        if (q < SS) {
            float inv = 1.0f / l_run[r];
            out[((size_t)(b * SS + q)) * DM + hh * HD + lr] = f2bf(of0[r] * inv);
            out[((size_t)(b * SS + q)) * DM + hh * HD + 16 + lr] = f2bf(of1[r] * inv);
        }
    }
}

// ---------- final: d2 conv + r4 1x1 conv + alpha blend, out (B,T,LEADS) ----------
__global__ __launch_bounds__(256) void final2_k(const float* __restrict__ ud1,
                                                const float* __restrict__ r3i,
                                                const float* __restrict__ d2w,
                                                const float* __restrict__ d2b,
                                                const float* __restrict__ r4w,
                                                const float* __restrict__ r4b,
                                                const float* __restrict__ alpha,
                                                float* __restrict__ out) {
    __shared__ float u_s[64][66];
    __shared__ float r_s[64][64];
    __shared__ float wd_s[64][3][12];
    __shared__ float wr_s[64][12];
    __shared__ float o_s[64][12];
    const int b = blockIdx.z, t0 = blockIdx.x * 64, tid = threadIdx.x;
    for (int idx = tid; idx < 64 * 66; idx += 256) {
        int ci = idx / 66, j = idx - ci * 66;
        int t = t0 + j - 1;
        u_s[ci][j] = (t >= 0 && t < TLEN) ? ud1[((size_t)(b * 64 + ci)) * TLEN + t] : 0.f;
    }
    for (int idx = tid; idx < 64 * 64; idx += 256) {
        int ci = idx >> 6, j = idx & 63;
        int t = t0 + j;
        r_s[ci][j] = (t < TLEN) ? r3i[((size_t)(b * 64 + ci)) * TLEN + t] : 0.f;
    }
    for (int idx = tid; idx < 64 * 3 * 12; idx += 256) {
        int l = idx % 12, k = (idx / 12) % 3, ci = idx / 36;
        wd_s[ci][k][l] = d2w[(l * 64 + ci) * 3 + k];
    }
    for (int idx = tid; idx < 64 * 12; idx += 256) {
        int l = idx % 12, ci = idx / 12;
        wr_s[ci][l] = r4w[l * 64 + ci];
    }
    __syncthreads();
    const int tl = tid & 63, lg = tid >> 6;
    float accD[3] = {}, accR[3] = {};
    for (int ci = 0; ci < 64; ++ci) {
        float u0 = u_s[ci][tl], u1 = u_s[ci][tl + 1], u2 = u_s[ci][tl + 2];
        float rv = r_s[ci][tl];
        #pragma unroll
        for (int c = 0; c < 3; ++c) {
            int l = lg * 3 + c;
            accD[c] += u0 * wd_s[ci][0][l] + u1 * wd_s[ci][1][l] + u2 * wd_s[ci][2][l];
            accR[c] = fmaf(rv, wr_s[ci][l], accR[c]);
        }
    }
    float al = alpha[0];
    #pragma unroll
    for (int c = 0; c < 3; ++c) {
        int l = lg * 3 + c;
        o_s[tl][l] = accD[c] + d2b[l] + al * (accR[c] + r4b[l]);
    }
    __syncthreads();
    for (int idx = tid; idx < 64 * 12; idx += 256) {
        int t = t0 + idx / 12;
        if (t < TLEN) out[((size_t)b * TLEN + t) * 12 + idx % 12] = o_s[idx / 12][idx % 12];
    }
}

extern "C" void kernel_launch(void* const* d_in, const int* in_sizes, int n_in,
                              void* d_out, int out_size, void* d_ws, size_t ws_size,
                              hipStream_t stream) {
    const float* x     = (const float*)d_in[0];
    const float* pe_w1 = (const float*)d_in[1];
    const float* pe_b1 = (const float*)d_in[2];
    const float* pe_w2 = (const float*)d_in[3];
    const float* pe_b2 = (const float*)d_in[4];
    const float* pe_pw = (const float*)d_in[5];
    const float* pe_pb = (const float*)d_in[6];
    const float* pe_g  = (const float*)d_in[7];
    const float* pe_bb = (const float*)d_in[8];
    const float* cb    = (const float*)d_in[9];
    const float* tp_w  = (const float*)d_in[10];
    const float* tp_b  = (const float*)d_in[11];
    const float* tp_g  = (const float*)d_in[12];
    const float* tp_bb = (const float*)d_in[13];
    const float* ln1_g = (const float*)d_in[14];
    const float* ln1_b = (const float*)d_in[15];
    const float* inw   = (const float*)d_in[16];
    const float* inb   = (const float*)d_in[17];
    const float* ow    = (const float*)d_in[18];
    const float* ob    = (const float*)d_in[19];
    const float* ln2_g = (const float*)d_in[20];
    const float* ln2_b = (const float*)d_in[21];
    const float* f1w   = (const float*)d_in[22];
    const float* f1b   = (const float*)d_in[23];
    const float* f2w   = (const float*)d_in[24];
    const float* f2b   = (const float*)d_in[25];
    const float* slopes= (const float*)d_in[26];
    const float* fn_g  = (const float*)d_in[27];
    const float* fn_b  = (const float*)d_in[28];
    const float* up_w  = (const float*)d_in[29];
    const float* up_b  = (const float*)d_in[30];
    const float* d1w   = (const float*)d_in[31];
    const float* d1b   = (const float*)d_in[32];
    const float* d2w   = (const float*)d_in[33];
    const float* d2b   = (const float*)d_in[34];
    const float* r1w   = (const float*)d_in[35];
    const float* r1b   = (const float*)d_in[36];
    const float* r2w   = (const float*)d_in[37];
    const float* r2b   = (const float*)d_in[38];
    const float* r3w   = (const float*)d_in[39];
    const float* r3b   = (const float*)d_in[40];
    const float* r4w   = (const float*)d_in[41];
    const float* r4b   = (const float*)d_in[42];
    const float* alpha = (const float*)d_in[43];

    float* W = (float*)d_ws;
    size_t off = 0;
    auto alloc = [&](size_t n) { float* p = W + off; off += (n + 3) & ~(size_t)3; return p; };
    const size_t M = (size_t)BATCH * SS;  // 6400
    float* A   = alloc((size_t)BATCH * DP * TLEN);     // conv2 patch-major / upproj out
    float* Bb  = alloc((size_t)BATCH * 64 * TLEN);     // h1 / ud1
    float* Cc  = alloc((size_t)BATCH * 64 * TLEN);     // r1 / r3
    float* Dd  = alloc((size_t)BATCH * 64 * TLEN);     // r2
    float* ze  = alloc(M * DP);
    float* tx  = alloc(M * DM);                        // patch-gemm out / tokproj out
    float* hb  = alloc(M * DM);                        // residual stream
    float* qf  = alloc(M * 3 * DM);                    // qkv bf16 / ffn1 bf16 alias
    float* cbn = alloc(VV);
    float* vqs = alloc(M);
    unsigned short* zqb  = (unsigned short*)alloc(M * DP / 2);
    unsigned short* xnb  = (unsigned short*)alloc(M * DM / 2);
    unsigned short* aob  = (unsigned short*)alloc(M * DM / 2);
    unsigned short* qkvb = (unsigned short*)qf;        // bf16 qkv (M*768 ushorts)
    unsigned short* ffb  = (unsigned short*)qf;        // bf16 ffn1 (M*1024 ushorts) — qkv dead by then
    unsigned short* inwb = (unsigned short*)alloc((size_t)NLAY * 3 * DM * DM / 2);
    unsigned short* owb  = (unsigned short*)alloc((size_t)NLAY * DM * DM / 2);
    unsigned short* f1wb = (unsigned short*)alloc((size_t)NLAY * 4 * DM * DM / 2);
    unsigned short* f2wb = (unsigned short*)alloc((size_t)NLAY * 4 * DM * DM / 2);
    unsigned short* tpwb = (unsigned short*)alloc((size_t)DM * DP / 2);
    unsigned short* upwb = (unsigned short*)alloc((size_t)1152 * DM / 2);
    if (off * sizeof(float) > ws_size) return;

    float* outp = (float*)d_out;
    const dim3 cgrid(57, 1, BATCH);

    // --- weight conversions (bf16) ---
    tobf_k<<<(NLAY * 3 * DM * DM + 255) / 256, 256, 0, stream>>>(inw, inwb, NLAY * 3 * DM * DM);
    tobf_k<<<(NLAY * DM * DM + 255) / 256, 256, 0, stream>>>(ow, owb, NLAY * DM * DM);
    tobf_k<<<(NLAY * 4 * DM * DM + 255) / 256, 256, 0, stream>>>(f1w, f1wb, NLAY * 4 * DM * DM);
    tobf_k<<<(NLAY * 4 * DM * DM + 255) / 256, 256, 0, stream>>>(f2w, f2wb, NLAY * 4 * DM * DM);
    tobf_k<<<(DM * DP + 255) / 256, 256, 0, stream>>>(tp_w, tpwb, DM * DP);
    upwt_k<<<(1152 * 256 + 255) / 256, 256, 0, stream>>>(up_w, upwb);

    // --- encoder (fp32: protects VQ argmin) ---
    convg_k<12, 3, 1, 1, 0><<<cgrid, 256, 0, stream>>>(x, pe_w1, pe_b1, Bb, 64, 1);
    convg_k<64, 3, 0, 1, 1><<<dim3(57, 2, BATCH), 256, 0, stream>>>(Bb, pe_w2, pe_b2, A, 128, 1);
    cbnorm_k<<<2, 256, 0, stream>>>(cb, cbn);
    gemm_k<0, 0><<<dim3(2, M / 64), 256, 0, stream>>>(A, pe_pw, pe_pb, nullptr, tx, M, DP, DP * PP);
    ln128_k<<<M, 128, 0, stream>>>(tx, pe_g, pe_bb, ze);
    vq2_k<<<M / 32, 256, 0, stream>>>(ze, cb, cbn, zqb, vqs);
    vqreduce_k<<<1, 256, 0, stream>>>(vqs, outp + (size_t)BATCH * TLEN * LEADS);

    // --- token projection + LN ---
    bgemm_k<0, 0, 0><<<dim3(DM / 128, M / 128), 256, 0, stream>>>(zqb, tpwb, tp_b, nullptr, tx, M, DM, DP);
    lnw_k<0><<<M / 4, 256, 0, stream>>>(tx, tp_g, tp_bb, hb);

    // --- transformer (bf16 MFMA GEMMs + fused flash MFMA attention) ---
    for (int l = 0; l < NLAY; ++l) {
        lnw_k<1><<<M / 4, 256, 0, stream>>>(hb, ln1_g + l * DM, ln1_b + l * DM, xnb);
        bgemm_k<0, 0, 1><<<dim3(3 * DM / 128, M / 128), 256, 0, stream>>>(
            xnb, inwb + (size_t)l * 3 * DM * DM, inb + l * 3 * DM, nullptr, qkvb, M, 3 * DM, DM);
        fattn_k<<<dim3((SS + 63) / 64, NH, BATCH), 256, 0, stream>>>(qkvb, slopes + l * NH, aob);
        bgemm_k<0, 1, 0><<<dim3(DM / 128, M / 128), 256, 0, stream>>>(
            aob, owb + (size_t)l * DM * DM, ob + l * DM, hb, hb, M, DM, DM);
        lnw_k<1><<<M / 4, 256, 0, stream>>>(hb, ln2_g + l * DM, ln2_b + l * DM, xnb);
        bgemm_k<1, 0, 1><<<dim3(4 * DM / 128, M / 128), 256, 0, stream>>>(
            xnb, f1wb + (size_t)l * 4 * DM * DM, f1b + l * 4 * DM, nullptr, ffb, M, 4 * DM, DM);
        bgemm_k<0, 1, 0><<<dim3(DM / 128, M / 128), 256, 0, stream>>>(
            ffb, f2wb + (size_t)l * 4 * DM * DM, f2b + l * DM, hb, hb, M, DM, 4 * DM);
    }
    lnw_k<1><<<M / 4, 256, 0, stream>>>(hb, fn_g, fn_b, xnb);

    // --- decoder: upproj bf16 GEMM -> patch-major fp32, then d1 conv ---
    bgemm_k<1, 0, 0><<<dim3(1152 / 128, M / 128), 256, 0, stream>>>(xnb, upwb, up_b, nullptr, A, M, 1152, DM);
    convg_k<128, 5, 2, 1, 0><<<cgrid, 256, 0, stream>>>(A, d1w, d1b, Bb, 64, 2);

    // --- residual CNN ---
    convg_k<12, 7, 1, 1, 0><<<cgrid, 256, 0, stream>>>(x, r1w, r1b, Cc, 64, 3);
    convg_k<64, 5, 0, 1, 0><<<cgrid, 256, 0, stream>>>(Cc, r2w, r2b, Dd, 64, 2);
    convg_k<64, 3, 0, 1, 0><<<cgrid, 256, 0, stream>>>(Dd, r3w, r3b, Cc, 64, 1);

    // --- fused d2 conv + r4 conv + alpha blend ---
    final2_k<<<cgrid, 256, 0, stream>>>(Bb, Cc, d2w, d2b, r4w, r4b, alpha, outp);
}

// Round 5
// 1037.466 us; speedup vs baseline: 7.3635x; 1.0975x over previous
//
#include <hip/hip_runtime.h>
#include <hip/hip_bf16.h>
#include <math.h>

#define BATCH 16
#define TLEN 3600
#define LEADS 12
#define PP 9
#define SS 400
#define DP 128
#define DM 256
#define NH 8
#define HD 32
#define NLAY 6
#define VV 512
#define RH 64

typedef __attribute__((ext_vector_type(8))) short short8b;
typedef __attribute__((ext_vector_type(4))) float f32x4;

__device__ __forceinline__ float gelu_f(float x) {
    return 0.5f * x * (1.0f + erff(x * 0.70710678118654752f));
}

__device__ __forceinline__ unsigned short f2bf(float f) {
    union { float f; unsigned u; } v; v.f = f;
    return (unsigned short)((v.u + 0x7FFFu + ((v.u >> 16) & 1u)) >> 16);
}

__device__ __forceinline__ float bf2f(unsigned short h) {
    union { unsigned u; float f; } v; v.u = ((unsigned)h) << 16; return v.f;
}

// ---------- block reduction helpers ----------
__device__ __forceinline__ float block_sum_256(float v, float* sm) {
    #pragma unroll
    for (int o = 32; o > 0; o >>= 1) v += __shfl_down(v, o);
    __syncthreads();
    if ((threadIdx.x & 63) == 0) sm[threadIdx.x >> 6] = v;
    __syncthreads();
    return sm[0] + sm[1] + sm[2] + sm[3];
}

__device__ __forceinline__ float block_sum_128(float v, float* sm) {
    #pragma unroll
    for (int o = 32; o > 0; o >>= 1) v += __shfl_down(v, o);
    __syncthreads();
    if ((threadIdx.x & 63) == 0) sm[threadIdx.x >> 6] = v;
    __syncthreads();
    return sm[0] + sm[1];
}

// ---------- generic LDS-staged implicit-GEMM conv (fp32) ----------
// LAYOUT 0: in(B,CI,T). LAYOUT 1: in(B,T,CI).
// OL 0: out(B,Co,T) fp32. OL 1: out(B,S,Co*9) patch-major fp32. OL 2: out(B,T,Co) bf16 TM.
template <int CI, int K, int LAYOUT, int ACT, int OL>
__global__ __launch_bounds__(256) void convg_k(const float* __restrict__ in,
                                               const float* __restrict__ w,
                                               const float* __restrict__ bias,
                                               float* __restrict__ out,
                                               int Co, int pad) {
    constexpr int CHUNK = (CI % 16 == 0) ? 16 : CI;
    constexpr int TT = 64 + K - 1;
    constexpr int NV = (K + 6) / 4;
    constexpr int TTP = 64 + 4 * NV;
    __shared__ __align__(16) float in_s[CHUNK][TTP];
    __shared__ __align__(16) float w_s[CHUNK][K][64];
    const int b = blockIdx.z;
    const int co0 = blockIdx.y * 64;
    const int t0 = blockIdx.x * 64;
    const int tid = threadIdx.x;
    const int tx = tid & 15, ty = tid >> 4;
    float acc[4][4] = {};
    for (int c0 = 0; c0 < CI; c0 += CHUNK) {
        __syncthreads();
        for (int idx = tid; idx < CHUNK * TT; idx += 256) {
            int ci = idx / TT, j = idx - ci * TT;
            int t = t0 + j - pad;
            float v = 0.f;
            if (t >= 0 && t < TLEN) {
                if (LAYOUT == 0) v = in[((size_t)(b * CI + c0 + ci)) * TLEN + t];
                else v = in[((size_t)b * TLEN + t) * CI + (c0 + ci)];
            }
            in_s[ci][j] = v;
        }
        for (int idx = tid; idx < CHUNK * K * 64; idx += 256) {
            int co = idx & 63; int rest = idx >> 6; int k = rest % K; int ci = rest / K;
            w_s[ci][k][co] = w[((size_t)(co0 + co) * CI + (c0 + ci)) * K + k];
        }
        __syncthreads();
        #pragma unroll
        for (int ci = 0; ci < CHUNK; ++ci) {
            float tv[NV * 4];
            #pragma unroll
            for (int vv = 0; vv < NV; ++vv)
                *(float4*)&tv[vv * 4] = *(const float4*)&in_s[ci][tx * 4 + vv * 4];
            #pragma unroll
            for (int k = 0; k < K; ++k) {
                float4 wv = *(const float4*)&w_s[ci][k][ty * 4];
                #pragma unroll
                for (int j = 0; j < 4; ++j) {
                    float iv = tv[j + k];
                    acc[0][j] = fmaf(wv.x, iv, acc[0][j]);
                    acc[1][j] = fmaf(wv.y, iv, acc[1][j]);
                    acc[2][j] = fmaf(wv.z, iv, acc[2][j]);
                    acc[3][j] = fmaf(wv.w, iv, acc[3][j]);
                }
            }
        }
    }
    if (OL == 0) {
        const bool full = (t0 + 64 <= TLEN);
        #pragma unroll
        for (int i = 0; i < 4; ++i) {
            int co = co0 + ty * 4 + i;
            float bs = bias[co];
            float* orow = out + ((size_t)(b * Co + co)) * TLEN;
            if (full) {
                float4 o4;
                float vv0 = acc[i][0] + bs, vv1 = acc[i][1] + bs, vv2 = acc[i][2] + bs, vv3 = acc[i][3] + bs;
                if (ACT) { vv0 = gelu_f(vv0); vv1 = gelu_f(vv1); vv2 = gelu_f(vv2); vv3 = gelu_f(vv3); }
                o4.x = vv0; o4.y = vv1; o4.z = vv2; o4.w = vv3;
                *(float4*)&orow[t0 + tx * 4] = o4;
            } else {
                #pragma unroll
                for (int j = 0; j < 4; ++j) {
                    int t = t0 + tx * 4 + j;
                    if (t < TLEN) {
                        float v = acc[i][j] + bs;
                        if (ACT) v = gelu_f(v);
                        orow[t] = v;
                    }
                }
            }
        }
    } else if (OL == 1) {
        #pragma unroll
        for (int i = 0; i < 4; ++i) {
            int co = co0 + ty * 4 + i;
            float bs = bias[co];
            #pragma unroll
            for (int j = 0; j < 4; ++j) {
                int t = t0 + tx * 4 + j;
                if (t < TLEN) {
                    float v = acc[i][j] + bs;
                    if (ACT) v = gelu_f(v);
                    int s = t / PP, kk = t - s * PP;
                    out[((size_t)(b * SS + s)) * (size_t)(Co * PP) + co * PP + kk] = v;
                }
            }
        }
    } else {
        unsigned short* ob = (unsigned short*)out;
        #pragma unroll
        for (int i = 0; i < 4; ++i) {
            int co = co0 + ty * 4 + i;
            float bs = bias[co];
            #pragma unroll
            for (int j = 0; j < 4; ++j) {
                int t = t0 + tx * 4 + j;
                if (t < TLEN) {
                    float v = acc[i][j] + bs;
                    if (ACT) v = gelu_f(v);
                    ob[((size_t)(b * TLEN + t)) * 64 + co] = f2bf(v);
                }
            }
        }
    }
}

// ---------- bf16 MFMA implicit-GEMM conv ----------
// in (B,T,CI) bf16 TM; wpk [k][co][ci] bf16; out (B,T,64) bf16 TM, GELU.
template <int CI, int K, int PAD>
__global__ __launch_bounds__(256) void mfconv_k(const unsigned short* __restrict__ in,
                                                const unsigned short* __restrict__ wpk,
                                                const float* __restrict__ bias,
                                                unsigned short* __restrict__ out) {
    constexpr int CIC = (CI > 64) ? 64 : CI;
    constexpr int NCH = CI / CIC;
    constexpr int TROWS = 128 + K - 1;
    constexpr int CQ = CIC / 8;
    __shared__ __align__(16) unsigned short in_s[TROWS][CIC + 8];
    __shared__ __align__(16) unsigned short w_s[K][64][CIC + 8];
    const int b = blockIdx.z;
    const int t0 = blockIdx.x * 128;
    const int tid = threadIdx.x;
    const int w = tid >> 6, lane = tid & 63;
    const int fr = lane & 15, kg = (lane >> 4) * 8;
    f32x4 acc[2][4];
    #pragma unroll
    for (int i = 0; i < 2; ++i)
        #pragma unroll
        for (int j = 0; j < 4; ++j) acc[i][j] = (f32x4){0.f, 0.f, 0.f, 0.f};
    for (int ch = 0; ch < NCH; ++ch) {
        const int c0 = ch * CIC;
        if (ch) __syncthreads();
        for (int u = tid; u < TROWS * CQ; u += 256) {
            int row = u / CQ, q = u - row * CQ;
            int t = t0 + row - PAD;
            short8b v = (short8b){0, 0, 0, 0, 0, 0, 0, 0};
            if (t >= 0 && t < TLEN)
                v = *(const short8b*)&in[((size_t)(b * TLEN + t)) * CI + c0 + q * 8];
            *(short8b*)&in_s[row][q * 8] = v;
        }
        for (int u = tid; u < K * 64 * CQ; u += 256) {
            int q = u % CQ; int rest = u / CQ; int co = rest & 63; int k = rest >> 6;
            *(short8b*)&w_s[k][co][q * 8] =
                *(const short8b*)&wpk[((size_t)(k * 64 + co)) * CI + c0 + q * 8];
        }
        __syncthreads();
        #pragma unroll
        for (int k = 0; k < K; ++k) {
            #pragma unroll
            for (int c32 = 0; c32 < CIC / 32; ++c32) {
                short8b a0 = *(const short8b*)&in_s[w * 32 + fr + k][c32 * 32 + kg];
                short8b a1 = *(const short8b*)&in_s[w * 32 + 16 + fr + k][c32 * 32 + kg];
                short8b b0 = *(const short8b*)&w_s[k][fr][c32 * 32 + kg];
                short8b b1 = *(const short8b*)&w_s[k][16 + fr][c32 * 32 + kg];
                short8b b2 = *(const short8b*)&w_s[k][32 + fr][c32 * 32 + kg];
                short8b b3 = *(const short8b*)&w_s[k][48 + fr][c32 * 32 + kg];
                acc[0][0] = __builtin_amdgcn_mfma_f32_16x16x32_bf16(a0, b0, acc[0][0], 0, 0, 0);
                acc[0][1] = __builtin_amdgcn_mfma_f32_16x16x32_bf16(a0, b1, acc[0][1], 0, 0, 0);
                acc[0][2] = __builtin_amdgcn_mfma_f32_16x16x32_bf16(a0, b2, acc[0][2], 0, 0, 0);
                acc[0][3] = __builtin_amdgcn_mfma_f32_16x16x32_bf16(a0, b3, acc[0][3], 0, 0, 0);
                acc[1][0] = __builtin_amdgcn_mfma_f32_16x16x32_bf16(a1, b0, acc[1][0], 0, 0, 0);
                acc[1][1] = __builtin_amdgcn_mfma_f32_16x16x32_bf16(a1, b1, acc[1][1], 0, 0, 0);
                acc[1][2] = __builtin_amdgcn_mfma_f32_16x16x32_bf16(a1, b2, acc[1][2], 0, 0, 0);
                acc[1][3] = __builtin_amdgcn_mfma_f32_16x16x32_bf16(a1, b3, acc[1][3], 0, 0, 0);
            }
        }
    }
    const int orow = (lane >> 4) * 4, ocol = lane & 15;
    #pragma unroll
    for (int i = 0; i < 2; ++i)
        #pragma unroll
        for (int j = 0; j < 4; ++j) {
            const int co = j * 16 + ocol;
            const float bv = bias[co];
            #pragma unroll
            for (int r = 0; r < 4; ++r) {
                int t = t0 + w * 32 + i * 16 + orow + r;
                if (t < TLEN)
                    out[((size_t)(b * TLEN + t)) * 64 + co] = f2bf(gelu_f(acc[i][j][r] + bv));
            }
        }
}

// ---------- fp32 GEMM (patch projection only) ----------
template <int ACT, int RES>
__global__ __launch_bounds__(256) void gemm_k(const float* __restrict__ A,
                                              const float* __restrict__ W,
                                              const float* __restrict__ bias,
                                              const float* __restrict__ res,
                                              float* __restrict__ C,
                                              int M, int N, int K) {
    __shared__ float As[16][65];
    __shared__ float Bs[16][65];
    const int bm = blockIdx.y * 64, bn = blockIdx.x * 64;
    const int tid = threadIdx.x;
    const int tx = tid & 15, ty = tid >> 4;
    float acc[4][4] = {};
    const int lr = tid >> 2;
    const int lc = (tid & 3) * 4;
    for (int k0 = 0; k0 < K; k0 += 16) {
        float4 av = *(const float4*)&A[(size_t)(bm + lr) * K + k0 + lc];
        As[lc + 0][lr] = av.x; As[lc + 1][lr] = av.y; As[lc + 2][lr] = av.z; As[lc + 3][lr] = av.w;
        float4 wv = *(const float4*)&W[(size_t)(bn + lr) * K + k0 + lc];
        Bs[lc + 0][lr] = wv.x; Bs[lc + 1][lr] = wv.y; Bs[lc + 2][lr] = wv.z; Bs[lc + 3][lr] = wv.w;
        __syncthreads();
        #pragma unroll
        for (int kk = 0; kk < 16; ++kk) {
            float a[4], bv[4];
            #pragma unroll
            for (int i = 0; i < 4; ++i) a[i] = As[kk][ty * 4 + i];
            #pragma unroll
            for (int j = 0; j < 4; ++j) bv[j] = Bs[kk][tx * 4 + j];
            #pragma unroll
            for (int i = 0; i < 4; ++i)
                #pragma unroll
                for (int j = 0; j < 4; ++j) acc[i][j] = fmaf(a[i], bv[j], acc[i][j]);
        }
        __syncthreads();
    }
    #pragma unroll
    for (int i = 0; i < 4; ++i) {
        int m = bm + ty * 4 + i;
        #pragma unroll
        for (int j = 0; j < 4; ++j) {
            int n = bn + tx * 4 + j;
            float t = acc[i][j] + bias[n];
            if (ACT == 1) t = gelu_f(t);
            if (RES == 1) t += res[(size_t)m * N + n];
            C[(size_t)m * N + n] = t;
        }
    }
}

// ---------- bf16 MFMA GEMM: C = [res +] act( A(MxK)bf16 @ W(NxK)^T bf16 + bias ) ----------
template <int ACT, int RES, int OUTBF>
__global__ __launch_bounds__(256) void bgemm_k(const unsigned short* __restrict__ A,
                                               const unsigned short* __restrict__ W,
                                               const float* __restrict__ bias,
                                               const float* __restrict__ res,
                                               void* __restrict__ Cv,
                                               int M, int N, int K) {
    __shared__ __align__(16) unsigned short As[128][40];
    __shared__ __align__(16) unsigned short Bs[128][40];
    const int tid = threadIdx.x;
    const int gm0 = blockIdx.y * 128, gn0 = blockIdx.x * 128;
    const int w = tid >> 6, lane = tid & 63;
    const int wr0 = (w >> 1) * 64, wc0 = (w & 1) * 64;
    const int srow = tid >> 1, sc = (tid & 1) * 16;
    const unsigned short* ga = A + (size_t)(gm0 + srow) * K + sc;
    const unsigned short* gb = W + (size_t)(gn0 + srow) * K + sc;
    short8b ra0 = *(const short8b*)(ga), ra1 = *(const short8b*)(ga + 8);
    short8b rb0 = *(const short8b*)(gb), rb1 = *(const short8b*)(gb + 8);
    f32x4 acc[4][4];
    #pragma unroll
    for (int i = 0; i < 4; ++i)
        #pragma unroll
        for (int j = 0; j < 4; ++j) acc[i][j] = (f32x4){0.f, 0.f, 0.f, 0.f};
    const int fr = lane & 15, kg = (lane >> 4) * 8;
    const int nstep = K >> 5;
    for (int s = 0; s < nstep; ++s) {
        __syncthreads();
        *(short8b*)&As[srow][sc] = ra0; *(short8b*)&As[srow][sc + 8] = ra1;
        *(short8b*)&Bs[srow][sc] = rb0; *(short8b*)&Bs[srow][sc + 8] = rb1;
        __syncthreads();
        if (s + 1 < nstep) {
            ga += 32; gb += 32;
            ra0 = *(const short8b*)(ga); ra1 = *(const short8b*)(ga + 8);
            rb0 = *(const short8b*)(gb); rb1 = *(const short8b*)(gb + 8);
        }
        short8b af[4], bf[4];
        #pragma unroll
        for (int i = 0; i < 4; ++i) {
            af[i] = *(const short8b*)&As[wr0 + i * 16 + fr][kg];
            bf[i] = *(const short8b*)&Bs[wc0 + i * 16 + fr][kg];
        }
        #pragma unroll
        for (int i = 0; i < 4; ++i)
            #pragma unroll
            for (int j = 0; j < 4; ++j)
                acc[i][j] = __builtin_amdgcn_mfma_f32_16x16x32_bf16(af[i], bf[j], acc[i][j], 0, 0, 0);
    }
    const int orow = (lane >> 4) * 4, ocol = lane & 15;
    #pragma unroll
    for (int i = 0; i < 4; ++i) {
        #pragma unroll
        for (int j = 0; j < 4; ++j) {
            const int colg = gn0 + wc0 + j * 16 + ocol;
            const float bsv = bias[colg];
            #pragma unroll
            for (int r = 0; r < 4; ++r) {
                const int rowg = gm0 + wr0 + i * 16 + orow + r;
                float v = acc[i][j][r] + bsv;
                if (ACT) v = gelu_f(v);
                if (RES) v += res[(size_t)rowg * N + colg];
                if (OUTBF) ((unsigned short*)Cv)[(size_t)rowg * N + colg] = f2bf(v);
                else ((float*)Cv)[(size_t)rowg * N + colg] = v;
            }
        }
    }
}

// ---------- weight fp32 -> bf16 ----------
__global__ void tobf_k(const float* __restrict__ in, unsigned short* __restrict__ out, int n) {
    int i = blockIdx.x * 256 + threadIdx.x;
    if (i < n) out[i] = f2bf(in[i]);
}

// conv weight (Co,CI,K) -> bf16 [k][co][ci]
__global__ void cpack_k(const float* __restrict__ w, unsigned short* __restrict__ out,
                        int Co, int CI, int K) {
    int idx = blockIdx.x * 256 + threadIdx.x;
    if (idx < Co * CI * K) {
        int ci = idx % CI; int rest = idx / CI; int co = rest % Co; int k = rest / Co;
        out[idx] = f2bf(w[((size_t)co * CI + ci) * K + k]);
    }
}

// up_w (256,128,9) -> bf16 W'[n][d], n = k*128+o (time-major producing); also expand bias
__global__ void upwt2_k(const float* __restrict__ w, const float* __restrict__ bsrc,
                        unsigned short* __restrict__ out, float* __restrict__ b2) {
    int idx = blockIdx.x * 256 + threadIdx.x;
    if (idx < 1152 * 256) {
        int d = idx & 255, n = idx >> 8;
        int o = n & 127, k = n >> 7;
        out[(size_t)n * 256 + d] = f2bf(w[(size_t)d * 1152 + o * 9 + k]);
    }
    if (idx < 1152) b2[idx] = bsrc[idx & 127];
}

// ---------- LayerNorm over 128 ----------
__global__ __launch_bounds__(128) void ln128_k(const float* __restrict__ in,
                                               const float* __restrict__ g,
                                               const float* __restrict__ bb,
                                               float* __restrict__ out) {
    int row = blockIdx.x, tid = threadIdx.x;
    __shared__ float sm[2];
    float v = in[(size_t)row * DP + tid];
    float mean = block_sum_128(v, sm) * (1.0f / DP);
    float d = v - mean;
    float var = block_sum_128(d * d, sm) * (1.0f / DP);
    out[(size_t)row * DP + tid] = d * rsqrtf(var + 1e-5f) * g[tid] + bb[tid];
}

// ---------- codebook norms ----------
__global__ void cbnorm_k(const float* __restrict__ cb, float* __restrict__ cbn) {
    int c = blockIdx.x * 256 + threadIdx.x;
    if (c < VV) {
        const float* cr = cb + (size_t)c * DP;
        float s = 0;
        for (int i = 0; i < DP; ++i) s += cr[i] * cr[i];
        cbn[c] = s;
    }
}

// ---------- VQ: tiled distance GEMM + argmin + commit partials; zq bf16 ----------
__global__ __launch_bounds__(256) void vq2_k(const float* __restrict__ ze,
                                             const float* __restrict__ cb,
                                             const float* __restrict__ cbn,
                                             unsigned short* __restrict__ zqb,
                                             float* __restrict__ vqs) {
    __shared__ __align__(16) float z_s[32][132];
    __shared__ __align__(16) float cb_s[64][132];
    __shared__ float cbn_s[64];
    __shared__ float bval[256];
    __shared__ int bidx[256];
    __shared__ int tok_s[32];
    __shared__ float psum[256];
    const int tid = threadIdx.x;
    const int r0 = blockIdx.x * 32;
    const int r = tid >> 3, cs = tid & 7;
    for (int idx = tid; idx < 32 * 128; idx += 256) {
        int rr = idx >> 7, cc = idx & 127;
        z_s[rr][cc] = ze[((size_t)(r0 + rr)) * DP + cc];
    }
    float best = 1e30f; int bi = 0;
    for (int c0 = 0; c0 < VV; c0 += 64) {
        __syncthreads();
        for (int idx = tid; idx < 64 * 128; idx += 256) {
            int rr = idx >> 7, cc = idx & 127;
            cb_s[rr][cc] = cb[((size_t)(c0 + rr)) * DP + cc];
        }
        if (tid < 64) cbn_s[tid] = cbn[c0 + tid];
        __syncthreads();
        float dot[8] = {};
        for (int i = 0; i < 128; i += 4) {
            float4 zv = *(const float4*)&z_s[r][i];
            #pragma unroll
            for (int j = 0; j < 8; ++j) {
                float4 cv = *(const float4*)&cb_s[cs + 8 * j][i];
                dot[j] += zv.x * cv.x + zv.y * cv.y + zv.z * cv.z + zv.w * cv.w;
            }
        }
        #pragma unroll
        for (int j = 0; j < 8; ++j) {
            float dist = cbn_s[cs + 8 * j] - 2.0f * dot[j];
            if (dist < best) { best = dist; bi = c0 + cs + 8 * j; }
        }
    }
    bval[tid] = best; bidx[tid] = bi;
    __syncthreads();
    if (cs == 0) {
        float bv = bval[tid]; int bix = bidx[tid];
        #pragma unroll
        for (int j = 1; j < 8; ++j) {
            float v = bval[tid + j]; int ix = bidx[tid + j];
            if (v < bv || (v == bv && ix < bix)) { bv = v; bix = ix; }
        }
        tok_s[r] = bix;
    }
    __syncthreads();
    int tok = tok_s[r];
    float part = 0;
    const float* cr = cb + (size_t)tok * DP + cs * 16;
    #pragma unroll
    for (int i = 0; i < 16; i += 4) {
        float4 qv = *(const float4*)(cr + i);
        float4 zv = *(const float4*)&z_s[r][cs * 16 + i];
        float dx = qv.x - zv.x, dy = qv.y - zv.y, dz = qv.z - zv.z, dw = qv.w - zv.w;
        part += dx * dx + dy * dy + dz * dz + dw * dw;
        size_t ob = ((size_t)(r0 + r)) * DP + cs * 16 + i;
        zqb[ob + 0] = f2bf(qv.x); zqb[ob + 1] = f2bf(qv.y);
        zqb[ob + 2] = f2bf(qv.z); zqb[ob + 3] = f2bf(qv.w);
    }
    psum[tid] = part;
    __syncthreads();
    if (cs == 0) {
        float s = 0;
        #pragma unroll
        for (int j = 0; j < 8; ++j) s += psum[tid + j];
        vqs[r0 + r] = s;
    }
}

__global__ void vqreduce_k(const float* __restrict__ vqs, float* __restrict__ out) {
    float s = 0;
    for (int i = threadIdx.x; i < BATCH * SS; i += 256) s += vqs[i];
    __shared__ float sm[4];
    s = block_sum_256(s, sm);
    if (threadIdx.x == 0) out[0] = s * (1.25f / (float)(BATCH * SS * DP));
}

// ---------- wave-per-row LayerNorm over 256 (shfl-only) ----------
template <int OUTBF>
__global__ __launch_bounds__(256) void lnw_k(const float* __restrict__ in,
                                             const float* __restrict__ g,
                                             const float* __restrict__ bb,
                                             void* __restrict__ out) {
    const int row = blockIdx.x * 4 + (threadIdx.x >> 6);
    const int lane = threadIdx.x & 63;
    float4 v = *(const float4*)&in[(size_t)row * DM + lane * 4];
    float s = v.x + v.y + v.z + v.w;
    #pragma unroll
    for (int o = 1; o < 64; o <<= 1) s += __shfl_xor(s, o);
    float mean = s * (1.0f / DM);
    float dx = v.x - mean, dy = v.y - mean, dz = v.z - mean, dw = v.w - mean;
    float vv = dx * dx + dy * dy + dz * dz + dw * dw;
    #pragma unroll
    for (int o = 1; o < 64; o <<= 1) vv += __shfl_xor(vv, o);
    float rstd = rsqrtf(vv * (1.0f / DM) + 1e-5f);
    float4 gv = *(const float4*)&g[lane * 4];
    float4 bv = *(const float4*)&bb[lane * 4];
    float o0 = dx * rstd * gv.x + bv.x;
    float o1 = dy * rstd * gv.y + bv.y;
    float o2 = dz * rstd * gv.z + bv.z;
    float o3 = dw * rstd * gv.w + bv.w;
    if (OUTBF) {
        unsigned long long pk = (unsigned long long)f2bf(o0)
                              | ((unsigned long long)f2bf(o1) << 16)
                              | ((unsigned long long)f2bf(o2) << 32)
                              | ((unsigned long long)f2bf(o3) << 48);
        *(unsigned long long*)((unsigned short*)out + (size_t)row * DM + lane * 4) = pk;
    } else {
        float4 o4; o4.x = o0; o4.y = o1; o4.z = o2; o4.w = o3;
        *(float4*)((float*)out + (size_t)row * DM + lane * 4) = o4;
    }
}

// ---------- fused flash MFMA attention ----------
__global__ __launch_bounds__(256) void fattn_k(const unsigned short* __restrict__ qkv,
                                               const float* __restrict__ slopes,
                                               unsigned short* __restrict__ out) {
    __shared__ __align__(16) unsigned short Qs[64][40];
    __shared__ __align__(16) unsigned short Ks[64][40];
    __shared__ __align__(16) unsigned short Vt[32][72];
    __shared__ __align__(16) unsigned short Ps[4][16][72];
    const int qb = blockIdx.x, hh = blockIdx.y, b = blockIdx.z;
    const int tid = threadIdx.x;
    const int w = tid >> 6, lane = tid & 63;
    const int lr = lane & 15, lg = lane >> 4;
    const float slope = fabsf(slopes[hh]);
    const unsigned short* base = qkv + (size_t)b * SS * (3 * DM);
    {
        int row = tid >> 2, c = (tid & 3) * 8;
        int q = qb * 64 + row; q = q < SS ? q : SS - 1;
        *(short8b*)&Qs[row][c] = *(const short8b*)(base + (size_t)q * (3 * DM) + hh * HD + c);
    }
    __syncthreads();
    const short8b qa = *(const short8b*)&Qs[w * 16 + lr][lg * 8];
    float m_run[4] = {-1e30f, -1e30f, -1e30f, -1e30f};
    float l_run[4] = {0.f, 0.f, 0.f, 0.f};
    f32x4 of0 = (f32x4){0.f, 0.f, 0.f, 0.f}, of1 = (f32x4){0.f, 0.f, 0.f, 0.f};
    const int qg0 = qb * 64 + w * 16 + lg * 4;
    for (int kt = 0; kt < SS; kt += 64) {
        const int tl = (SS - kt) < 64 ? (SS - kt) : 64;
        const int nks = tl >> 4;
        __syncthreads();
        {
            int row = tid >> 2, c = (tid & 3) * 8;
            if (row < tl) {
                *(short8b*)&Ks[row][c] =
                    *(const short8b*)(base + (size_t)(kt + row) * (3 * DM) + DM + hh * HD + c);
                short8b v8 = *(const short8b*)(base + (size_t)(kt + row) * (3 * DM) + 2 * DM + hh * HD + c);
                #pragma unroll
                for (int j = 0; j < 8; ++j) Vt[c + j][row] = ((unsigned short*)&v8)[j];
            }
        }
        __syncthreads();
        f32x4 sf[4];
        #pragma unroll
        for (int ks = 0; ks < 4; ++ks) {
            if (ks < nks) {
                short8b kb = *(const short8b*)&Ks[ks * 16 + lr][lg * 8];
                sf[ks] = __builtin_amdgcn_mfma_f32_16x16x32_bf16(qa, kb, (f32x4){0.f, 0.f, 0.f, 0.f}, 0, 0, 0);
            }
        }
        float pv[4][4];
        #pragma unroll
        for (int r = 0; r < 4; ++r) {
            float tmax = -1e30f;
            #pragma unroll
            for (int ks = 0; ks < 4; ++ks) {
                if (ks < nks) {
                    float sv = sf[ks][r] * 0.17677669529663687f
                             - slope * fabsf((float)(qg0 + r - (kt + ks * 16 + lr)));
                    pv[ks][r] = sv;
                    tmax = fmaxf(tmax, sv);
                }
            }
            #pragma unroll
            for (int o = 1; o < 16; o <<= 1) tmax = fmaxf(tmax, __shfl_xor(tmax, o));
            float mnew = fmaxf(m_run[r], tmax);
            float sc = __expf(m_run[r] - mnew);
            m_run[r] = mnew;
            float tsum = 0.f;
            #pragma unroll
            for (int ks = 0; ks < 4; ++ks) {
                if (ks < nks) {
                    float e = __expf(pv[ks][r] - mnew);
                    pv[ks][r] = e;
                    tsum += e;
                }
            }
            #pragma unroll
            for (int o = 1; o < 16; o <<= 1) tsum += __shfl_xor(tsum, o);
            l_run[r] = l_run[r] * sc + tsum;
            of0[r] *= sc; of1[r] *= sc;
        }
        #pragma unroll
        for (int ks = 0; ks < 4; ++ks)
            #pragma unroll
            for (int r = 0; r < 4; ++r)
                Ps[w][lg * 4 + r][ks * 16 + lr] = (ks < nks) ? f2bf(pv[ks][r]) : (unsigned short)0;
        #pragma unroll
        for (int kc = 0; kc < 64; kc += 32) {
            if (kc < nks * 16) {
                short8b pa = *(const short8b*)&Ps[w][lr][kc + lg * 8];
                short8b vb0 = *(const short8b*)&Vt[lr][kc + lg * 8];
                short8b vb1 = *(const short8b*)&Vt[16 + lr][kc + lg * 8];
                of0 = __builtin_amdgcn_mfma_f32_16x16x32_bf16(pa, vb0, of0, 0, 0, 0);
                of1 = __builtin_amdgcn_mfma_f32_16x16x32_bf16(pa, vb1, of1, 0, 0, 0);
            }
        }
    }
    #pragma unroll
    for (int r = 0; r < 4; ++r) {
        int q = qg0 + r;
        if (q < SS) {
            float inv = 1.0f / l_run[r];
            out[((size_t)(b * SS + q)) * DM + hh * HD + lr] = f2bf(of0[r] * inv);
            out[((size_t)(b * SS + q)) * DM + hh * HD + 16 + lr] = f2bf(of1[r] * inv);
        }
    }
}

// ---------- final: d2 conv + r4 1x1 conv + alpha blend; inputs bf16 TM ----------
__global__ __launch_bounds__(256) void final2_k(const unsigned short* __restrict__ ud1,
                                                const unsigned short* __restrict__ r3i,
                                                const float* __restrict__ d2w,
                                                const float* __restrict__ d2b,
                                                const float* __restrict__ r4w,
                                                const float* __restrict__ r4b,
                                                const float* __restrict__ alpha,
                                                float* __restrict__ out) {
    __shared__ float u_s[64][66];
    __shared__ float r_s[64][64];
    __shared__ float wd_s[64][3][12];
    __shared__ float wr_s[64][12];
    __shared__ float o_s[64][12];
    const int b = blockIdx.z, t0 = blockIdx.x * 64, tid = threadIdx.x;
    for (int u2 = tid; u2 < 66 * 8; u2 += 256) {
        int j = u2 >> 3, q = u2 & 7;
        int t = t0 + j - 1;
        short8b v = (short8b){0, 0, 0, 0, 0, 0, 0, 0};
        if (t >= 0 && t < TLEN) v = *(const short8b*)&ud1[((size_t)(b * TLEN + t)) * 64 + q * 8];
        #pragma unroll
        for (int i = 0; i < 8; ++i) u_s[q * 8 + i][j] = bf2f((unsigned short)v[i]);
    }
    for (int u2 = tid; u2 < 64 * 8; u2 += 256) {
        int j = u2 >> 3, q = u2 & 7;
        int t = t0 + j;
        short8b v = (short8b){0, 0, 0, 0, 0, 0, 0, 0};
        if (t < TLEN) v = *(const short8b*)&r3i[((size_t)(b * TLEN + t)) * 64 + q * 8];
        #pragma unroll
        for (int i = 0; i < 8; ++i) r_s[q * 8 + i][j] = bf2f((unsigned short)v[i]);
    }
    for (int idx = tid; idx < 64 * 3 * 12; idx += 256) {
        int l = idx % 12, k = (idx / 12) % 3, ci = idx / 36;
        wd_s[ci][k][l] = d2w[(l * 64 + ci) * 3 + k];
    }
    for (int idx = tid; idx < 64 * 12; idx += 256) {
        int l = idx % 12, ci = idx / 12;
        wr_s[ci][l] = r4w[l * 64 + ci];
    }
    __syncthreads();
    const int tl = tid & 63, lg = tid >> 6;
    float accD[3] = {}, accR[3] = {};
    for (int ci = 0; ci < 64; ++ci) {
        float u1v = u_s[ci][tl], u0 = (tl == 0) ? ((t0 == 0) ? 0.f : u_s[ci][tl]) : 0.f;
        (void)u0;
        float ua = (tl > 0) ? u_s[ci][tl - 1 + 1] : u_s[ci][0];
        (void)ua; (void)u1v;
        float a0 = u_s[ci][tl], a1 = u_s[ci][tl + 1], a2 = u_s[ci][tl + 2];
        float rv = r_s[ci][tl];
        #pragma unroll
        for (int c = 0; c < 3; ++c) {
            int l = lg * 3 + c;
            accD[c] += a0 * wd_s[ci][0][l] + a1 * wd_s[ci][1][l] + a2 * wd_s[ci][2][l];
            accR[c] = fmaf(rv, wr_s[ci][l], accR[c]);
        }
    }
    float al = alpha[0];
    #pragma unroll
    for (int c = 0; c < 3; ++c) {
        int l = lg * 3 + c;
        o_s[tl][l] = accD[c] + d2b[l] + al * (accR[c] + r4b[l]);
    }
    __syncthreads();
    for (int idx = tid; idx < 64 * 12; idx += 256) {
        int t = t0 + idx / 12;
        if (t < TLEN) out[((size_t)b * TLEN + t) * 12 + idx % 12] = o_s[idx / 12][idx % 12];
    }
}

extern "C" void kernel_launch(void* const* d_in, const int* in_sizes, int n_in,
                              void* d_out, int out_size, void* d_ws, size_t ws_size,
                              hipStream_t stream) {
    const float* x     = (const float*)d_in[0];
    const float* pe_w1 = (const float*)d_in[1];
    const float* pe_b1 = (const float*)d_in[2];
    const float* pe_w2 = (const float*)d_in[3];
    const float* pe_b2 = (const float*)d_in[4];
    const float* pe_pw = (const float*)d_in[5];
    const float* pe_pb = (const float*)d_in[6];
    const float* pe_g  = (const float*)d_in[7];
    const float* pe_bb = (const float*)d_in[8];
    const float* cb    = (const float*)d_in[9];
    const float* tp_w  = (const float*)d_in[10];
    const float* tp_b  = (const float*)d_in[11];
    const float* tp_g  = (const float*)d_in[12];
    const float* tp_bb = (const float*)d_in[13];
    const float* ln1_g = (const float*)d_in[14];
    const float* ln1_b = (const float*)d_in[15];
    const float* inw   = (const float*)d_in[16];
    const float* inb   = (const float*)d_in[17];
    const float* ow    = (const float*)d_in[18];
    const float* ob    = (const float*)d_in[19];
    const float* ln2_g = (const float*)d_in[20];
    const float* ln2_b = (const float*)d_in[21];
    const float* f1w   = (const float*)d_in[22];
    const float* f1b   = (const float*)d_in[23];
    const float* f2w   = (const float*)d_in[24];
    const float* f2b   = (const float*)d_in[25];
    const float* slopes= (const float*)d_in[26];
    const float* fn_g  = (const float*)d_in[27];
    const float* fn_b  = (const float*)d_in[28];
    const float* up_w  = (const float*)d_in[29];
    const float* up_b  = (const float*)d_in[30];
    const float* d1w   = (const float*)d_in[31];
    const float* d1b   = (const float*)d_in[32];
    const float* d2w   = (const float*)d_in[33];
    const float* d2b   = (const float*)d_in[34];
    const float* r1w   = (const float*)d_in[35];
    const float* r1b   = (const float*)d_in[36];
    const float* r2w   = (const float*)d_in[37];
    const float* r2b   = (const float*)d_in[38];
    const float* r3w   = (const float*)d_in[39];
    const float* r3b   = (const float*)d_in[40];
    const float* r4w   = (const float*)d_in[41];
    const float* r4b   = (const float*)d_in[42];
    const float* alpha = (const float*)d_in[43];

    float* W = (float*)d_ws;
    size_t off = 0;
    auto alloc = [&](size_t n) { float* p = W + off; off += (n + 3) & ~(size_t)3; return p; };
    const size_t M = (size_t)BATCH * SS;  // 6400
    float* A    = alloc((size_t)BATCH * DP * TLEN);      // pe2 patch-major fp32
    float* Bb   = alloc((size_t)BATCH * 64 * TLEN);      // pe1 out fp32 (B,64,T)
    float* ze   = alloc(M * DP);
    float* tx   = alloc(M * DM);
    float* hb   = alloc(M * DM);
    float* qf   = alloc(M * 3 * DM);                     // qkv/ffn1 bf16 alias + utm alias
    float* cbn  = alloc(VV);
    float* vqs  = alloc(M);
    float* upb2 = alloc(1152);
    unsigned short* zqb  = (unsigned short*)alloc(M * DP / 2);
    unsigned short* xnb  = (unsigned short*)alloc(M * DM / 2);
    unsigned short* aob  = (unsigned short*)alloc(M * DM / 2);
    unsigned short* qkvb = (unsigned short*)qf;
    unsigned short* ffb  = (unsigned short*)qf;
    unsigned short* utm  = (unsigned short*)qf;          // (B,T,128) bf16 — qkv/ffn dead by then
    unsigned short* inwb = (unsigned short*)alloc((size_t)NLAY * 3 * DM * DM / 2);
    unsigned short* owb  = (unsigned short*)alloc((size_t)NLAY * DM * DM / 2);
    unsigned short* f1wb = (unsigned short*)alloc((size_t)NLAY * 4 * DM * DM / 2);
    unsigned short* f2wb = (unsigned short*)alloc((size_t)NLAY * 4 * DM * DM / 2);
    unsigned short* tpwb = (unsigned short*)alloc((size_t)DM * DP / 2);
    unsigned short* upwb = (unsigned short*)alloc((size_t)1152 * DM / 2);
    unsigned short* r2pk = (unsigned short*)alloc((size_t)64 * 64 * 5 / 2);
    unsigned short* r3pk = (unsigned short*)alloc((size_t)64 * 64 * 3 / 2 + 2);
    unsigned short* d1pk = (unsigned short*)alloc((size_t)64 * 128 * 5 / 2);
    unsigned short* r1tm = (unsigned short*)alloc((size_t)BATCH * TLEN * 64 / 2);
    unsigned short* r2tm = (unsigned short*)alloc((size_t)BATCH * TLEN * 64 / 2);
    unsigned short* r3tm = (unsigned short*)alloc((size_t)BATCH * TLEN * 64 / 2);
    unsigned short* d1tm = (unsigned short*)alloc((size_t)BATCH * TLEN * 64 / 2);
    if (off * sizeof(float) > ws_size) return;

    float* outp = (float*)d_out;
    const dim3 cgrid(57, 1, BATCH);    // 64-t tiles
    const dim3 mgrid(29, 1, BATCH);    // 128-t tiles

    // --- weight conversions / packs ---
    tobf_k<<<(NLAY * 3 * DM * DM + 255) / 256, 256, 0, stream>>>(inw, inwb, NLAY * 3 * DM * DM);
    tobf_k<<<(NLAY * DM * DM + 255) / 256, 256, 0, stream>>>(ow, owb, NLAY * DM * DM);
    tobf_k<<<(NLAY * 4 * DM * DM + 255) / 256, 256, 0, stream>>>(f1w, f1wb, NLAY * 4 * DM * DM);
    tobf_k<<<(NLAY * 4 * DM * DM + 255) / 256, 256, 0, stream>>>(f2w, f2wb, NLAY * 4 * DM * DM);
    tobf_k<<<(DM * DP + 255) / 256, 256, 0, stream>>>(tp_w, tpwb, DM * DP);
    upwt2_k<<<(1152 * 256 + 255) / 256, 256, 0, stream>>>(up_w, up_b, upwb, upb2);
    cpack_k<<<(64 * 64 * 5 + 255) / 256, 256, 0, stream>>>(r2w, r2pk, 64, 64, 5);
    cpack_k<<<(64 * 64 * 3 + 255) / 256, 256, 0, stream>>>(r3w, r3pk, 64, 64, 3);
    cpack_k<<<(64 * 128 * 5 + 255) / 256, 256, 0, stream>>>(d1w, d1pk, 64, 128, 5);

    // --- encoder (fp32: protects VQ argmin) ---
    convg_k<12, 3, 1, 1, 0><<<cgrid, 256, 0, stream>>>(x, pe_w1, pe_b1, Bb, 64, 1);
    convg_k<64, 3, 0, 1, 1><<<dim3(57, 2, BATCH), 256, 0, stream>>>(Bb, pe_w2, pe_b2, A, 128, 1);
    cbnorm_k<<<2, 256, 0, stream>>>(cb, cbn);
    gemm_k<0, 0><<<dim3(2, M / 64), 256, 0, stream>>>(A, pe_pw, pe_pb, nullptr, tx, M, DP, DP * PP);
    ln128_k<<<M, 128, 0, stream>>>(tx, pe_g, pe_bb, ze);
    vq2_k<<<M / 32, 256, 0, stream>>>(ze, cb, cbn, zqb, vqs);
    vqreduce_k<<<1, 256, 0, stream>>>(vqs, outp + (size_t)BATCH * TLEN * LEADS);

    // --- residual CNN (r1 fp32 compute -> bf16 TM; r2/r3 MFMA) ---
    convg_k<12, 7, 1, 1, 2><<<cgrid, 256, 0, stream>>>(x, r1w, r1b, (float*)r1tm, 64, 3);
    mfconv_k<64, 5, 2><<<mgrid, 256, 0, stream>>>(r1tm, r2pk, r2b, r2tm);
    mfconv_k<64, 3, 1><<<mgrid, 256, 0, stream>>>(r2tm, r3pk, r3b, r3tm);

    // --- token projection + LN ---
    bgemm_k<0, 0, 0><<<dim3(DM / 128, M / 128), 256, 0, stream>>>(zqb, tpwb, tp_b, nullptr, tx, M, DM, DP);
    lnw_k<0><<<M / 4, 256, 0, stream>>>(tx, tp_g, tp_bb, hb);

    // --- transformer ---
    for (int l = 0; l < NLAY; ++l) {
        lnw_k<1><<<M / 4, 256, 0, stream>>>(hb, ln1_g + l * DM, ln1_b + l * DM, xnb);
        bgemm_k<0, 0, 1><<<dim3(3 * DM / 128, M / 128), 256, 0, stream>>>(
            xnb, inwb + (size_t)l * 3 * DM * DM, inb + l * 3 * DM, nullptr, qkvb, M, 3 * DM, DM);
        fattn_k<<<dim3((SS + 63) / 64, NH, BATCH), 256, 0, stream>>>(qkvb, slopes + l * NH, aob);
        bgemm_k<0, 1, 0><<<dim3(DM / 128, M / 128), 256, 0, stream>>>(
            aob, owb + (size_t)l * DM * DM, ob + l * DM, hb, hb, M, DM, DM);
        lnw_k<1><<<M / 4, 256, 0, stream>>>(hb, ln2_g + l * DM, ln2_b + l * DM, xnb);
        bgemm_k<1, 0, 1><<<dim3(4 * DM / 128, M / 128), 256, 0, stream>>>(
            xnb, f1wb + (size_t)l * 4 * DM * DM, f1b + l * 4 * DM, nullptr, ffb, M, 4 * DM, DM);
        bgemm_k<0, 1, 0><<<dim3(DM / 128, M / 128), 256, 0, stream>>>(
            ffb, f2wb + (size_t)l * 4 * DM * DM, f2b + l * DM, hb, hb, M, DM, 4 * DM);
    }
    lnw_k<1><<<M / 4, 256, 0, stream>>>(hb, fn_g, fn_b, xnb);

    // --- decoder: upproj bgemm -> bf16 (B,T,128) TM, then d1 MFMA conv ---
    bgemm_k<1, 0, 1><<<dim3(1152 / 128, M / 128), 256, 0, stream>>>(xnb, upwb, upb2, nullptr, utm, M, 1152, DM);
    mfconv_k<128, 5, 2><<<mgrid, 256, 0, stream>>>(utm, d1pk, d1b, d1tm);

    // --- fused d2 conv + r4 conv + alpha blend ---
    final2_k<<<cgrid, 256, 0, stream>>>(d1tm, r3tm, d2w, d2b, r4w, r4b, alpha, outp);
}

// Round 6
// 902.418 us; speedup vs baseline: 8.4655x; 1.1497x over previous
//
#include <hip/hip_runtime.h>
#include <hip/hip_bf16.h>
#include <math.h>

#define BATCH 16
#define TLEN 3600
#define LEADS 12
#define PP 9
#define SS 400
#define DP 128
#define DM 256
#define NH 8
#define HD 32
#define NLAY 6
#define VV 512
#define RH 64

typedef __attribute__((ext_vector_type(8))) short short8b;
typedef __attribute__((ext_vector_type(4))) float f32x4;

__device__ __forceinline__ float gelu_f(float x) {
    return 0.5f * x * (1.0f + erff(x * 0.70710678118654752f));
}

__device__ __forceinline__ unsigned short f2bf(float f) {
    union { float f; unsigned u; } v; v.f = f;
    return (unsigned short)((v.u + 0x7FFFu + ((v.u >> 16) & 1u)) >> 16);
}

__device__ __forceinline__ float bf2f(unsigned short h) {
    union { unsigned u; float f; } v; v.u = ((unsigned)h) << 16; return v.f;
}

// ---------- block reduction helpers ----------
__device__ __forceinline__ float block_sum_256(float v, float* sm) {
    #pragma unroll
    for (int o = 32; o > 0; o >>= 1) v += __shfl_down(v, o);
    __syncthreads();
    if ((threadIdx.x & 63) == 0) sm[threadIdx.x >> 6] = v;
    __syncthreads();
    return sm[0] + sm[1] + sm[2] + sm[3];
}

__device__ __forceinline__ float block_sum_128(float v, float* sm) {
    #pragma unroll
    for (int o = 32; o > 0; o >>= 1) v += __shfl_down(v, o);
    __syncthreads();
    if ((threadIdx.x & 63) == 0) sm[threadIdx.x >> 6] = v;
    __syncthreads();
    return sm[0] + sm[1];
}

// ---------- fused pe1 + r1: both read x (B,T,12) ----------
// pe1: K=3 pad=1 -> out1 (B,64,T) fp32 GELU.  r1: K=7 pad=3 -> out7 (B,T,64) bf16 TM GELU.
__global__ __launch_bounds__(256, 4) void enc1_k(const float* __restrict__ x,
                                                 const float* __restrict__ w1,
                                                 const float* __restrict__ b1,
                                                 const float* __restrict__ w7,
                                                 const float* __restrict__ b7,
                                                 float* __restrict__ out1,
                                                 unsigned short* __restrict__ out7) {
    __shared__ __align__(16) float xs[12][80];      // j=0..69 -> t = t0 + j - 3
    __shared__ float w1s[12][3][64];
    __shared__ float w7s[12][7][64];
    const int b = blockIdx.y, t0 = blockIdx.x * 64, tid = threadIdx.x;
    const int tx = tid & 15, ty = tid >> 4;
    for (int idx = tid; idx < 70 * 12; idx += 256) {
        int j = idx / 12, ci = idx - j * 12;
        int t = t0 + j - 3;
        xs[ci][j] = (t >= 0 && t < TLEN) ? x[((size_t)b * TLEN + t) * 12 + ci] : 0.f;
    }
    for (int idx = tid; idx < 12 * 3 * 64; idx += 256) {
        int co = idx & 63; int rest = idx >> 6; int k = rest % 3; int ci = rest / 3;
        w1s[ci][k][co] = w1[(co * 12 + ci) * 3 + k];
    }
    for (int idx = tid; idx < 12 * 7 * 64; idx += 256) {
        int co = idx & 63; int rest = idx >> 6; int k = rest % 7; int ci = rest / 7;
        w7s[ci][k][co] = w7[(co * 12 + ci) * 7 + k];
    }
    __syncthreads();
    float a1[4][4] = {}, a7[4][4] = {};
    #pragma unroll 2
    for (int ci = 0; ci < 12; ++ci) {
        float tv[12];
        *(float4*)&tv[0] = *(const float4*)&xs[ci][tx * 4];
        *(float4*)&tv[4] = *(const float4*)&xs[ci][tx * 4 + 4];
        *(float4*)&tv[8] = *(const float4*)&xs[ci][tx * 4 + 8];
        #pragma unroll
        for (int k = 0; k < 7; ++k) {                 // r1: j = lt + k
            float4 wv = *(const float4*)&w7s[ci][k][ty * 4];
            #pragma unroll
            for (int j = 0; j < 4; ++j) {
                float iv = tv[j + k];
                a7[0][j] = fmaf(wv.x, iv, a7[0][j]);
                a7[1][j] = fmaf(wv.y, iv, a7[1][j]);
                a7[2][j] = fmaf(wv.z, iv, a7[2][j]);
                a7[3][j] = fmaf(wv.w, iv, a7[3][j]);
            }
        }
        #pragma unroll
        for (int k = 0; k < 3; ++k) {                 // pe1: j = lt + k + 2
            float4 wv = *(const float4*)&w1s[ci][k][ty * 4];
            #pragma unroll
            for (int j = 0; j < 4; ++j) {
                float iv = tv[j + k + 2];
                a1[0][j] = fmaf(wv.x, iv, a1[0][j]);
                a1[1][j] = fmaf(wv.y, iv, a1[1][j]);
                a1[2][j] = fmaf(wv.z, iv, a1[2][j]);
                a1[3][j] = fmaf(wv.w, iv, a1[3][j]);
            }
        }
    }
    const bool full = (t0 + 64 <= TLEN);
    #pragma unroll
    for (int i = 0; i < 4; ++i) {                     // pe1 out: (B,64,T)
        int co = ty * 4 + i;
        float bs = b1[co];
        float* orow = out1 + ((size_t)(b * 64 + co)) * TLEN;
        if (full) {
            float4 o4;
            o4.x = gelu_f(a1[i][0] + bs); o4.y = gelu_f(a1[i][1] + bs);
            o4.z = gelu_f(a1[i][2] + bs); o4.w = gelu_f(a1[i][3] + bs);
            *(float4*)&orow[t0 + tx * 4] = o4;
        } else {
            #pragma unroll
            for (int j = 0; j < 4; ++j) {
                int t = t0 + tx * 4 + j;
                if (t < TLEN) orow[t] = gelu_f(a1[i][j] + bs);
            }
        }
    }
    float bv0 = b7[ty * 4], bv1 = b7[ty * 4 + 1], bv2 = b7[ty * 4 + 2], bv3 = b7[ty * 4 + 3];
    #pragma unroll
    for (int j = 0; j < 4; ++j) {                     // r1 out: (B,T,64) bf16
        int t = t0 + tx * 4 + j;
        if (t < TLEN) {
            unsigned long long pk =
                  (unsigned long long)f2bf(gelu_f(a7[0][j] + bv0))
                | ((unsigned long long)f2bf(gelu_f(a7[1][j] + bv1)) << 16)
                | ((unsigned long long)f2bf(gelu_f(a7[2][j] + bv2)) << 32)
                | ((unsigned long long)f2bf(gelu_f(a7[3][j] + bv3)) << 48);
            *(unsigned long long*)&out7[((size_t)(b * TLEN + t)) * 64 + ty * 4] = pk;
        }
    }
}

// ---------- generic LDS-staged implicit-GEMM conv (fp32) ----------
// LAYOUT 0: in(B,CI,T). LAYOUT 1: in(B,T,CI).
// OL 0: out(B,Co,T) fp32. OL 1: out(B,S,Co*9) patch-major fp32.
template <int CI, int K, int LAYOUT, int ACT, int OL>
__global__ __launch_bounds__(256) void convg_k(const float* __restrict__ in,
                                               const float* __restrict__ w,
                                               const float* __restrict__ bias,
                                               float* __restrict__ out,
                                               int Co, int pad) {
    constexpr int CHUNK = (CI % 16 == 0) ? 16 : CI;
    constexpr int TT = 64 + K - 1;
    constexpr int NV = (K + 6) / 4;
    constexpr int TTP = 64 + 4 * NV;
    __shared__ __align__(16) float in_s[CHUNK][TTP];
    __shared__ __align__(16) float w_s[CHUNK][K][64];
    const int b = blockIdx.z;
    const int co0 = blockIdx.y * 64;
    const int t0 = blockIdx.x * 64;
    const int tid = threadIdx.x;
    const int tx = tid & 15, ty = tid >> 4;
    float acc[4][4] = {};
    for (int c0 = 0; c0 < CI; c0 += CHUNK) {
        __syncthreads();
        for (int idx = tid; idx < CHUNK * TT; idx += 256) {
            int ci = idx / TT, j = idx - ci * TT;
            int t = t0 + j - pad;
            float v = 0.f;
            if (t >= 0 && t < TLEN) {
                if (LAYOUT == 0) v = in[((size_t)(b * CI + c0 + ci)) * TLEN + t];
                else v = in[((size_t)b * TLEN + t) * CI + (c0 + ci)];
            }
            in_s[ci][j] = v;
        }
        for (int idx = tid; idx < CHUNK * K * 64; idx += 256) {
            int co = idx & 63; int rest = idx >> 6; int k = rest % K; int ci = rest / K;
            w_s[ci][k][co] = w[((size_t)(co0 + co) * CI + (c0 + ci)) * K + k];
        }
        __syncthreads();
        #pragma unroll
        for (int ci = 0; ci < CHUNK; ++ci) {
            float tv[NV * 4];
            #pragma unroll
            for (int vv = 0; vv < NV; ++vv)
                *(float4*)&tv[vv * 4] = *(const float4*)&in_s[ci][tx * 4 + vv * 4];
            #pragma unroll
            for (int k = 0; k < K; ++k) {
                float4 wv = *(const float4*)&w_s[ci][k][ty * 4];
                #pragma unroll
                for (int j = 0; j < 4; ++j) {
                    float iv = tv[j + k];
                    acc[0][j] = fmaf(wv.x, iv, acc[0][j]);
                    acc[1][j] = fmaf(wv.y, iv, acc[1][j]);
                    acc[2][j] = fmaf(wv.z, iv, acc[2][j]);
                    acc[3][j] = fmaf(wv.w, iv, acc[3][j]);
                }
            }
        }
    }
    if (OL == 0) {
        const bool full = (t0 + 64 <= TLEN);
        #pragma unroll
        for (int i = 0; i < 4; ++i) {
            int co = co0 + ty * 4 + i;
            float bs = bias[co];
            float* orow = out + ((size_t)(b * Co + co)) * TLEN;
            if (full) {
                float4 o4;
                float vv0 = acc[i][0] + bs, vv1 = acc[i][1] + bs, vv2 = acc[i][2] + bs, vv3 = acc[i][3] + bs;
                if (ACT) { vv0 = gelu_f(vv0); vv1 = gelu_f(vv1); vv2 = gelu_f(vv2); vv3 = gelu_f(vv3); }
                o4.x = vv0; o4.y = vv1; o4.z = vv2; o4.w = vv3;
                *(float4*)&orow[t0 + tx * 4] = o4;
            } else {
                #pragma unroll
                for (int j = 0; j < 4; ++j) {
                    int t = t0 + tx * 4 + j;
                    if (t < TLEN) {
                        float v = acc[i][j] + bs;
                        if (ACT) v = gelu_f(v);
                        orow[t] = v;
                    }
                }
            }
        }
    } else {
        #pragma unroll
        for (int i = 0; i < 4; ++i) {
            int co = co0 + ty * 4 + i;
            float bs = bias[co];
            #pragma unroll
            for (int j = 0; j < 4; ++j) {
                int t = t0 + tx * 4 + j;
                if (t < TLEN) {
                    float v = acc[i][j] + bs;
                    if (ACT) v = gelu_f(v);
                    int s = t / PP, kk = t - s * PP;
                    out[((size_t)(b * SS + s)) * (size_t)(Co * PP) + co * PP + kk] = v;
                }
            }
        }
    }
}

// ---------- bf16 MFMA implicit-GEMM conv ----------
template <int CI, int K, int PAD>
__global__ __launch_bounds__(256) void mfconv_k(const unsigned short* __restrict__ in,
                                                const unsigned short* __restrict__ wpk,
                                                const float* __restrict__ bias,
                                                unsigned short* __restrict__ out) {
    constexpr int CIC = (CI > 64) ? 64 : CI;
    constexpr int NCH = CI / CIC;
    constexpr int TROWS = 128 + K - 1;
    constexpr int CQ = CIC / 8;
    __shared__ __align__(16) unsigned short in_s[TROWS][CIC + 8];
    __shared__ __align__(16) unsigned short w_s[K][64][CIC + 8];
    const int b = blockIdx.z;
    const int t0 = blockIdx.x * 128;
    const int tid = threadIdx.x;
    const int w = tid >> 6, lane = tid & 63;
    const int fr = lane & 15, kg = (lane >> 4) * 8;
    f32x4 acc[2][4];
    #pragma unroll
    for (int i = 0; i < 2; ++i)
        #pragma unroll
        for (int j = 0; j < 4; ++j) acc[i][j] = (f32x4){0.f, 0.f, 0.f, 0.f};
    for (int ch = 0; ch < NCH; ++ch) {
        const int c0 = ch * CIC;
        if (ch) __syncthreads();
        for (int u = tid; u < TROWS * CQ; u += 256) {
            int row = u / CQ, q = u - row * CQ;
            int t = t0 + row - PAD;
            short8b v = (short8b){0, 0, 0, 0, 0, 0, 0, 0};
            if (t >= 0 && t < TLEN)
                v = *(const short8b*)&in[((size_t)(b * TLEN + t)) * CI + c0 + q * 8];
            *(short8b*)&in_s[row][q * 8] = v;
        }
        for (int u = tid; u < K * 64 * CQ; u += 256) {
            int q = u % CQ; int rest = u / CQ; int co = rest & 63; int k = rest >> 6;
            *(short8b*)&w_s[k][co][q * 8] =
                *(const short8b*)&wpk[((size_t)(k * 64 + co)) * CI + c0 + q * 8];
        }
        __syncthreads();
        #pragma unroll
        for (int k = 0; k < K; ++k) {
            #pragma unroll
            for (int c32 = 0; c32 < CIC / 32; ++c32) {
                short8b a0 = *(const short8b*)&in_s[w * 32 + fr + k][c32 * 32 + kg];
                short8b a1 = *(const short8b*)&in_s[w * 32 + 16 + fr + k][c32 * 32 + kg];
                short8b b0 = *(const short8b*)&w_s[k][fr][c32 * 32 + kg];
                short8b b1 = *(const short8b*)&w_s[k][16 + fr][c32 * 32 + kg];
                short8b b2 = *(const short8b*)&w_s[k][32 + fr][c32 * 32 + kg];
                short8b b3 = *(const short8b*)&w_s[k][48 + fr][c32 * 32 + kg];
                acc[0][0] = __builtin_amdgcn_mfma_f32_16x16x32_bf16(a0, b0, acc[0][0], 0, 0, 0);
                acc[0][1] = __builtin_amdgcn_mfma_f32_16x16x32_bf16(a0, b1, acc[0][1], 0, 0, 0);
                acc[0][2] = __builtin_amdgcn_mfma_f32_16x16x32_bf16(a0, b2, acc[0][2], 0, 0, 0);
                acc[0][3] = __builtin_amdgcn_mfma_f32_16x16x32_bf16(a0, b3, acc[0][3], 0, 0, 0);
                acc[1][0] = __builtin_amdgcn_mfma_f32_16x16x32_bf16(a1, b0, acc[1][0], 0, 0, 0);
                acc[1][1] = __builtin_amdgcn_mfma_f32_16x16x32_bf16(a1, b1, acc[1][1], 0, 0, 0);
                acc[1][2] = __builtin_amdgcn_mfma_f32_16x16x32_bf16(a1, b2, acc[1][2], 0, 0, 0);
                acc[1][3] = __builtin_amdgcn_mfma_f32_16x16x32_bf16(a1, b3, acc[1][3], 0, 0, 0);
            }
        }
    }
    const int orow = (lane >> 4) * 4, ocol = lane & 15;
    #pragma unroll
    for (int i = 0; i < 2; ++i)
        #pragma unroll
        for (int j = 0; j < 4; ++j) {
            const int co = j * 16 + ocol;
            const float bv = bias[co];
            #pragma unroll
            for (int r = 0; r < 4; ++r) {
                int t = t0 + w * 32 + i * 16 + orow + r;
                if (t < TLEN)
                    out[((size_t)(b * TLEN + t)) * 64 + co] = f2bf(gelu_f(acc[i][j][r] + bv));
            }
        }
}

// ---------- split-K fp32 GEMM for patch projection: partials, no bias ----------
__global__ __launch_bounds__(256) void gemmsk_k(const float* __restrict__ A,
                                                const float* __restrict__ W,
                                                float* __restrict__ Cp,
                                                int M, int N, int K, int KS) {
    __shared__ float As[16][65];
    __shared__ float Bs[16][65];
    const int bm = blockIdx.y * 64, bn = blockIdx.x * 64, z = blockIdx.z;
    const int tid = threadIdx.x;
    const int tx = tid & 15, ty = tid >> 4;
    float acc[4][4] = {};
    const int lr = tid >> 2;
    const int lc = (tid & 3) * 4;
    const int kb = z * KS;
    for (int k0 = kb; k0 < kb + KS; k0 += 16) {
        float4 av = *(const float4*)&A[(size_t)(bm + lr) * K + k0 + lc];
        As[lc + 0][lr] = av.x; As[lc + 1][lr] = av.y; As[lc + 2][lr] = av.z; As[lc + 3][lr] = av.w;
        float4 wv = *(const float4*)&W[(size_t)(bn + lr) * K + k0 + lc];
        Bs[lc + 0][lr] = wv.x; Bs[lc + 1][lr] = wv.y; Bs[lc + 2][lr] = wv.z; Bs[lc + 3][lr] = wv.w;
        __syncthreads();
        #pragma unroll
        for (int kk = 0; kk < 16; ++kk) {
            float a[4], bv[4];
            #pragma unroll
            for (int i = 0; i < 4; ++i) a[i] = As[kk][ty * 4 + i];
            #pragma unroll
            for (int j = 0; j < 4; ++j) bv[j] = Bs[kk][tx * 4 + j];
            #pragma unroll
            for (int i = 0; i < 4; ++i)
                #pragma unroll
                for (int j = 0; j < 4; ++j) acc[i][j] = fmaf(a[i], bv[j], acc[i][j]);
        }
        __syncthreads();
    }
    float* Cz = Cp + (size_t)z * M * N;
    #pragma unroll
    for (int i = 0; i < 4; ++i) {
        int m = bm + ty * 4 + i;
        #pragma unroll
        for (int j = 0; j < 4; ++j) {
            int n = bn + tx * 4 + j;
            Cz[(size_t)m * N + n] = acc[i][j];
        }
    }
}

// ---------- bf16 MFMA GEMM ----------
template <int ACT, int RES, int OUTBF>
__global__ __launch_bounds__(256) void bgemm_k(const unsigned short* __restrict__ A,
                                               const unsigned short* __restrict__ W,
                                               const float* __restrict__ bias,
                                               const float* __restrict__ res,
                                               void* __restrict__ Cv,
                                               int M, int N, int K) {
    __shared__ __align__(16) unsigned short As[128][40];
    __shared__ __align__(16) unsigned short Bs[128][40];
    const int tid = threadIdx.x;
    const int gm0 = blockIdx.y * 128, gn0 = blockIdx.x * 128;
    const int w = tid >> 6, lane = tid & 63;
    const int wr0 = (w >> 1) * 64, wc0 = (w & 1) * 64;
    const int srow = tid >> 1, sc = (tid & 1) * 16;
    const unsigned short* ga = A + (size_t)(gm0 + srow) * K + sc;
    const unsigned short* gb = W + (size_t)(gn0 + srow) * K + sc;
    short8b ra0 = *(const short8b*)(ga), ra1 = *(const short8b*)(ga + 8);
    short8b rb0 = *(const short8b*)(gb), rb1 = *(const short8b*)(gb + 8);
    f32x4 acc[4][4];
    #pragma unroll
    for (int i = 0; i < 4; ++i)
        #pragma unroll
        for (int j = 0; j < 4; ++j) acc[i][j] = (f32x4){0.f, 0.f, 0.f, 0.f};
    const int fr = lane & 15, kg = (lane >> 4) * 8;
    const int nstep = K >> 5;
    for (int s = 0; s < nstep; ++s) {
        __syncthreads();
        *(short8b*)&As[srow][sc] = ra0; *(short8b*)&As[srow][sc + 8] = ra1;
        *(short8b*)&Bs[srow][sc] = rb0; *(short8b*)&Bs[srow][sc + 8] = rb1;
        __syncthreads();
        if (s + 1 < nstep) {
            ga += 32; gb += 32;
            ra0 = *(const short8b*)(ga); ra1 = *(const short8b*)(ga + 8);
            rb0 = *(const short8b*)(gb); rb1 = *(const short8b*)(gb + 8);
        }
        short8b af[4], bf[4];
        #pragma unroll
        for (int i = 0; i < 4; ++i) {
            af[i] = *(const short8b*)&As[wr0 + i * 16 + fr][kg];
            bf[i] = *(const short8b*)&Bs[wc0 + i * 16 + fr][kg];
        }
        #pragma unroll
        for (int i = 0; i < 4; ++i)
            #pragma unroll
            for (int j = 0; j < 4; ++j)
                acc[i][j] = __builtin_amdgcn_mfma_f32_16x16x32_bf16(af[i], bf[j], acc[i][j], 0, 0, 0);
    }
    const int orow = (lane >> 4) * 4, ocol = lane & 15;
    #pragma unroll
    for (int i = 0; i < 4; ++i) {
        #pragma unroll
        for (int j = 0; j < 4; ++j) {
            const int colg = gn0 + wc0 + j * 16 + ocol;
            const float bsv = bias[colg];
            #pragma unroll
            for (int r = 0; r < 4; ++r) {
                const int rowg = gm0 + wr0 + i * 16 + orow + r;
                float v = acc[i][j][r] + bsv;
                if (ACT) v = gelu_f(v);
                if (RES) v += res[(size_t)rowg * N + colg];
                if (OUTBF) ((unsigned short*)Cv)[(size_t)rowg * N + colg] = f2bf(v);
                else ((float*)Cv)[(size_t)rowg * N + colg] = v;
            }
        }
    }
}

// ---------- weight fp32 -> bf16 ----------
__global__ void tobf_k(const float* __restrict__ in, unsigned short* __restrict__ out, int n) {
    int i = blockIdx.x * 256 + threadIdx.x;
    if (i < n) out[i] = f2bf(in[i]);
}

// conv weight (Co,CI,K) -> bf16 [k][co][ci]
__global__ void cpack_k(const float* __restrict__ w, unsigned short* __restrict__ out,
                        int Co, int CI, int K) {
    int idx = blockIdx.x * 256 + threadIdx.x;
    if (idx < Co * CI * K) {
        int ci = idx % CI; int rest = idx / CI; int co = rest % Co; int k = rest / Co;
        out[idx] = f2bf(w[((size_t)co * CI + ci) * K + k]);
    }
}

// up_w (256,128,9) -> bf16 W'[n][d], n = k*128+o; also expand bias
__global__ void upwt2_k(const float* __restrict__ w, const float* __restrict__ bsrc,
                        unsigned short* __restrict__ out, float* __restrict__ b2) {
    int idx = blockIdx.x * 256 + threadIdx.x;
    if (idx < 1152 * 256) {
        int d = idx & 255, n = idx >> 8;
        int o = n & 127, k = n >> 7;
        out[(size_t)n * 256 + d] = f2bf(w[(size_t)d * 1152 + o * 9 + k]);
    }
    if (idx < 1152) b2[idx] = bsrc[idx & 127];
}

// ---------- LayerNorm over 128 with 4-way split-K partial sum + bias ----------
__global__ __launch_bounds__(128) void ln128s_k(const float* __restrict__ part,
                                                const float* __restrict__ bias,
                                                const float* __restrict__ g,
                                                const float* __restrict__ bb,
                                                float* __restrict__ out,
                                                int M) {
    int row = blockIdx.x, tid = threadIdx.x;
    __shared__ float sm[2];
    size_t stride = (size_t)M * DP;
    size_t base = (size_t)row * DP + tid;
    float v = part[base] + part[base + stride] + part[base + 2 * stride] + part[base + 3 * stride]
            + bias[tid];
    float mean = block_sum_128(v, sm) * (1.0f / DP);
    float d = v - mean;
    float var = block_sum_128(d * d, sm) * (1.0f / DP);
    out[(size_t)row * DP + tid] = d * rsqrtf(var + 1e-5f) * g[tid] + bb[tid];
}

// ---------- codebook norms ----------
__global__ void cbnorm_k(const float* __restrict__ cb, float* __restrict__ cbn) {
    int c = blockIdx.x * 256 + threadIdx.x;
    if (c < VV) {
        const float* cr = cb + (size_t)c * DP;
        float s = 0;
        for (int i = 0; i < DP; ++i) s += cr[i] * cr[i];
        cbn[c] = s;
    }
}

// ---------- VQ: tiled distance GEMM + argmin + commit partials; zq bf16 ----------
__global__ __launch_bounds__(256) void vq2_k(const float* __restrict__ ze,
                                             const float* __restrict__ cb,
                                             const float* __restrict__ cbn,
                                             unsigned short* __restrict__ zqb,
                                             float* __restrict__ vqs) {
    __shared__ __align__(16) float z_s[32][132];
    __shared__ __align__(16) float cb_s[64][132];
    __shared__ float cbn_s[64];
    __shared__ float bval[256];
    __shared__ int bidx[256];
    __shared__ int tok_s[32];
    __shared__ float psum[256];
    const int tid = threadIdx.x;
    const int r0 = blockIdx.x * 32;
    const int r = tid >> 3, cs = tid & 7;
    for (int idx = tid; idx < 32 * 128; idx += 256) {
        int rr = idx >> 7, cc = idx & 127;
        z_s[rr][cc] = ze[((size_t)(r0 + rr)) * DP + cc];
    }
    float best = 1e30f; int bi = 0;
    for (int c0 = 0; c0 < VV; c0 += 64) {
        __syncthreads();
        for (int idx = tid; idx < 64 * 128; idx += 256) {
            int rr = idx >> 7, cc = idx & 127;
            cb_s[rr][cc] = cb[((size_t)(c0 + rr)) * DP + cc];
        }
        if (tid < 64) cbn_s[tid] = cbn[c0 + tid];
        __syncthreads();
        float dot[8] = {};
        for (int i = 0; i < 128; i += 4) {
            float4 zv = *(const float4*)&z_s[r][i];
            #pragma unroll
            for (int j = 0; j < 8; ++j) {
                float4 cv = *(const float4*)&cb_s[cs + 8 * j][i];
                dot[j] += zv.x * cv.x + zv.y * cv.y + zv.z * cv.z + zv.w * cv.w;
            }
        }
        #pragma unroll
        for (int j = 0; j < 8; ++j) {
            float dist = cbn_s[cs + 8 * j] - 2.0f * dot[j];
            if (dist < best) { best = dist; bi = c0 + cs + 8 * j; }
        }
    }
    bval[tid] = best; bidx[tid] = bi;
    __syncthreads();
    if (cs == 0) {
        float bv = bval[tid]; int bix = bidx[tid];
        #pragma unroll
        for (int j = 1; j < 8; ++j) {
            float v = bval[tid + j]; int ix = bidx[tid + j];
            if (v < bv || (v == bv && ix < bix)) { bv = v; bix = ix; }
        }
        tok_s[r] = bix;
    }
    __syncthreads();
    int tok = tok_s[r];
    float part = 0;
    const float* cr = cb + (size_t)tok * DP + cs * 16;
    #pragma unroll
    for (int i = 0; i < 16; i += 4) {
        float4 qv = *(const float4*)(cr + i);
        float4 zv = *(const float4*)&z_s[r][cs * 16 + i];
        float dx = qv.x - zv.x, dy = qv.y - zv.y, dz = qv.z - zv.z, dw = qv.w - zv.w;
        part += dx * dx + dy * dy + dz * dz + dw * dw;
        size_t ob = ((size_t)(r0 + r)) * DP + cs * 16 + i;
        zqb[ob + 0] = f2bf(qv.x); zqb[ob + 1] = f2bf(qv.y);
        zqb[ob + 2] = f2bf(qv.z); zqb[ob + 3] = f2bf(qv.w);
    }
    psum[tid] = part;
    __syncthreads();
    if (cs == 0) {
        float s = 0;
        #pragma unroll
        for (int j = 0; j < 8; ++j) s += psum[tid + j];
        vqs[r0 + r] = s;
    }
}

__global__ void vqreduce_k(const float* __restrict__ vqs, float* __restrict__ out) {
    float s = 0;
    for (int i = threadIdx.x; i < BATCH * SS; i += 256) s += vqs[i];
    __shared__ float sm[4];
    s = block_sum_256(s, sm);
    if (threadIdx.x == 0) out[0] = s * (1.25f / (float)(BATCH * SS * DP));
}

// ---------- wave-per-row LayerNorm over 256 (shfl-only) ----------
template <int OUTBF>
__global__ __launch_bounds__(256) void lnw_k(const float* __restrict__ in,
                                             const float* __restrict__ g,
                                             const float* __restrict__ bb,
                                             void* __restrict__ out) {
    const int row = blockIdx.x * 4 + (threadIdx.x >> 6);
    const int lane = threadIdx.x & 63;
    float4 v = *(const float4*)&in[(size_t)row * DM + lane * 4];
    float s = v.x + v.y + v.z + v.w;
    #pragma unroll
    for (int o = 1; o < 64; o <<= 1) s += __shfl_xor(s, o);
    float mean = s * (1.0f / DM);
    float dx = v.x - mean, dy = v.y - mean, dz = v.z - mean, dw = v.w - mean;
    float vv = dx * dx + dy * dy + dz * dz + dw * dw;
    #pragma unroll
    for (int o = 1; o < 64; o <<= 1) vv += __shfl_xor(vv, o);
    float rstd = rsqrtf(vv * (1.0f / DM) + 1e-5f);
    float4 gv = *(const float4*)&g[lane * 4];
    float4 bv = *(const float4*)&bb[lane * 4];
    float o0 = dx * rstd * gv.x + bv.x;
    float o1 = dy * rstd * gv.y + bv.y;
    float o2 = dz * rstd * gv.z + bv.z;
    float o3 = dw * rstd * gv.w + bv.w;
    if (OUTBF) {
        unsigned long long pk = (unsigned long long)f2bf(o0)
                              | ((unsigned long long)f2bf(o1) << 16)
                              | ((unsigned long long)f2bf(o2) << 32)
                              | ((unsigned long long)f2bf(o3) << 48);
        *(unsigned long long*)((unsigned short*)out + (size_t)row * DM + lane * 4) = pk;
    } else {
        float4 o4; o4.x = o0; o4.y = o1; o4.z = o2; o4.w = o3;
        *(float4*)((float*)out + (size_t)row * DM + lane * 4) = o4;
    }
}

// ---------- fused flash MFMA attention ----------
__global__ __launch_bounds__(256) void fattn_k(const unsigned short* __restrict__ qkv,
                                               const float* __restrict__ slopes,
                                               unsigned short* __restrict__ out) {
    __shared__ __align__(16) unsigned short Qs[64][40];
    __shared__ __align__(16) unsigned short Ks[64][40];
    __shared__ __align__(16) unsigned short Vt[32][72];
    __shared__ __align__(16) unsigned short Ps[4][16][72];
    const int qb = blockIdx.x, hh = blockIdx.y, b = blockIdx.z;
    const int tid = threadIdx.x;
    const int w = tid >> 6, lane = tid & 63;
    const int lr = lane & 15, lg = lane >> 4;
    const float slope = fabsf(slopes[hh]);
    const unsigned short* base = qkv + (size_t)b * SS * (3 * DM);
    {
        int row = tid >> 2, c = (tid & 3) * 8;
        int q = qb * 64 + row; q = q < SS ? q : SS - 1;
        *(short8b*)&Qs[row][c] = *(const short8b*)(base + (size_t)q * (3 * DM) + hh * HD + c);
    }
    __syncthreads();
    const short8b qa = *(const short8b*)&Qs[w * 16 + lr][lg * 8];
    float m_run[4] = {-1e30f, -1e30f, -1e30f, -1e30f};
    float l_run[4] = {0.f, 0.f, 0.f, 0.f};
    f32x4 of0 = (f32x4){0.f, 0.f, 0.f, 0.f}, of1 = (f32x4){0.f, 0.f, 0.f, 0.f};
    const int qg0 = qb * 64 + w * 16 + lg * 4;
    for (int kt = 0; kt < SS; kt += 64) {
        const int tl = (SS - kt) < 64 ? (SS - kt) : 64;
        const int nks = tl >> 4;
        __syncthreads();
        {
            int row = tid >> 2, c = (tid & 3) * 8;
            if (row < tl) {
                *(short8b*)&Ks[row][c] =
                    *(const short8b*)(base + (size_t)(kt + row) * (3 * DM) + DM + hh * HD + c);
                short8b v8 = *(const short8b*)(base + (size_t)(kt + row) * (3 * DM) + 2 * DM + hh * HD + c);
                #pragma unroll
                for (int j = 0; j < 8; ++j) Vt[c + j][row] = ((unsigned short*)&v8)[j];
            }
        }
        __syncthreads();
        f32x4 sf[4];
        #pragma unroll
        for (int ks = 0; ks < 4; ++ks) {
            if (ks < nks) {
                short8b kb = *(const short8b*)&Ks[ks * 16 + lr][lg * 8];
                sf[ks] = __builtin_amdgcn_mfma_f32_16x16x32_bf16(qa, kb, (f32x4){0.f, 0.f, 0.f, 0.f}, 0, 0, 0);
            }
        }
        float pv[4][4];
        #pragma unroll
        for (int r = 0; r < 4; ++r) {
            float tmax = -1e30f;
            #pragma unroll
            for (int ks = 0; ks < 4; ++ks) {
                if (ks < nks) {
                    float sv = sf[ks][r] * 0.17677669529663687f
                             - slope * fabsf((float)(qg0 + r - (kt + ks * 16 + lr)));
                    pv[ks][r] = sv;
                    tmax = fmaxf(tmax, sv);
                }
            }
            #pragma unroll
            for (int o = 1; o < 16; o <<= 1) tmax = fmaxf(tmax, __shfl_xor(tmax, o));
            float mnew = fmaxf(m_run[r], tmax);
            float sc = __expf(m_run[r] - mnew);
            m_run[r] = mnew;
            float tsum = 0.f;
            #pragma unroll
            for (int ks = 0; ks < 4; ++ks) {
                if (ks < nks) {
                    float e = __expf(pv[ks][r] - mnew);
                    pv[ks][r] = e;
                    tsum += e;
                }
            }
            #pragma unroll
            for (int o = 1; o < 16; o <<= 1) tsum += __shfl_xor(tsum, o);
            l_run[r] = l_run[r] * sc + tsum;
            of0[r] *= sc; of1[r] *= sc;
        }
        #pragma unroll
        for (int ks = 0; ks < 4; ++ks)
            #pragma unroll
            for (int r = 0; r < 4; ++r)
                Ps[w][lg * 4 + r][ks * 16 + lr] = (ks < nks) ? f2bf(pv[ks][r]) : (unsigned short)0;
        #pragma unroll
        for (int kc = 0; kc < 64; kc += 32) {
            if (kc < nks * 16) {
                short8b pa = *(const short8b*)&Ps[w][lr][kc + lg * 8];
                short8b vb0 = *(const short8b*)&Vt[lr][kc + lg * 8];
                short8b vb1 = *(const short8b*)&Vt[16 + lr][kc + lg * 8];
                of0 = __builtin_amdgcn_mfma_f32_16x16x32_bf16(pa, vb0, of0, 0, 0, 0);
                of1 = __builtin_amdgcn_mfma_f32_16x16x32_bf16(pa, vb1, of1, 0, 0, 0);
            }
        }
    }
    #pragma unroll
    for (int r = 0; r < 4; ++r) {
        int q = qg0 + r;
        if (q < SS) {
            float inv = 1.0f / l_run[r];
            out[((size_t)(b * SS + q)) * DM + hh * HD + lr] = f2bf(of0[r] * inv);
            out[((size_t)(b * SS + q)) * DM + hh * HD + 16 + lr] = f2bf(of1[r] * inv);
        }
    }
}

// ---------- final: d2 conv + r4 1x1 conv + alpha blend; inputs bf16 TM ----------
__global__ __launch_bounds__(256) void final2_k(const unsigned short* __restrict__ ud1,
                                                const unsigned short* __restrict__ r3i,
                                                const float* __restrict__ d2w,
                                                const float* __restrict__ d2b,
                                                const float* __restrict__ r4w,
                                                const float* __restrict__ r4b,
                                                const float* __restrict__ alpha,
                                                float* __restrict__ out) {
    __shared__ float u_s[64][66];
    __shared__ float r_s[64][64];
    __shared__ float wd_s[64][3][12];
    __shared__ float wr_s[64][12];
    __shared__ float o_s[64][12];
    const int b = blockIdx.z, t0 = blockIdx.x * 64, tid = threadIdx.x;
    for (int u2 = tid; u2 < 66 * 8; u2 += 256) {
        int j = u2 >> 3, q = u2 & 7;
        int t = t0 + j - 1;
        short8b v = (short8b){0, 0, 0, 0, 0, 0, 0, 0};
        if (t >= 0 && t < TLEN) v = *(const short8b*)&ud1[((size_t)(b * TLEN + t)) * 64 + q * 8];
        #pragma unroll
        for (int i = 0; i < 8; ++i) u_s[q * 8 + i][j] = bf2f((unsigned short)v[i]);
    }
    for (int u2 = tid; u2 < 64 * 8; u2 += 256) {
        int j = u2 >> 3, q = u2 & 7;
        int t = t0 + j;
        short8b v = (short8b){0, 0, 0, 0, 0, 0, 0, 0};
        if (t < TLEN) v = *(const short8b*)&r3i[((size_t)(b * TLEN + t)) * 64 + q * 8];
        #pragma unroll
        for (int i = 0; i < 8; ++i) r_s[q * 8 + i][j] = bf2f((unsigned short)v[i]);
    }
    for (int idx = tid; idx < 64 * 3 * 12; idx += 256) {
        int l = idx % 12, k = (idx / 12) % 3, ci = idx / 36;
        wd_s[ci][k][l] = d2w[(l * 64 + ci) * 3 + k];
    }
    for (int idx = tid; idx < 64 * 12; idx += 256) {
        int l = idx % 12, ci = idx / 12;
        wr_s[ci][l] = r4w[l * 64 + ci];
    }
    __syncthreads();
    const int tl = tid & 63, lg = tid >> 6;
    float accD[3] = {}, accR[3] = {};
    for (int ci = 0; ci < 64; ++ci) {
        float a0 = u_s[ci][tl], a1 = u_s[ci][tl + 1], a2 = u_s[ci][tl + 2];
        float rv = r_s[ci][tl];
        #pragma unroll
        for (int c = 0; c < 3; ++c) {
            int l = lg * 3 + c;
            accD[c] += a0 * wd_s[ci][0][l] + a1 * wd_s[ci][1][l] + a2 * wd_s[ci][2][l];
            accR[c] = fmaf(rv, wr_s[ci][l], accR[c]);
        }
    }
    float al = alpha[0];
    #pragma unroll
    for (int c = 0; c < 3; ++c) {
        int l = lg * 3 + c;
        o_s[tl][l] = accD[c] + d2b[l] + al * (accR[c] + r4b[l]);
    }
    __syncthreads();
    for (int idx = tid; idx < 64 * 12; idx += 256) {
        int t = t0 + idx / 12;
        if (t < TLEN) out[((size_t)b * TLEN + t) * 12 + idx % 12] = o_s[idx / 12][idx % 12];
    }
}

extern "C" void kernel_launch(void* const* d_in, const int* in_sizes, int n_in,
                              void* d_out, int out_size, void* d_ws, size_t ws_size,
                              hipStream_t stream) {
    const float* x     = (const float*)d_in[0];
    const float* pe_w1 = (const float*)d_in[1];
    const float* pe_b1 = (const float*)d_in[2];
    const float* pe_w2 = (const float*)d_in[3];
    const float* pe_b2 = (const float*)d_in[4];
    const float* pe_pw = (const float*)d_in[5];
    const float* pe_pb = (const float*)d_in[6];
    const float* pe_g  = (const float*)d_in[7];
    const float* pe_bb = (const float*)d_in[8];
    const float* cb    = (const float*)d_in[9];
    const float* tp_w  = (const float*)d_in[10];
    const float* tp_b  = (const float*)d_in[11];
    const float* tp_g  = (const float*)d_in[12];
    const float* tp_bb = (const float*)d_in[13];
    const float* ln1_g = (const float*)d_in[14];
    const float* ln1_b = (const float*)d_in[15];
    const float* inw   = (const float*)d_in[16];
    const float* inb   = (const float*)d_in[17];
    const float* ow    = (const float*)d_in[18];
    const float* ob    = (const float*)d_in[19];
    const float* ln2_g = (const float*)d_in[20];
    const float* ln2_b = (const float*)d_in[21];
    const float* f1w   = (const float*)d_in[22];
    const float* f1b   = (const float*)d_in[23];
    const float* f2w   = (const float*)d_in[24];
    const float* f2b   = (const float*)d_in[25];
    const float* slopes= (const float*)d_in[26];
    const float* fn_g  = (const float*)d_in[27];
    const float* fn_b  = (const float*)d_in[28];
    const float* up_w  = (const float*)d_in[29];
    const float* up_b  = (const float*)d_in[30];
    const float* d1w   = (const float*)d_in[31];
    const float* d1b   = (const float*)d_in[32];
    const float* d2w   = (const float*)d_in[33];
    const float* d2b   = (const float*)d_in[34];
    const float* r1w   = (const float*)d_in[35];
    const float* r1b   = (const float*)d_in[36];
    const float* r2w   = (const float*)d_in[37];
    const float* r2b   = (const float*)d_in[38];
    const float* r3w   = (const float*)d_in[39];
    const float* r3b   = (const float*)d_in[40];
    const float* r4w   = (const float*)d_in[41];
    const float* r4b   = (const float*)d_in[42];
    const float* alpha = (const float*)d_in[43];

    float* W = (float*)d_ws;
    size_t off = 0;
    auto alloc = [&](size_t n) { float* p = W + off; off += (n + 3) & ~(size_t)3; return p; };
    const size_t M = (size_t)BATCH * SS;  // 6400
    float* A    = alloc((size_t)BATCH * DP * TLEN);      // pe2 patch-major fp32
    float* Bb   = alloc((size_t)BATCH * 64 * TLEN);      // pe1 out fp32 (B,64,T)
    float* ze   = alloc(M * DP);
    float* tx   = alloc(M * DM);
    float* hb   = alloc(M * DM);
    float* qf   = alloc(M * 3 * DM);                     // qkv/ffn1/utm alias + pgemm partials
    float* cbn  = alloc(VV);
    float* vqs  = alloc(M);
    float* upb2 = alloc(1152);
    unsigned short* zqb  = (unsigned short*)alloc(M * DP / 2);
    unsigned short* xnb  = (unsigned short*)alloc(M * DM / 2);
    unsigned short* aob  = (unsigned short*)alloc(M * DM / 2);
    float* pgpart        = qf;                           // 4 x M x 128 fp32 = 13.1MB <= qf 19.6MB
    unsigned short* qkvb = (unsigned short*)qf;
    unsigned short* ffb  = (unsigned short*)qf;
    unsigned short* utm  = (unsigned short*)qf;
    unsigned short* inwb = (unsigned short*)alloc((size_t)NLAY * 3 * DM * DM / 2);
    unsigned short* owb  = (unsigned short*)alloc((size_t)NLAY * DM * DM / 2);
    unsigned short* f1wb = (unsigned short*)alloc((size_t)NLAY * 4 * DM * DM / 2);
    unsigned short* f2wb = (unsigned short*)alloc((size_t)NLAY * 4 * DM * DM / 2);
    unsigned short* tpwb = (unsigned short*)alloc((size_t)DM * DP / 2);
    unsigned short* upwb = (unsigned short*)alloc((size_t)1152 * DM / 2);
    unsigned short* r2pk = (unsigned short*)alloc((size_t)64 * 64 * 5 / 2);
    unsigned short* r3pk = (unsigned short*)alloc((size_t)64 * 64 * 3 / 2 + 2);
    unsigned short* d1pk = (unsigned short*)alloc((size_t)64 * 128 * 5 / 2);
    unsigned short* r1tm = (unsigned short*)alloc((size_t)BATCH * TLEN * 64 / 2);
    unsigned short* r2tm = (unsigned short*)alloc((size_t)BATCH * TLEN * 64 / 2);
    unsigned short* r3tm = (unsigned short*)alloc((size_t)BATCH * TLEN * 64 / 2);
    unsigned short* d1tm = (unsigned short*)alloc((size_t)BATCH * TLEN * 64 / 2);
    if (off * sizeof(float) > ws_size) return;

    float* outp = (float*)d_out;
    const dim3 cgrid(57, 1, BATCH);    // 64-t tiles
    const dim3 mgrid(29, 1, BATCH);    // 128-t tiles

    // --- weight conversions / packs ---
    tobf_k<<<(NLAY * 3 * DM * DM + 255) / 256, 256, 0, stream>>>(inw, inwb, NLAY * 3 * DM * DM);
    tobf_k<<<(NLAY * DM * DM + 255) / 256, 256, 0, stream>>>(ow, owb, NLAY * DM * DM);
    tobf_k<<<(NLAY * 4 * DM * DM + 255) / 256, 256, 0, stream>>>(f1w, f1wb, NLAY * 4 * DM * DM);
    tobf_k<<<(NLAY * 4 * DM * DM + 255) / 256, 256, 0, stream>>>(f2w, f2wb, NLAY * 4 * DM * DM);
    tobf_k<<<(DM * DP + 255) / 256, 256, 0, stream>>>(tp_w, tpwb, DM * DP);
    upwt2_k<<<(1152 * 256 + 255) / 256, 256, 0, stream>>>(up_w, up_b, upwb, upb2);
    cpack_k<<<(64 * 64 * 5 + 255) / 256, 256, 0, stream>>>(r2w, r2pk, 64, 64, 5);
    cpack_k<<<(64 * 64 * 3 + 255) / 256, 256, 0, stream>>>(r3w, r3pk, 64, 64, 3);
    cpack_k<<<(64 * 128 * 5 + 255) / 256, 256, 0, stream>>>(d1w, d1pk, 64, 128, 5);

    // --- fused pe1 + r1 (fp32 compute) ---
    enc1_k<<<dim3(57, BATCH), 256, 0, stream>>>(x, pe_w1, pe_b1, r1w, r1b, Bb, r1tm);

    // --- encoder tail (fp32: protects VQ argmin) ---
    convg_k<64, 3, 0, 1, 1><<<dim3(57, 2, BATCH), 256, 0, stream>>>(Bb, pe_w2, pe_b2, A, 128, 1);
    cbnorm_k<<<2, 256, 0, stream>>>(cb, cbn);
    gemmsk_k<<<dim3(2, M / 64, 4), 256, 0, stream>>>(A, pe_pw, pgpart, M, DP, DP * PP, DP * PP / 4);
    ln128s_k<<<M, 128, 0, stream>>>(pgpart, pe_pb, pe_g, pe_bb, ze, M);
    vq2_k<<<M / 32, 256, 0, stream>>>(ze, cb, cbn, zqb, vqs);
    vqreduce_k<<<1, 256, 0, stream>>>(vqs, outp + (size_t)BATCH * TLEN * LEADS);

    // --- residual CNN (r2/r3 MFMA) ---
    mfconv_k<64, 5, 2><<<mgrid, 256, 0, stream>>>(r1tm, r2pk, r2b, r2tm);
    mfconv_k<64, 3, 1><<<mgrid, 256, 0, stream>>>(r2tm, r3pk, r3b, r3tm);

    // --- token projection + LN ---
    bgemm_k<0, 0, 0><<<dim3(DM / 128, M / 128), 256, 0, stream>>>(zqb, tpwb, tp_b, nullptr, tx, M, DM, DP);
    lnw_k<0><<<M / 4, 256, 0, stream>>>(tx, tp_g, tp_bb, hb);

    // --- transformer ---
    for (int l = 0; l < NLAY; ++l) {
        lnw_k<1><<<M / 4, 256, 0, stream>>>(hb, ln1_g + l * DM, ln1_b + l * DM, xnb);
        bgemm_k<0, 0, 1><<<dim3(3 * DM / 128, M / 128), 256, 0, stream>>>(
            xnb, inwb + (size_t)l * 3 * DM * DM, inb + l * 3 * DM, nullptr, qkvb, M, 3 * DM, DM);
        fattn_k<<<dim3((SS + 63) / 64, NH, BATCH), 256, 0, stream>>>(qkvb, slopes + l * NH, aob);
        bgemm_k<0, 1, 0><<<dim3(DM / 128, M / 128), 256, 0, stream>>>(
            aob, owb + (size_t)l * DM * DM, ob + l * DM, hb, hb, M, DM, DM);
        lnw_k<1><<<M / 4, 256, 0, stream>>>(hb, ln2_g + l * DM, ln2_b + l * DM, xnb);
        bgemm_k<1, 0, 1><<<dim3(4 * DM / 128, M / 128), 256, 0, stream>>>(
            xnb, f1wb + (size_t)l * 4 * DM * DM, f1b + l * 4 * DM, nullptr, ffb, M, 4 * DM, DM);
        bgemm_k<0, 1, 0><<<dim3(DM / 128, M / 128), 256, 0, stream>>>(
            ffb, f2wb + (size_t)l * 4 * DM * DM, f2b + l * DM, hb, hb, M, DM, 4 * DM);
    }
    lnw_k<1><<<M / 4, 256, 0, stream>>>(hb, fn_g, fn_b, xnb);

    // --- decoder: upproj bgemm -> bf16 (B,T,128) TM, then d1 MFMA conv ---
    bgemm_k<1, 0, 1><<<dim3(1152 / 128, M / 128), 256, 0, stream>>>(xnb, upwb, upb2, nullptr, utm, M, 1152, DM);
    mfconv_k<128, 5, 2><<<mgrid, 256, 0, stream>>>(utm, d1pk, d1b, d1tm);

    // --- fused d2 conv + r4 conv + alpha blend ---
    final2_k<<<cgrid, 256, 0, stream>>>(d1tm, r3tm, d2w, d2b, r4w, r4b, alpha, outp);
}